// Round 4
// baseline (573.336 us; speedup 1.0000x reference)
//
#include <hip/hip_runtime.h>
#include <hip/hip_bf16.h>
#include <math.h>

#define HH 256
#define NCC 128
#define SPWW 64
#define CST 8192
#define VV 10000
#define BBB 16
#define TTT 256
#define LOG2E 1.4426950408889634f
#define LN2 0.6931471805599453f

typedef __attribute__((ext_vector_type(8))) short short8;
typedef __attribute__((ext_vector_type(4))) float f32x4;
typedef unsigned short u16;

__device__ inline float bf2f(u16 u) {
    union { unsigned int i; float f; } v; v.i = ((unsigned int)u) << 16; return v.f;
}
__device__ inline u16 f2bf(float f) {
    __hip_bfloat16 h = __float2bfloat16(f);
    return *reinterpret_cast<u16*>(&h);
}

// ---------------- embeddings (bf16 out) ----------------
__global__ __launch_bounds__(256) void fhmm_emb_bf16_kernel(
    const float* __restrict__ e1, const float* __restrict__ e2,
    u16* __restrict__ out)
{
    int idx = blockIdx.x * 256 + threadIdx.x;   // over 8192*256
    int s = idx >> 8, h = idx & 255;
    out[idx] = f2bf(e1[(s >> 6) * HH + h] + e2[(s & 63) * HH + h]);
}

// ---------------- weight transpose 256x256: Wt[n][k] = bf16(W[k][n]) ----------------
__global__ __launch_bounds__(256) void fhmm_wtrans_kernel(
    const float* __restrict__ W, u16* __restrict__ Wt)
{
    __shared__ float t[64][65];
    int k0 = blockIdx.x * 64, n0 = blockIdx.y * 64, tid = threadIdx.x;
    #pragma unroll
    for (int i = 0; i < 16; ++i) {
        int idx = tid + i * 256; int r = idx >> 6, c = idx & 63;
        t[r][c] = W[(k0 + r) * HH + n0 + c];
    }
    __syncthreads();
    #pragma unroll
    for (int i = 0; i < 16; ++i) {
        int idx = tid + i * 256; int r = idx >> 6, c = idx & 63;
        Wt[(n0 + r) * HH + k0 + c] = f2bf(t[c][r]);
    }
}

// ---------------- pw transpose: pwT[v][k] = bf16(pw[k][v]) ----------------
__global__ __launch_bounds__(256) void fhmm_pwtrans_kernel(
    const float* __restrict__ pw, u16* __restrict__ pwT)
{
    __shared__ float t[64][65];
    int v0 = blockIdx.x * 64, k0 = blockIdx.y * 64, tid = threadIdx.x;
    #pragma unroll
    for (int i = 0; i < 16; ++i) {
        int idx = tid + i * 256; int r = idx >> 6, c = idx & 63;   // r:k, c:v
        int v = v0 + c;
        t[r][c] = (v < VV) ? pw[(size_t)(k0 + r) * VV + v] : 0.f;
    }
    __syncthreads();
    #pragma unroll
    for (int i = 0; i < 16; ++i) {
        int idx = tid + i * 256; int r = idx >> 6, c = idx & 63;   // r:v, c:k
        int v = v0 + r;
        if (v < VV) pwT[(size_t)v * HH + k0 + c] = f2bf(t[c][r]);
    }
}

// ---------------- MFMA MLP layer: Y = relu(X@W + b) [+ res], all bf16 I/O ----------------
__global__ __launch_bounds__(256) void fhmm_mlp_mfma(
    const u16* __restrict__ Xbf, const u16* __restrict__ Wt,
    const float* __restrict__ bias, const u16* __restrict__ resbf,
    u16* __restrict__ Ybf)
{
    int m0 = blockIdx.x * 64, n0 = blockIdx.y * 64;
    __shared__ char Xs[32768];
    __shared__ char Ws[32768];
    int tid = threadIdx.x, w = tid >> 6, lane = tid & 63, lr = lane & 15, lg = lane >> 4;
    const char* xsrc = (const char*)(Xbf + (size_t)m0 * HH);
    const char* wsrc = (const char*)(Wt + (size_t)n0 * HH);
    #pragma unroll
    for (int i = 0; i < 8; ++i) {
        int cc = i * 256 + tid; int row = cc >> 5, tt = cc & 31;
        int dst = row * 512 + ((tt ^ (row & 7)) << 4);
        *(uint4*)&Xs[dst] = *(const uint4*)(xsrc + cc * 16);
        *(uint4*)&Ws[dst] = *(const uint4*)(wsrc + cc * 16);
    }
    __syncthreads();
    short8 bfr[8];
    int brow = w * 16 + lr, bb = brow * 512, bsw = (brow & 7) << 4;
    #pragma unroll
    for (int ks = 0; ks < 8; ++ks)
        bfr[ks] = *(const short8*)(Ws + bb + (((ks * 4 + lg) << 4) ^ bsw));
    int cb = w * 16 + lg * 4;
    f32x4 bv = *(const f32x4*)(bias + n0 + cb);
    #pragma unroll
    for (int rm = 0; rm < 4; ++rm) {
        f32x4 acc = {0.f, 0.f, 0.f, 0.f};
        int ar = rm * 16 + lr, ab = ar * 512, asw = (ar & 7) << 4;
        #pragma unroll
        for (int ks = 0; ks < 8; ++ks) {
            short8 af = *(const short8*)(Xs + ab + (((ks * 4 + lg) << 4) ^ asw));
            acc = __builtin_amdgcn_mfma_f32_16x16x32_bf16(bfr[ks], af, acc, 0, 0, 0);
        }
        int gm = m0 + rm * 16 + lr;
        ushort4 o;
        if (resbf) {
            const u16* rp = resbf + (size_t)gm * HH + n0 + cb;
            #pragma unroll
            for (int e = 0; e < 4; ++e)
                ((u16*)&o)[e] = f2bf(fmaxf(acc[e] + bv[e], 0.f) + bf2f(rp[e]));
        } else {
            #pragma unroll
            for (int e = 0; e < 4; ++e)
                ((u16*)&o)[e] = f2bf(fmaxf(acc[e] + bv[e], 0.f));
        }
        *(ushort4*)(Ybf + (size_t)gm * HH + n0 + cb) = o;
    }
}

// ---------------- start head: dot with pw (bf16 h) ----------------
__global__ __launch_bounds__(256) void fhmm_dotpw_kernel(
    const u16* __restrict__ hb, const float* __restrict__ pw,
    const float* __restrict__ pbp, float* __restrict__ p)
{
    int wv = threadIdx.x >> 6;
    int lane = threadIdx.x & 63;
    int s = blockIdx.x * 4 + wv;
    const u16* hr = hb + (size_t)s * HH;
    float acc = 0.f;
    #pragma unroll
    for (int i = 0; i < 4; ++i) acc += bf2f(hr[i * 64 + lane]) * pw[i * 64 + lane];
    #pragma unroll
    for (int d = 32; d; d >>= 1) acc += __shfl_xor(acc, d);
    if (lane == 0) p[s] = acc + pbp[0];
}

// ---------------- in-place log_softmax over a length-8192 vector ----------------
__global__ __launch_bounds__(1024) void fhmm_lsm_vec_kernel(float* __restrict__ p)
{
    __shared__ float red[64];
    int tid = threadIdx.x;
    float m = -1e30f;
    for (int i = tid; i < CST; i += 1024) m = fmaxf(m, p[i]);
    #pragma unroll
    for (int d = 32; d; d >>= 1) m = fmaxf(m, __shfl_xor(m, d));
    if ((tid & 63) == 0) red[tid >> 6] = m;
    __syncthreads();
    if (tid == 0) {
        float mm = red[0];
        for (int q = 1; q < 16; ++q) mm = fmaxf(mm, red[q]);
        red[32] = mm;
    }
    __syncthreads();
    float M = red[32];
    float s = 0.f;
    for (int i = tid; i < CST; i += 1024) s += expf(p[i] - M);
    #pragma unroll
    for (int d = 32; d; d >>= 1) s += __shfl_xor(s, d);
    if ((tid & 63) == 0) red[tid >> 6] = s;
    __syncthreads();
    if (tid == 0) {
        float ss = 0.f;
        for (int q = 0; q < 16; ++q) ss += red[q];
        red[33] = ss;
    }
    __syncthreads();
    float lse = M + logf(red[33]);
    for (int i = tid; i < CST; i += 1024) p[i] -= lse;
}

// ---------------- transition row-lse via MFMA (streaming over 8192 cols) ----------------
// output pre-scaled to base-2 (× log2e) for the scan
__global__ __launch_bounds__(256) void fhmm_trans_lse_mfma(
    const u16* __restrict__ Abf,   // h_state bf16 [8192][256]
    const u16* __restrict__ Bbf,   // next_emb bf16 [8192][256]
    float* __restrict__ lse2)
{
    __shared__ char bs[2][32768];
    __shared__ float cmb[4][32], csb[4][32];
    int tid = threadIdx.x;
    int w = tid >> 6, lane = tid & 63;
    int lr = lane & 15, lg = lane >> 4;
    int r0 = blockIdx.x * 32;

    short8 afr[2][8];
    #pragma unroll
    for (int rm = 0; rm < 2; ++rm)
        #pragma unroll
        for (int ks = 0; ks < 8; ++ks)
            afr[rm][ks] = *reinterpret_cast<const short8*>(
                Abf + (size_t)(r0 + rm * 16 + lr) * HH + ks * 32 + lg * 8);

    int soff[8], doff[8];
    #pragma unroll
    for (int i = 0; i < 8; ++i) {
        int c = i * 256 + tid;
        int row = c >> 5, t = c & 31;
        soff[i] = c * 16;
        doff[i] = row * 512 + ((t ^ (row & 7)) << 4);
    }
    const char* Bbytes = reinterpret_cast<const char*>(Bbf);
    #pragma unroll
    for (int i = 0; i < 8; ++i)
        *reinterpret_cast<uint4*>(&bs[0][doff[i]]) =
            *reinterpret_cast<const uint4*>(Bbytes + soff[i]);
    __syncthreads();

    float m0 = -1e30f, s0 = 0.f, m1 = -1e30f, s1 = 0.f;
    int brow = w * 16 + lr;
    int bbase = brow * 512;
    int bswz = (brow & 7) << 4;

    for (int ct = 0; ct < 128; ++ct) {
        uint4 stg[8];
        if (ct < 127) {
            const char* src = Bbytes + (size_t)(ct + 1) * 32768;
            #pragma unroll
            for (int i = 0; i < 8; ++i)
                stg[i] = *reinterpret_cast<const uint4*>(src + soff[i]);
        }
        const char* bsrc = bs[ct & 1];
        f32x4 acc0 = {0.f, 0.f, 0.f, 0.f};
        f32x4 acc1 = {0.f, 0.f, 0.f, 0.f};
        #pragma unroll
        for (int ks = 0; ks < 8; ++ks) {
            short8 bf = *reinterpret_cast<const short8*>(
                bsrc + bbase + ((((ks * 4 + lg)) << 4) ^ bswz));
            acc0 = __builtin_amdgcn_mfma_f32_16x16x32_bf16(bf, afr[0][ks], acc0, 0, 0, 0);
            acc1 = __builtin_amdgcn_mfma_f32_16x16x32_bf16(bf, afr[1][ks], acc1, 0, 0, 0);
        }
        {
            float lm = fmaxf(fmaxf(acc0[0], acc0[1]), fmaxf(acc0[2], acc0[3]));
            float mn = fmaxf(m0, lm);
            s0 = s0 * __expf(m0 - mn)
               + __expf(acc0[0] - mn) + __expf(acc0[1] - mn)
               + __expf(acc0[2] - mn) + __expf(acc0[3] - mn);
            m0 = mn;
        }
        {
            float lm = fmaxf(fmaxf(acc1[0], acc1[1]), fmaxf(acc1[2], acc1[3]));
            float mn = fmaxf(m1, lm);
            s1 = s1 * __expf(m1 - mn)
               + __expf(acc1[0] - mn) + __expf(acc1[1] - mn)
               + __expf(acc1[2] - mn) + __expf(acc1[3] - mn);
            m1 = mn;
        }
        if (ct < 127) {
            char* dstb = bs[(ct + 1) & 1];
            #pragma unroll
            for (int i = 0; i < 8; ++i)
                *reinterpret_cast<uint4*>(dstb + doff[i]) = stg[i];
        }
        __syncthreads();
    }

    #pragma unroll
    for (int d = 16; d < 64; d <<= 1) {
        float m2 = __shfl_xor(m0, d), sx = __shfl_xor(s0, d);
        float mn = fmaxf(m0, m2);
        s0 = s0 * __expf(m0 - mn) + sx * __expf(m2 - mn); m0 = mn;
        m2 = __shfl_xor(m1, d); sx = __shfl_xor(s1, d);
        mn = fmaxf(m1, m2);
        s1 = s1 * __expf(m1 - mn) + sx * __expf(m2 - mn); m1 = mn;
    }
    if (lane < 16) {
        cmb[w][lane] = m0;      csb[w][lane] = s0;
        cmb[w][lane + 16] = m1; csb[w][lane + 16] = s1;
    }
    __syncthreads();
    if (tid < 32) {
        float M = cmb[0][tid], S = csb[0][tid];
        #pragma unroll
        for (int q = 1; q < 4; ++q) {
            float m2 = cmb[q][tid], sx = csb[q][tid];
            float mn = fmaxf(M, m2);
            S = S * __expf(M - mn) + sx * __expf(m2 - mn); M = mn;
        }
        lse2[r0 + tid] = (M + logf(S)) * LOG2E;
    }
}

// ---------------- per-(b,t) 64x64 transition-logit blocks, TRANSPOSED bf16 out ----------------
// potsT2[blk][j][i] = logits[i][j] * log2e  (base-2 prescaled)
__global__ __launch_bounds__(256) void fhmm_pots_mfma(
    const u16* __restrict__ Abf, const u16* __restrict__ Bbf,
    const int* __restrict__ text, const int* __restrict__ w2s,
    u16* __restrict__ potsT2)
{
    int blk = blockIdx.x;              // b*255 + t
    int b = blk / (TTT - 1), t = blk % (TTT - 1);
    int sr = w2s[text[b * TTT + t] * SPWW];
    int sc = w2s[text[b * TTT + t + 1] * SPWW];
    __shared__ char As_[32768];
    __shared__ char Bs_[32768];
    int tid = threadIdx.x;
    int w = tid >> 6, lane = tid & 63;
    int lr = lane & 15, lg = lane >> 4;

    const char* Asrc = reinterpret_cast<const char*>(Abf + (size_t)sr * HH);
    const char* Bsrc = reinterpret_cast<const char*>(Bbf + (size_t)sc * HH);
    #pragma unroll
    for (int i = 0; i < 8; ++i) {
        int c = i * 256 + tid;
        int row = c >> 5, tt = c & 31;
        int dst = row * 512 + ((tt ^ (row & 7)) << 4);
        *reinterpret_cast<uint4*>(&As_[dst]) = *reinterpret_cast<const uint4*>(Asrc + c * 16);
        *reinterpret_cast<uint4*>(&Bs_[dst]) = *reinterpret_cast<const uint4*>(Bsrc + c * 16);
    }
    __syncthreads();

    short8 bfr[8];
    int brow = w * 16 + lr;
    int bbase = brow * 512;
    int bswz = (brow & 7) << 4;
    #pragma unroll
    for (int ks = 0; ks < 8; ++ks)
        bfr[ks] = *reinterpret_cast<const short8*>(
            Bs_ + bbase + (((ks * 4 + lg) << 4) ^ bswz));

    u16* op = potsT2 + (size_t)blk * 4096;
    #pragma unroll
    for (int rm = 0; rm < 4; ++rm) {
        f32x4 acc = {0.f, 0.f, 0.f, 0.f};
        int arow = rm * 16 + lr;
        int abase = arow * 512;
        int aswz = (arow & 7) << 4;
        #pragma unroll
        for (int ks = 0; ks < 8; ++ks) {
            short8 af = *reinterpret_cast<const short8*>(
                As_ + abase + (((ks * 4 + lg) << 4) ^ aswz));
            acc = __builtin_amdgcn_mfma_f32_16x16x32_bf16(af, bfr[ks], acc, 0, 0, 0);
        }
        // lane holds C[i = rm*16+lg*4+e][j = w*16+lr]; store potsT[j*64 + i]
        ushort4 o;
        #pragma unroll
        for (int e = 0; e < 4; ++e) ((u16*)&o)[e] = f2bf(acc[e] * LOG2E);
        *(ushort4*)(op + (size_t)(w * 16 + lr) * 64 + rm * 16 + lg * 4) = o;
    }
}

// ---------------- per-class emission GEMM: Ew[v][k] = H_c @ pwT[v] + pb[v] ----------------
__global__ __launch_bounds__(256) void fhmm_ew_mfma(
    const u16* __restrict__ hpre_bf, const u16* __restrict__ pwT,
    const float* __restrict__ pb, const int* __restrict__ wlist,
    const int* __restrict__ counts, const int* __restrict__ offsets,
    float* __restrict__ Ew)
{
    int c = blockIdx.x;
    int cnt = counts[c], off = offsets[c];
    __shared__ char Hs[32768];
    int tid = threadIdx.x, w = tid >> 6, lane = tid & 63, lr = lane & 15, lg = lane >> 4;
    const char* src = (const char*)(hpre_bf + (size_t)c * 64 * HH);
    #pragma unroll
    for (int i = 0; i < 8; ++i) {
        int cc = i * 256 + tid; int row = cc >> 5, tt = cc & 31;
        *(uint4*)&Hs[row * 512 + ((tt ^ (row & 7)) << 4)] = *(const uint4*)(src + cc * 16);
    }
    __syncthreads();
    for (int ch = 0; ch * 64 < cnt; ++ch) {
        int widx = ch * 64 + w * 16 + lr;
        bool valid = widx < cnt;
        int v = valid ? wlist[off + widx] : 0;
        short8 bw[8];
        short8 bz = {0, 0, 0, 0, 0, 0, 0, 0};
        #pragma unroll
        for (int ks = 0; ks < 8; ++ks)
            bw[ks] = valid ? *(const short8*)(pwT + (size_t)v * HH + ks * 32 + lg * 8) : bz;
        float pbv = valid ? pb[v] : 0.f;
        #pragma unroll
        for (int rm = 0; rm < 4; ++rm) {
            f32x4 acc = {0.f, 0.f, 0.f, 0.f};
            int ar = rm * 16 + lr, ab = ar * 512, asw = (ar & 7) << 4;
            #pragma unroll
            for (int ks = 0; ks < 8; ++ks) {
                short8 ah = *(const short8*)(Hs + ab + (((ks * 4 + lg) << 4) ^ asw));
                acc = __builtin_amdgcn_mfma_f32_16x16x32_bf16(ah, bw[ks], acc, 0, 0, 0);
            }
            if (valid) {
                f32x4 o;
                #pragma unroll
                for (int e = 0; e < 4; ++e) o[e] = acc[e] + pbv;
                *(f32x4*)(Ew + (size_t)v * 64 + rm * 16 + lg * 4) = o;
            }
        }
    }
}

// ---------------- class word-lists ----------------
__global__ void fhmm_init_counts_kernel(int* counts, int* cursor) {
    int i = threadIdx.x;
    if (i < NCC) { counts[i] = 0; cursor[i] = 0; }
}
__global__ void fhmm_hist_kernel(const int* __restrict__ w2s, int* counts) {
    int v = blockIdx.x * 256 + threadIdx.x;
    if (v < VV) atomicAdd(&counts[w2s[v * SPWW] >> 6], 1);
}
__global__ void fhmm_offsets_kernel(const int* counts, int* offsets) {
    if (threadIdx.x == 0) {
        int acc = 0;
        for (int c = 0; c < NCC; ++c) { offsets[c] = acc; acc += counts[c]; }
        offsets[NCC] = acc;
    }
}
__global__ void fhmm_scatter_kernel(const int* __restrict__ w2s, const int* offsets,
                                    int* cursor, int* wlist) {
    int v = blockIdx.x * 256 + threadIdx.x;
    if (v < VV) {
        int c = w2s[v * SPWW] >> 6;
        int pos = atomicAdd(&cursor[c], 1);
        wlist[offsets[c] + pos] = v;
    }
}

// ---------------- per-state emission lse ----------------
__global__ __launch_bounds__(64) void fhmm_lse_em_kernel(
    const float* __restrict__ Ew, const int* __restrict__ wlist,
    const int* __restrict__ counts, const int* __restrict__ offsets,
    float* __restrict__ lse_em)
{
    int c = blockIdx.x, k = threadIdx.x;
    int cnt = counts[c], off = offsets[c];
    float m = -1e30f;
    for (int i = 0; i < cnt; ++i) m = fmaxf(m, Ew[wlist[off + i] * 64 + k]);
    float s = 0.f;
    for (int i = 0; i < cnt; ++i) s += __expf(Ew[wlist[off + i] * 64 + k] - m);
    lse_em[c * 64 + k] = (cnt > 0) ? (m + logf(s)) : -1e30f;
}

// ---------------- obs2[b,t,k] (base-2 prescaled) ----------------
__global__ __launch_bounds__(64) void fhmm_obs_kernel(
    const float* __restrict__ Ew, const float* __restrict__ lse_em,
    const int* __restrict__ text, const int* __restrict__ w2s,
    float* __restrict__ obs2)
{
    int i = blockIdx.x;      // b*T + t
    int k = threadIdx.x;
    int v = text[i];
    int s = w2s[v * SPWW + k];
    obs2[i * 64 + k] = (Ew[v * 64 + k] - lse_em[s]) * LOG2E;
}

// ---------------- forward scan: base-2, raw barriers (no vmcnt drain), depth-8 prefetch ----------------
__global__ __launch_bounds__(512) void fhmm_scan_kernel(
    const int* __restrict__ text, const int* __restrict__ w2s,
    const float* __restrict__ startv, const float* __restrict__ lse_trans2,
    const u16* __restrict__ potsT2, const float* __restrict__ obs2,
    float* __restrict__ out)
{
    int b = blockIdx.x;
    int tid = threadIdx.x;
    int j = tid >> 3, g = tid & 7;
    __shared__ float al[2][64];
    __shared__ float afin[64];
    __shared__ int srow_lds[256];
    if (tid < 256) srow_lds[tid] = w2s[text[b * TTT + tid] * SPWW];
    __syncthreads();
    if (g == 0) {
        int s0 = srow_lds[0];
        al[1][j] = startv[s0 + j] * LOG2E + obs2[(size_t)(b * TTT) * 64 + j]
                   - lse_trans2[s0 + j];
    }

    const u16* pbase = potsT2 + (size_t)b * 255 * 4096;
    uint4 pv[8]; float ob[8], lt[8];
    #pragma unroll
    for (int d = 0; d < 8; ++d) {
        int t = 1 + d;
        pv[d] = *(const uint4*)(pbase + (size_t)(t - 1) * 4096 + j * 64 + g * 8);
        ob[d] = obs2[(size_t)(b * TTT + t) * 64 + j];
        lt[d] = lse_trans2[srow_lds[t] + j];
    }
    asm volatile("s_waitcnt lgkmcnt(0)\ns_barrier" ::: "memory");

    for (int t0 = 1; t0 < 256; t0 += 8) {
        #pragma unroll
        for (int d = 0; d < 8; ++d) {
            int t = t0 + d;
            if (t <= 255) {
                uint4 P = pv[d];
                float obv = ob[d], ltv = lt[d];
                // prefetch step t+8 (stays in flight across raw barriers)
                if (t + 8 <= 255) {
                    int tn = t + 8;
                    pv[d] = *(const uint4*)(pbase + (size_t)(tn - 1) * 4096 + j * 64 + g * 8);
                    ob[d] = obs2[(size_t)(b * TTT + tn) * 64 + j];
                    lt[d] = lse_trans2[srow_lds[tn] + j];
                }
                const float* ab = al[t & 1];
                const u16* ps = (const u16*)&P;
                float vv[8];
                #pragma unroll
                for (int ii = 0; ii < 8; ++ii)
                    vv[ii] = ab[g * 8 + ii] + bf2f(ps[ii]);
                float m = fmaxf(fmaxf(fmaxf(vv[0], vv[1]), fmaxf(vv[2], vv[3])),
                                fmaxf(fmaxf(vv[4], vv[5]), fmaxf(vv[6], vv[7])));
                float s = 0.f;
                #pragma unroll
                for (int ii = 0; ii < 8; ++ii) s += exp2f(vv[ii] - m);
                #pragma unroll
                for (int dd = 1; dd < 8; dd <<= 1) {
                    float m2 = __shfl_xor(m, dd);
                    float s2 = __shfl_xor(s, dd);
                    float mn = fmaxf(m, m2);
                    s = s * exp2f(m - mn) + s2 * exp2f(m2 - mn);
                    m = mn;
                }
                float alpha_t = m + log2f(s) + obv;
                if (g == 0) {
                    if (t < 255) al[(t + 1) & 1][j] = alpha_t - ltv;
                    else afin[j] = alpha_t;
                }
                asm volatile("s_waitcnt lgkmcnt(0)\ns_barrier" ::: "memory");
            }
        }
    }

    if (tid < 64) {
        float a = afin[tid];
        float m = a;
        #pragma unroll
        for (int d = 32; d; d >>= 1) m = fmaxf(m, __shfl_xor(m, d));
        float s = exp2f(a - m);
        #pragma unroll
        for (int d = 32; d; d >>= 1) s += __shfl_xor(s, d);
        if (tid == 0) out[b] = (m + log2f(s)) * LN2;
    }
}

extern "C" void kernel_launch(void* const* d_in, const int* in_sizes, int n_in,
                              void* d_out, int out_size, void* d_ws, size_t ws_size,
                              hipStream_t stream) {
    const int* text        = (const int*)d_in[0];
    const int* w2s         = (const int*)d_in[1];
    const float* se1_start = (const float*)d_in[2];
    const float* se2_start = (const float*)d_in[3];
    const float* start_w1  = (const float*)d_in[4];
    const float* start_b1  = (const float*)d_in[5];
    const float* start_w2  = (const float*)d_in[6];
    const float* start_b2  = (const float*)d_in[7];
    const float* start_pw  = (const float*)d_in[8];
    const float* start_pb  = (const float*)d_in[9];
    const float* se1_state = (const float*)d_in[10];
    const float* se2_state = (const float*)d_in[11];
    const float* se1_next  = (const float*)d_in[12];
    const float* se2_next  = (const float*)d_in[13];
    const float* trans_w1  = (const float*)d_in[14];
    const float* trans_b1  = (const float*)d_in[15];
    const float* trans_w2  = (const float*)d_in[16];
    const float* trans_b2  = (const float*)d_in[17];
    const float* se1_pre   = (const float*)d_in[18];
    const float* se2_pre   = (const float*)d_in[19];
    const float* term_w1   = (const float*)d_in[20];
    const float* term_b1   = (const float*)d_in[21];
    const float* term_w2   = (const float*)d_in[22];
    const float* term_b2   = (const float*)d_in[23];
    const float* term_pw   = (const float*)d_in[24];
    const float* term_pb   = (const float*)d_in[25];
    float* out = (float*)d_out;

    char* wp = (char*)d_ws;
    auto alloc = [&](size_t bytes) {
        char* p = wp;
        wp += (bytes + 255) & ~(size_t)255;
        return (void*)p;
    };
    u16* emb_bf      = (u16*)alloc((size_t)CST * HH * 2);
    u16* h1_bf       = (u16*)alloc((size_t)CST * HH * 2);
    u16* hstart_bf   = (u16*)alloc((size_t)CST * HH * 2);
    u16* h_state_bf  = (u16*)alloc((size_t)CST * HH * 2);
    u16* h_pre_bf    = (u16*)alloc((size_t)CST * HH * 2);
    u16* next_emb_bf = (u16*)alloc((size_t)CST * HH * 2);
    u16* Wt          = (u16*)alloc((size_t)6 * HH * HH * 2);
    u16* pwT         = (u16*)alloc((size_t)VV * HH * 2);
    float* startv    = (float*)alloc(CST * 4);
    float* lse_trans = (float*)alloc(CST * 4);
    float* lse_em    = (float*)alloc(CST * 4);
    float* Ew        = (float*)alloc((size_t)VV * 64 * 4);
    int* counts      = (int*)alloc(NCC * 4);
    int* offsets     = (int*)alloc((NCC + 4) * 4);
    int* cursor      = (int*)alloc(NCC * 4);
    int* wlist       = (int*)alloc(VV * 4);
    float* obs       = (float*)alloc((size_t)BBB * TTT * 64 * 4);
    u16* potsT       = (u16*)alloc((size_t)BBB * (TTT - 1) * 4096 * 2);

    // weight transposes
    const float* Ws_[6] = {start_w1, start_w2, trans_w1, trans_w2, term_w1, term_w2};
    for (int q = 0; q < 6; ++q)
        hipLaunchKernelGGL(fhmm_wtrans_kernel, dim3(4, 4), 256, 0, stream,
                           Ws_[q], Wt + (size_t)q * HH * HH);
    hipLaunchKernelGGL(fhmm_pwtrans_kernel, dim3((VV + 63) / 64, 4), 256, 0, stream,
                       term_pw, pwT);

    // class word-lists
    hipLaunchKernelGGL(fhmm_init_counts_kernel, dim3(1), 128, 0, stream, counts, cursor);
    hipLaunchKernelGGL(fhmm_hist_kernel, dim3(40), 256, 0, stream, w2s, counts);
    hipLaunchKernelGGL(fhmm_offsets_kernel, dim3(1), 64, 0, stream, counts, offsets);
    hipLaunchKernelGGL(fhmm_scatter_kernel, dim3(40), 256, 0, stream, w2s, offsets, cursor, wlist);

    // next_emb
    hipLaunchKernelGGL(fhmm_emb_bf16_kernel, dim3(8192), 256, 0, stream,
                       se1_next, se2_next, next_emb_bf);

    dim3 mmGrid(128, 4);
    // start head
    hipLaunchKernelGGL(fhmm_emb_bf16_kernel, dim3(8192), 256, 0, stream,
                       se1_start, se2_start, emb_bf);
    hipLaunchKernelGGL(fhmm_mlp_mfma, mmGrid, 256, 0, stream,
                       emb_bf, Wt + 0 * HH * HH, start_b1, (const u16*)nullptr, h1_bf);
    hipLaunchKernelGGL(fhmm_mlp_mfma, mmGrid, 256, 0, stream,
                       h1_bf, Wt + 1 * HH * HH, start_b2, emb_bf, hstart_bf);
    hipLaunchKernelGGL(fhmm_dotpw_kernel, dim3(2048), 256, 0, stream,
                       hstart_bf, start_pw, start_pb, startv);
    hipLaunchKernelGGL(fhmm_lsm_vec_kernel, dim3(1), 1024, 0, stream, startv);

    // state head
    hipLaunchKernelGGL(fhmm_emb_bf16_kernel, dim3(8192), 256, 0, stream,
                       se1_state, se2_state, emb_bf);
    hipLaunchKernelGGL(fhmm_mlp_mfma, mmGrid, 256, 0, stream,
                       emb_bf, Wt + 2 * HH * HH, trans_b1, (const u16*)nullptr, h1_bf);
    hipLaunchKernelGGL(fhmm_mlp_mfma, mmGrid, 256, 0, stream,
                       h1_bf, Wt + 3 * HH * HH, trans_b2, emb_bf, h_state_bf);

    // pre head
    hipLaunchKernelGGL(fhmm_emb_bf16_kernel, dim3(8192), 256, 0, stream,
                       se1_pre, se2_pre, emb_bf);
    hipLaunchKernelGGL(fhmm_mlp_mfma, mmGrid, 256, 0, stream,
                       emb_bf, Wt + 4 * HH * HH, term_b1, (const u16*)nullptr, h1_bf);
    hipLaunchKernelGGL(fhmm_mlp_mfma, mmGrid, 256, 0, stream,
                       h1_bf, Wt + 5 * HH * HH, term_b2, emb_bf, h_pre_bf);

    // transition row-lse + pots (base-2 prescaled outputs)
    hipLaunchKernelGGL(fhmm_trans_lse_mfma, dim3(256), 256, 0, stream,
                       h_state_bf, next_emb_bf, lse_trans);
    hipLaunchKernelGGL(fhmm_pots_mfma, dim3(BBB * (TTT - 1)), 256, 0, stream,
                       h_state_bf, next_emb_bf, text, w2s, potsT);

    // emission
    hipLaunchKernelGGL(fhmm_ew_mfma, dim3(NCC), 256, 0, stream,
                       h_pre_bf, pwT, term_pb, wlist, counts, offsets, Ew);
    hipLaunchKernelGGL(fhmm_lse_em_kernel, dim3(NCC), 64, 0, stream,
                       Ew, wlist, counts, offsets, lse_em);
    hipLaunchKernelGGL(fhmm_obs_kernel, dim3(BBB * TTT), 64, 0, stream,
                       Ew, lse_em, text, w2s, obs);

    // forward scan
    hipLaunchKernelGGL(fhmm_scan_kernel, dim3(BBB), 512, 0, stream,
                       text, w2s, startv, lse_trans, potsT, obs, out);
}

// Round 5
// 358.718 us; speedup vs baseline: 1.5983x; 1.5983x over previous
//
#include <hip/hip_runtime.h>
#include <hip/hip_bf16.h>
#include <math.h>

#define HH 256
#define NCC 128
#define SPWW 64
#define CST 8192
#define VV 10000
#define BBB 16
#define TTT 256
#define LOG2E 1.4426950408889634f
#define LN2 0.6931471805599453f

typedef __attribute__((ext_vector_type(8))) short short8;
typedef __attribute__((ext_vector_type(4))) float f32x4;
typedef unsigned short u16;

__device__ inline float bf2f(u16 u) {
    union { unsigned int i; float f; } v; v.i = ((unsigned int)u) << 16; return v.f;
}
__device__ inline u16 f2bf(float f) {
    __hip_bfloat16 h = __float2bfloat16(f);
    return *reinterpret_cast<u16*>(&h);
}
__device__ inline float ex2(float x) { return __builtin_amdgcn_exp2f(x); }
__device__ inline float lg2(float x) { return __builtin_amdgcn_logf(x); }

// ---------------- embeddings (bf16 out) ----------------
__global__ __launch_bounds__(256) void fhmm_emb_bf16_kernel(
    const float* __restrict__ e1, const float* __restrict__ e2,
    u16* __restrict__ out)
{
    int idx = blockIdx.x * 256 + threadIdx.x;   // over 8192*256
    int s = idx >> 8, h = idx & 255;
    out[idx] = f2bf(e1[(s >> 6) * HH + h] + e2[(s & 63) * HH + h]);
}

// ---------------- weight transpose 256x256: Wt[n][k] = bf16(W[k][n]) ----------------
__global__ __launch_bounds__(256) void fhmm_wtrans_kernel(
    const float* __restrict__ W, u16* __restrict__ Wt)
{
    __shared__ float t[64][65];
    int k0 = blockIdx.x * 64, n0 = blockIdx.y * 64, tid = threadIdx.x;
    #pragma unroll
    for (int i = 0; i < 16; ++i) {
        int idx = tid + i * 256; int r = idx >> 6, c = idx & 63;
        t[r][c] = W[(k0 + r) * HH + n0 + c];
    }
    __syncthreads();
    #pragma unroll
    for (int i = 0; i < 16; ++i) {
        int idx = tid + i * 256; int r = idx >> 6, c = idx & 63;
        Wt[(n0 + r) * HH + k0 + c] = f2bf(t[c][r]);
    }
}

// ---------------- pw transpose: pwT[v][k] = bf16(pw[k][v]) ----------------
__global__ __launch_bounds__(256) void fhmm_pwtrans_kernel(
    const float* __restrict__ pw, u16* __restrict__ pwT)
{
    __shared__ float t[64][65];
    int v0 = blockIdx.x * 64, k0 = blockIdx.y * 64, tid = threadIdx.x;
    #pragma unroll
    for (int i = 0; i < 16; ++i) {
        int idx = tid + i * 256; int r = idx >> 6, c = idx & 63;   // r:k, c:v
        int v = v0 + c;
        t[r][c] = (v < VV) ? pw[(size_t)(k0 + r) * VV + v] : 0.f;
    }
    __syncthreads();
    #pragma unroll
    for (int i = 0; i < 16; ++i) {
        int idx = tid + i * 256; int r = idx >> 6, c = idx & 63;   // r:v, c:k
        int v = v0 + r;
        if (v < VV) pwT[(size_t)v * HH + k0 + c] = f2bf(t[c][r]);
    }
}

// ---------------- MFMA MLP layer: Y = relu(X@W + b) [+ res], all bf16 I/O ----------------
__global__ __launch_bounds__(256) void fhmm_mlp_mfma(
    const u16* __restrict__ Xbf, const u16* __restrict__ Wt,
    const float* __restrict__ bias, const u16* __restrict__ resbf,
    u16* __restrict__ Ybf)
{
    int m0 = blockIdx.x * 64, n0 = blockIdx.y * 64;
    __shared__ char Xs[32768];
    __shared__ char Ws[32768];
    int tid = threadIdx.x, w = tid >> 6, lane = tid & 63, lr = lane & 15, lg = lane >> 4;
    const char* xsrc = (const char*)(Xbf + (size_t)m0 * HH);
    const char* wsrc = (const char*)(Wt + (size_t)n0 * HH);
    #pragma unroll
    for (int i = 0; i < 8; ++i) {
        int cc = i * 256 + tid; int row = cc >> 5, tt = cc & 31;
        int dst = row * 512 + ((tt ^ (row & 7)) << 4);
        *(uint4*)&Xs[dst] = *(const uint4*)(xsrc + cc * 16);
        *(uint4*)&Ws[dst] = *(const uint4*)(wsrc + cc * 16);
    }
    __syncthreads();
    short8 bfr[8];
    int brow = w * 16 + lr, bb = brow * 512, bsw = (brow & 7) << 4;
    #pragma unroll
    for (int ks = 0; ks < 8; ++ks)
        bfr[ks] = *(const short8*)(Ws + bb + (((ks * 4 + lg) << 4) ^ bsw));
    int cb = w * 16 + lg * 4;
    f32x4 bv = *(const f32x4*)(bias + n0 + cb);
    #pragma unroll
    for (int rm = 0; rm < 4; ++rm) {
        f32x4 acc = {0.f, 0.f, 0.f, 0.f};
        int ar = rm * 16 + lr, ab = ar * 512, asw = (ar & 7) << 4;
        #pragma unroll
        for (int ks = 0; ks < 8; ++ks) {
            short8 af = *(const short8*)(Xs + ab + (((ks * 4 + lg) << 4) ^ asw));
            acc = __builtin_amdgcn_mfma_f32_16x16x32_bf16(bfr[ks], af, acc, 0, 0, 0);
        }
        int gm = m0 + rm * 16 + lr;
        ushort4 o;
        if (resbf) {
            const u16* rp = resbf + (size_t)gm * HH + n0 + cb;
            #pragma unroll
            for (int e = 0; e < 4; ++e)
                ((u16*)&o)[e] = f2bf(fmaxf(acc[e] + bv[e], 0.f) + bf2f(rp[e]));
        } else {
            #pragma unroll
            for (int e = 0; e < 4; ++e)
                ((u16*)&o)[e] = f2bf(fmaxf(acc[e] + bv[e], 0.f));
        }
        *(ushort4*)(Ybf + (size_t)gm * HH + n0 + cb) = o;
    }
}

// ---------------- start head: dot with pw (bf16 h) ----------------
__global__ __launch_bounds__(256) void fhmm_dotpw_kernel(
    const u16* __restrict__ hb, const float* __restrict__ pw,
    const float* __restrict__ pbp, float* __restrict__ p)
{
    int wv = threadIdx.x >> 6;
    int lane = threadIdx.x & 63;
    int s = blockIdx.x * 4 + wv;
    const u16* hr = hb + (size_t)s * HH;
    float acc = 0.f;
    #pragma unroll
    for (int i = 0; i < 4; ++i) acc += bf2f(hr[i * 64 + lane]) * pw[i * 64 + lane];
    #pragma unroll
    for (int d = 32; d; d >>= 1) acc += __shfl_xor(acc, d);
    if (lane == 0) p[s] = acc + pbp[0];
}

// ---------------- in-place log_softmax over a length-8192 vector ----------------
__global__ __launch_bounds__(1024) void fhmm_lsm_vec_kernel(float* __restrict__ p)
{
    __shared__ float red[64];
    int tid = threadIdx.x;
    float m = -1e30f;
    for (int i = tid; i < CST; i += 1024) m = fmaxf(m, p[i]);
    #pragma unroll
    for (int d = 32; d; d >>= 1) m = fmaxf(m, __shfl_xor(m, d));
    if ((tid & 63) == 0) red[tid >> 6] = m;
    __syncthreads();
    if (tid == 0) {
        float mm = red[0];
        for (int q = 1; q < 16; ++q) mm = fmaxf(mm, red[q]);
        red[32] = mm;
    }
    __syncthreads();
    float M = red[32];
    float s = 0.f;
    for (int i = tid; i < CST; i += 1024) s += expf(p[i] - M);
    #pragma unroll
    for (int d = 32; d; d >>= 1) s += __shfl_xor(s, d);
    if ((tid & 63) == 0) red[tid >> 6] = s;
    __syncthreads();
    if (tid == 0) {
        float ss = 0.f;
        for (int q = 0; q < 16; ++q) ss += red[q];
        red[33] = ss;
    }
    __syncthreads();
    float lse = M + logf(red[33]);
    for (int i = tid; i < CST; i += 1024) p[i] -= lse;
}

// ---------------- transition row-lse via MFMA (streaming over 8192 cols) ----------------
// output pre-scaled to base-2 (× log2e)
__global__ __launch_bounds__(256) void fhmm_trans_lse_mfma(
    const u16* __restrict__ Abf,   // h_state bf16 [8192][256]
    const u16* __restrict__ Bbf,   // next_emb bf16 [8192][256]
    float* __restrict__ lse2)
{
    __shared__ char bs[2][32768];
    __shared__ float cmb[4][32], csb[4][32];
    int tid = threadIdx.x;
    int w = tid >> 6, lane = tid & 63;
    int lr = lane & 15, lg = lane >> 4;
    int r0 = blockIdx.x * 32;

    short8 afr[2][8];
    #pragma unroll
    for (int rm = 0; rm < 2; ++rm)
        #pragma unroll
        for (int ks = 0; ks < 8; ++ks)
            afr[rm][ks] = *reinterpret_cast<const short8*>(
                Abf + (size_t)(r0 + rm * 16 + lr) * HH + ks * 32 + lg * 8);

    int soff[8], doff[8];
    #pragma unroll
    for (int i = 0; i < 8; ++i) {
        int c = i * 256 + tid;
        int row = c >> 5, t = c & 31;
        soff[i] = c * 16;
        doff[i] = row * 512 + ((t ^ (row & 7)) << 4);
    }
    const char* Bbytes = reinterpret_cast<const char*>(Bbf);
    #pragma unroll
    for (int i = 0; i < 8; ++i)
        *reinterpret_cast<uint4*>(&bs[0][doff[i]]) =
            *reinterpret_cast<const uint4*>(Bbytes + soff[i]);
    __syncthreads();

    float m0 = -1e30f, s0 = 0.f, m1 = -1e30f, s1 = 0.f;
    int brow = w * 16 + lr;
    int bbase = brow * 512;
    int bswz = (brow & 7) << 4;

    for (int ct = 0; ct < 128; ++ct) {
        uint4 stg[8];
        if (ct < 127) {
            const char* src = Bbytes + (size_t)(ct + 1) * 32768;
            #pragma unroll
            for (int i = 0; i < 8; ++i)
                stg[i] = *reinterpret_cast<const uint4*>(src + soff[i]);
        }
        const char* bsrc = bs[ct & 1];
        f32x4 acc0 = {0.f, 0.f, 0.f, 0.f};
        f32x4 acc1 = {0.f, 0.f, 0.f, 0.f};
        #pragma unroll
        for (int ks = 0; ks < 8; ++ks) {
            short8 bf = *reinterpret_cast<const short8*>(
                bsrc + bbase + ((((ks * 4 + lg)) << 4) ^ bswz));
            acc0 = __builtin_amdgcn_mfma_f32_16x16x32_bf16(bf, afr[0][ks], acc0, 0, 0, 0);
            acc1 = __builtin_amdgcn_mfma_f32_16x16x32_bf16(bf, afr[1][ks], acc1, 0, 0, 0);
        }
        {
            float lm = fmaxf(fmaxf(acc0[0], acc0[1]), fmaxf(acc0[2], acc0[3]));
            float mn = fmaxf(m0, lm);
            s0 = s0 * __expf(m0 - mn)
               + __expf(acc0[0] - mn) + __expf(acc0[1] - mn)
               + __expf(acc0[2] - mn) + __expf(acc0[3] - mn);
            m0 = mn;
        }
        {
            float lm = fmaxf(fmaxf(acc1[0], acc1[1]), fmaxf(acc1[2], acc1[3]));
            float mn = fmaxf(m1, lm);
            s1 = s1 * __expf(m1 - mn)
               + __expf(acc1[0] - mn) + __expf(acc1[1] - mn)
               + __expf(acc1[2] - mn) + __expf(acc1[3] - mn);
            m1 = mn;
        }
        if (ct < 127) {
            char* dstb = bs[(ct + 1) & 1];
            #pragma unroll
            for (int i = 0; i < 8; ++i)
                *reinterpret_cast<uint4*>(dstb + doff[i]) = stg[i];
        }
        __syncthreads();
    }

    #pragma unroll
    for (int d = 16; d < 64; d <<= 1) {
        float m2 = __shfl_xor(m0, d), sx = __shfl_xor(s0, d);
        float mn = fmaxf(m0, m2);
        s0 = s0 * __expf(m0 - mn) + sx * __expf(m2 - mn); m0 = mn;
        m2 = __shfl_xor(m1, d); sx = __shfl_xor(s1, d);
        mn = fmaxf(m1, m2);
        s1 = s1 * __expf(m1 - mn) + sx * __expf(m2 - mn); m1 = mn;
    }
    if (lane < 16) {
        cmb[w][lane] = m0;      csb[w][lane] = s0;
        cmb[w][lane + 16] = m1; csb[w][lane + 16] = s1;
    }
    __syncthreads();
    if (tid < 32) {
        float M = cmb[0][tid], S = csb[0][tid];
        #pragma unroll
        for (int q = 1; q < 4; ++q) {
            float m2 = cmb[q][tid], sx = csb[q][tid];
            float mn = fmaxf(M, m2);
            S = S * __expf(M - mn) + sx * __expf(m2 - mn); M = mn;
        }
        lse2[r0 + tid] = (M + logf(S)) * LOG2E;
    }
}

// ---------------- per-(b,t) 64x64 transition-logit blocks, TRANSPOSED bf16 out ----------------
// potsT2[blk][j][i] = logits[i][j] * log2e
__global__ __launch_bounds__(256) void fhmm_pots_mfma(
    const u16* __restrict__ Abf, const u16* __restrict__ Bbf,
    const int* __restrict__ text, const int* __restrict__ w2s,
    u16* __restrict__ potsT2)
{
    int blk = blockIdx.x;              // b*255 + t
    int b = blk / (TTT - 1), t = blk % (TTT - 1);
    int sr = w2s[text[b * TTT + t] * SPWW];
    int sc = w2s[text[b * TTT + t + 1] * SPWW];
    __shared__ char As_[32768];
    __shared__ char Bs_[32768];
    int tid = threadIdx.x;
    int w = tid >> 6, lane = tid & 63;
    int lr = lane & 15, lg = lane >> 4;

    const char* Asrc = reinterpret_cast<const char*>(Abf + (size_t)sr * HH);
    const char* Bsrc = reinterpret_cast<const char*>(Bbf + (size_t)sc * HH);
    #pragma unroll
    for (int i = 0; i < 8; ++i) {
        int c = i * 256 + tid;
        int row = c >> 5, tt = c & 31;
        int dst = row * 512 + ((tt ^ (row & 7)) << 4);
        *reinterpret_cast<uint4*>(&As_[dst]) = *reinterpret_cast<const uint4*>(Asrc + c * 16);
        *reinterpret_cast<uint4*>(&Bs_[dst]) = *reinterpret_cast<const uint4*>(Bsrc + c * 16);
    }
    __syncthreads();

    short8 bfr[8];
    int brow = w * 16 + lr;
    int bbase = brow * 512;
    int bswz = (brow & 7) << 4;
    #pragma unroll
    for (int ks = 0; ks < 8; ++ks)
        bfr[ks] = *reinterpret_cast<const short8*>(
            Bs_ + bbase + (((ks * 4 + lg) << 4) ^ bswz));

    u16* op = potsT2 + (size_t)blk * 4096;
    #pragma unroll
    for (int rm = 0; rm < 4; ++rm) {
        f32x4 acc = {0.f, 0.f, 0.f, 0.f};
        int arow = rm * 16 + lr;
        int abase = arow * 512;
        int aswz = (arow & 7) << 4;
        #pragma unroll
        for (int ks = 0; ks < 8; ++ks) {
            short8 af = *reinterpret_cast<const short8*>(
                As_ + abase + (((ks * 4 + lg) << 4) ^ aswz));
            acc = __builtin_amdgcn_mfma_f32_16x16x32_bf16(af, bfr[ks], acc, 0, 0, 0);
        }
        ushort4 o;
        #pragma unroll
        for (int e = 0; e < 4; ++e) ((u16*)&o)[e] = f2bf(acc[e] * LOG2E);
        *(ushort4*)(op + (size_t)(w * 16 + lr) * 64 + rm * 16 + lg * 4) = o;
    }
}

// ---------------- per-class emission GEMM: Ew[v][k] = H_c @ pwT[v] + pb[v] ----------------
__global__ __launch_bounds__(256) void fhmm_ew_mfma(
    const u16* __restrict__ hpre_bf, const u16* __restrict__ pwT,
    const float* __restrict__ pb, const int* __restrict__ wlist,
    const int* __restrict__ counts, const int* __restrict__ offsets,
    float* __restrict__ Ew)
{
    int c = blockIdx.x;
    int cnt = counts[c], off = offsets[c];
    __shared__ char Hs[32768];
    int tid = threadIdx.x, w = tid >> 6, lane = tid & 63, lr = lane & 15, lg = lane >> 4;
    const char* src = (const char*)(hpre_bf + (size_t)c * 64 * HH);
    #pragma unroll
    for (int i = 0; i < 8; ++i) {
        int cc = i * 256 + tid; int row = cc >> 5, tt = cc & 31;
        *(uint4*)&Hs[row * 512 + ((tt ^ (row & 7)) << 4)] = *(const uint4*)(src + cc * 16);
    }
    __syncthreads();
    for (int ch = 0; ch * 64 < cnt; ++ch) {
        int widx = ch * 64 + w * 16 + lr;
        bool valid = widx < cnt;
        int v = valid ? wlist[off + widx] : 0;
        short8 bw[8];
        short8 bz = {0, 0, 0, 0, 0, 0, 0, 0};
        #pragma unroll
        for (int ks = 0; ks < 8; ++ks)
            bw[ks] = valid ? *(const short8*)(pwT + (size_t)v * HH + ks * 32 + lg * 8) : bz;
        float pbv = valid ? pb[v] : 0.f;
        #pragma unroll
        for (int rm = 0; rm < 4; ++rm) {
            f32x4 acc = {0.f, 0.f, 0.f, 0.f};
            int ar = rm * 16 + lr, ab = ar * 512, asw = (ar & 7) << 4;
            #pragma unroll
            for (int ks = 0; ks < 8; ++ks) {
                short8 ah = *(const short8*)(Hs + ab + (((ks * 4 + lg) << 4) ^ asw));
                acc = __builtin_amdgcn_mfma_f32_16x16x32_bf16(ah, bw[ks], acc, 0, 0, 0);
            }
            if (valid) {
                f32x4 o;
                #pragma unroll
                for (int e = 0; e < 4; ++e) o[e] = acc[e] + pbv;
                *(f32x4*)(Ew + (size_t)v * 64 + rm * 16 + lg * 4) = o;
            }
        }
    }
}

// ---------------- class word-lists ----------------
__global__ void fhmm_init_counts_kernel(int* counts, int* cursor) {
    int i = threadIdx.x;
    if (i < NCC) { counts[i] = 0; cursor[i] = 0; }
}
__global__ void fhmm_hist_kernel(const int* __restrict__ w2s, int* counts) {
    int v = blockIdx.x * 256 + threadIdx.x;
    if (v < VV) atomicAdd(&counts[w2s[v * SPWW] >> 6], 1);
}
__global__ void fhmm_offsets_kernel(const int* counts, int* offsets) {
    if (threadIdx.x == 0) {
        int acc = 0;
        for (int c = 0; c < NCC; ++c) { offsets[c] = acc; acc += counts[c]; }
        offsets[NCC] = acc;
    }
}
__global__ void fhmm_scatter_kernel(const int* __restrict__ w2s, const int* offsets,
                                    int* cursor, int* wlist) {
    int v = blockIdx.x * 256 + threadIdx.x;
    if (v < VV) {
        int c = w2s[v * SPWW] >> 6;
        int pos = atomicAdd(&cursor[c], 1);
        wlist[offsets[c] + pos] = v;
    }
}

// ---------------- per-state emission lse ----------------
__global__ __launch_bounds__(64) void fhmm_lse_em_kernel(
    const float* __restrict__ Ew, const int* __restrict__ wlist,
    const int* __restrict__ counts, const int* __restrict__ offsets,
    float* __restrict__ lse_em)
{
    int c = blockIdx.x, k = threadIdx.x;
    int cnt = counts[c], off = offsets[c];
    float m = -1e30f;
    for (int i = 0; i < cnt; ++i) m = fmaxf(m, Ew[wlist[off + i] * 64 + k]);
    float s = 0.f;
    for (int i = 0; i < cnt; ++i) s += __expf(Ew[wlist[off + i] * 64 + k] - m);
    lse_em[c * 64 + k] = (cnt > 0) ? (m + logf(s)) : -1e30f;
}

// ---------------- obs2[b,t,k] (base-2 prescaled) ----------------
__global__ __launch_bounds__(64) void fhmm_obs_kernel(
    const float* __restrict__ Ew, const float* __restrict__ lse_em,
    const int* __restrict__ text, const int* __restrict__ w2s,
    float* __restrict__ obs2)
{
    int i = blockIdx.x;      // b*T + t
    int k = threadIdx.x;
    int v = text[i];
    int s = w2s[v * SPWW + k];
    obs2[i * 64 + k] = (Ew[v * 64 + k] - lse_em[s]) * LOG2E;
}

// ================= TREE COMBINE: C = A (x) B in lse2 semiring ==================
// C[i][j] = lse2_k(A[i][k] + B[k][j]) = mA[i] + mB[j] + log2( sum_k P[i][k]*Q[k][j] )
//   P = exp2(A - rowmax(A)), Q = exp2(B - colmax(B)), P,Q in bf16 via MFMA.
// MODE 0 (level 1): A,B built on the fly:
//   M_t[i][j] = pots2_{t-1}[i][j] - lse_trans2[srow_{t-1}+i] + obs2[t][j],  t=1..255
//   pair p: A=M_{2p+1}, B=M_{2p+2}; p==127 -> B=identity -> C=A (exact copy).
// MODE 1: A,B read from f32 level buffer [b][2*pairs][64][64].
template<int MODE>
__global__ __launch_bounds__(256) void fhmm_combine(
    const u16* __restrict__ potsT2, const float* __restrict__ obs2,
    const float* __restrict__ lse_trans2,
    const int* __restrict__ text, const int* __restrict__ w2s,
    const float* __restrict__ Lin, float* __restrict__ Lout, int pairs)
{
    int p = blockIdx.x, b = blockIdx.y;
    int tid = threadIdx.x;
    int l6 = tid & 63, q = tid >> 6;

    __shared__ char Ps[8192];            // P [i][k] bf16, 128B rows, swizzled
    __shared__ char Qs[8192];            // Qt [j][k] bf16
    __shared__ float mA2[64], mB2[64];   // output offsets
    __shared__ float mAf[64], mBf[64];   // maxes used inside exp2
    __shared__ float part[2][4][64];
    __shared__ float ltB_l[64];

    float va[16], vb[16];
    float ltA = 0.f, obB = 0.f;
    float* Co = Lout + ((size_t)(b * pairs + p)) * 4096;

    if (MODE == 0) {
        int tA = 2 * p + 1, tB = 2 * p + 2;
        // ---- A side: lane = i, group q covers j = q*16..q*16+15
        int i = l6;
        const u16* pA = potsT2 + ((size_t)(b * 255 + (tA - 1))) * 4096;  // [j][i]
        ltA = lse_trans2[w2s[text[b * TTT + (tA - 1)] * SPWW] + i];
        float mloc = -3e38f;
        #pragma unroll
        for (int jj = 0; jj < 16; ++jj) {
            int j = q * 16 + jj;
            float v = bf2f(pA[j * 64 + i]) + obs2[(size_t)(b * TTT + tA) * 64 + j];
            va[jj] = v; mloc = fmaxf(mloc, v);
        }
        if (tB > 255) {          // B = identity: C = M_A exactly
            #pragma unroll
            for (int jj = 0; jj < 16; ++jj)
                Co[i * 64 + q * 16 + jj] = va[jj] - ltA;
            return;
        }
        part[0][q][i] = mloc;
        // ---- stage B's lse_trans row + raw B loads
        int srowB = w2s[text[b * TTT + (tB - 1)] * SPWW];
        if (tid < 64) ltB_l[tid] = lse_trans2[srowB + tid];
        const u16* pB = potsT2 + ((size_t)(b * 255 + (tB - 1))) * 4096;  // [j][k]
        obB = obs2[(size_t)(b * TTT + tB) * 64 + l6];
        uint4 r0 = *(const uint4*)(pB + (size_t)l6 * 64 + q * 16);
        uint4 r1 = *(const uint4*)(pB + (size_t)l6 * 64 + q * 16 + 8);
        __syncthreads();
        // ---- B side values: vb[kk] = pots_B[k][j] - ltB[k],  j=l6, k=q*16+kk
        const u16* rb = (const u16*)&r0;
        float mlocB = -3e38f;
        #pragma unroll
        for (int kk = 0; kk < 8; ++kk) {
            vb[kk] = bf2f(rb[kk]) - ltB_l[q * 16 + kk];
            mlocB = fmaxf(mlocB, vb[kk]);
        }
        rb = (const u16*)&r1;
        #pragma unroll
        for (int kk = 0; kk < 8; ++kk) {
            vb[8 + kk] = bf2f(rb[kk]) - ltB_l[q * 16 + 8 + kk];
            mlocB = fmaxf(mlocB, vb[8 + kk]);
        }
        part[1][q][l6] = mlocB;
    } else {
        const float* Af = Lin + ((size_t)(b * (2 * pairs) + 2 * p)) * 4096;
        const float* Bf = Af + 4096;
        // ---- A side: lane = i, contiguous read of 16 j's
        float mloc = -3e38f;
        #pragma unroll
        for (int jj = 0; jj < 16; ++jj) {
            float v = Af[l6 * 64 + q * 16 + jj];
            va[jj] = v; mloc = fmaxf(mloc, v);
        }
        part[0][q][l6] = mloc;
        // ---- B side: lane = j, strided column reads over k
        float mlocB = -3e38f;
        #pragma unroll
        for (int kk = 0; kk < 16; ++kk) {
            float v = Bf[(q * 16 + kk) * 64 + l6];
            vb[kk] = v; mlocB = fmaxf(mlocB, v);
        }
        part[1][q][l6] = mlocB;
        __syncthreads();   // aligns with MODE 0's barrier
    }
    __syncthreads();

    // ---- finalize maxes
    if (tid < 64) {
        float mf = fmaxf(fmaxf(part[0][0][tid], part[0][1][tid]),
                         fmaxf(part[0][2][tid], part[0][3][tid]));
        mAf[tid] = mf;
        mA2[tid] = (MODE == 0) ? (mf - ltA) : mf;
    } else if (tid < 128) {
        int j = tid & 63;
        float mf = fmaxf(fmaxf(part[1][0][j], part[1][1][j]),
                         fmaxf(part[1][2][j], part[1][3][j]));
        mBf[j] = mf;
        mB2[j] = (MODE == 0) ? (mf + obB) : mf;
    }
    __syncthreads();

    // ---- write P [i][k=j] and Qt [j][k] bf16 swizzled
    {
        float ma = mAf[l6];
        ushort4 o0, o1;
        #pragma unroll
        for (int e = 0; e < 4; ++e) ((u16*)&o0)[e] = f2bf(ex2(va[e] - ma));
        #pragma unroll
        for (int e = 0; e < 4; ++e) ((u16*)&o0)[4 + e] = 0;   // placeholder
        // pack 8 bf16 into one uint4 properly:
        u16 pk[16];
        #pragma unroll
        for (int e = 0; e < 16; ++e) pk[e] = f2bf(ex2(va[e] - ma));
        uint4* src = (uint4*)pk;
        int base = l6 * 128;
        int s0 = 2 * q, s1 = 2 * q + 1, sw = (l6 & 7);
        *(uint4*)&Ps[base + (((s0 ^ sw)) << 4)] = src[0];
        *(uint4*)&Ps[base + (((s1 ^ sw)) << 4)] = src[1];
        float mb = mBf[l6];
        #pragma unroll
        for (int e = 0; e < 16; ++e) pk[e] = f2bf(ex2(vb[e] - mb));
        *(uint4*)&Qs[base + (((s0 ^ sw)) << 4)] = src[0];
        *(uint4*)&Qs[base + (((s1 ^ sw)) << 4)] = src[1];
    }
    __syncthreads();

    // ---- MFMA: S = P . Q^T(=Qs rows), C = mA2 + mB2 + log2(S)
    int w = q, lr = l6 & 15, lg = l6 >> 4;
    int brow = w * 16 + lr;
    short8 bfr[2];
    #pragma unroll
    for (int ks = 0; ks < 2; ++ks)
        bfr[ks] = *(const short8*)(Qs + brow * 128 + ((((ks * 4 + lg)) << 4) ^ ((brow & 7) << 4)));
    #pragma unroll
    for (int rm = 0; rm < 4; ++rm) {
        f32x4 acc = {0.f, 0.f, 0.f, 0.f};
        int ar = rm * 16 + lr;
        #pragma unroll
        for (int ks = 0; ks < 2; ++ks) {
            short8 af = *(const short8*)(Ps + ar * 128 + ((((ks * 4 + lg)) << 4) ^ ((ar & 7) << 4)));
            acc = __builtin_amdgcn_mfma_f32_16x16x32_bf16(af, bfr[ks], acc, 0, 0, 0);
        }
        #pragma unroll
        for (int e = 0; e < 4; ++e) {
            int ii = rm * 16 + lg * 4 + e;
            int jj = w * 16 + lr;
            Co[ii * 64 + jj] = mA2[ii] + mB2[jj] + lg2(fmaxf(acc[e], 1e-33f));
        }
    }
}

// ---------------- final: out[b] = LN2 * lse2_{i,j}( a0_2[i] + Mtot[i][j] ) ----------------
__global__ __launch_bounds__(256) void fhmm_final(
    const float* __restrict__ startv, const float* __restrict__ obs2,
    const float* __restrict__ Mtot, const int* __restrict__ text,
    const int* __restrict__ w2s, float* __restrict__ out)
{
    int b = blockIdx.x, tid = threadIdx.x;
    __shared__ float a0[64];
    __shared__ float rm_[4], rs_[4];
    if (tid < 64) {
        int s0 = w2s[text[b * TTT] * SPWW];
        a0[tid] = startv[s0 + tid] * LOG2E + obs2[(size_t)(b * TTT) * 64 + tid];
    }
    __syncthreads();
    const float* M = Mtot + (size_t)b * 4096;
    float m = -3e38f, s = 0.f;
    for (int e = tid; e < 4096; e += 256) {
        float v = a0[e >> 6] + M[e];
        float mn = fmaxf(m, v);
        s = s * ex2(m - mn) + ex2(v - mn);
        m = mn;
    }
    #pragma unroll
    for (int d = 32; d; d >>= 1) {
        float m2 = __shfl_xor(m, d), sx = __shfl_xor(s, d);
        float mn = fmaxf(m, m2);
        s = s * ex2(m - mn) + sx * ex2(m2 - mn); m = mn;
    }
    if ((tid & 63) == 0) { rm_[tid >> 6] = m; rs_[tid >> 6] = s; }
    __syncthreads();
    if (tid == 0) {
        float M_ = rm_[0], S_ = rs_[0];
        #pragma unroll
        for (int qq = 1; qq < 4; ++qq) {
            float mn = fmaxf(M_, rm_[qq]);
            S_ = S_ * ex2(M_ - mn) + rs_[qq] * ex2(rm_[qq] - mn); M_ = mn;
        }
        out[b] = (M_ + lg2(S_)) * LN2;
    }
}

extern "C" void kernel_launch(void* const* d_in, const int* in_sizes, int n_in,
                              void* d_out, int out_size, void* d_ws, size_t ws_size,
                              hipStream_t stream) {
    const int* text        = (const int*)d_in[0];
    const int* w2s         = (const int*)d_in[1];
    const float* se1_start = (const float*)d_in[2];
    const float* se2_start = (const float*)d_in[3];
    const float* start_w1  = (const float*)d_in[4];
    const float* start_b1  = (const float*)d_in[5];
    const float* start_w2  = (const float*)d_in[6];
    const float* start_b2  = (const float*)d_in[7];
    const float* start_pw  = (const float*)d_in[8];
    const float* start_pb  = (const float*)d_in[9];
    const float* se1_state = (const float*)d_in[10];
    const float* se2_state = (const float*)d_in[11];
    const float* se1_next  = (const float*)d_in[12];
    const float* se2_next  = (const float*)d_in[13];
    const float* trans_w1  = (const float*)d_in[14];
    const float* trans_b1  = (const float*)d_in[15];
    const float* trans_w2  = (const float*)d_in[16];
    const float* trans_b2  = (const float*)d_in[17];
    const float* se1_pre   = (const float*)d_in[18];
    const float* se2_pre   = (const float*)d_in[19];
    const float* term_w1   = (const float*)d_in[20];
    const float* term_b1   = (const float*)d_in[21];
    const float* term_w2   = (const float*)d_in[22];
    const float* term_b2   = (const float*)d_in[23];
    const float* term_pw   = (const float*)d_in[24];
    const float* term_pb   = (const float*)d_in[25];
    float* out = (float*)d_out;

    char* wp = (char*)d_ws;
    auto alloc = [&](size_t bytes) {
        char* p = wp;
        wp += (bytes + 255) & ~(size_t)255;
        return (void*)p;
    };
    u16* emb_bf      = (u16*)alloc((size_t)CST * HH * 2);
    u16* h1_bf       = (u16*)alloc((size_t)CST * HH * 2);
    u16* hstart_bf   = (u16*)alloc((size_t)CST * HH * 2);
    u16* h_state_bf  = (u16*)alloc((size_t)CST * HH * 2);
    u16* h_pre_bf    = (u16*)alloc((size_t)CST * HH * 2);
    u16* next_emb_bf = (u16*)alloc((size_t)CST * HH * 2);
    u16* Wt          = (u16*)alloc((size_t)6 * HH * HH * 2);
    u16* pwT         = (u16*)alloc((size_t)VV * HH * 2);
    float* startv    = (float*)alloc(CST * 4);
    float* lse_trans = (float*)alloc(CST * 4);
    float* lse_em    = (float*)alloc(CST * 4);
    float* Ew        = (float*)alloc((size_t)VV * 64 * 4);
    int* counts      = (int*)alloc(NCC * 4);
    int* offsets     = (int*)alloc((NCC + 4) * 4);
    int* cursor      = (int*)alloc(NCC * 4);
    int* wlist       = (int*)alloc(VV * 4);
    float* obs       = (float*)alloc((size_t)BBB * TTT * 64 * 4);
    u16* potsT       = (u16*)alloc((size_t)BBB * (TTT - 1) * 4096 * 2);
    float* Lv0       = (float*)alloc((size_t)BBB * 128 * 4096 * 4);
    float* Lv1       = (float*)alloc((size_t)BBB * 64 * 4096 * 4);

    // weight transposes
    const float* Ws_[6] = {start_w1, start_w2, trans_w1, trans_w2, term_w1, term_w2};
    for (int q = 0; q < 6; ++q)
        hipLaunchKernelGGL(fhmm_wtrans_kernel, dim3(4, 4), 256, 0, stream,
                           Ws_[q], Wt + (size_t)q * HH * HH);
    hipLaunchKernelGGL(fhmm_pwtrans_kernel, dim3((VV + 63) / 64, 4), 256, 0, stream,
                       term_pw, pwT);

    // class word-lists
    hipLaunchKernelGGL(fhmm_init_counts_kernel, dim3(1), 128, 0, stream, counts, cursor);
    hipLaunchKernelGGL(fhmm_hist_kernel, dim3(40), 256, 0, stream, w2s, counts);
    hipLaunchKernelGGL(fhmm_offsets_kernel, dim3(1), 64, 0, stream, counts, offsets);
    hipLaunchKernelGGL(fhmm_scatter_kernel, dim3(40), 256, 0, stream, w2s, offsets, cursor, wlist);

    // next_emb
    hipLaunchKernelGGL(fhmm_emb_bf16_kernel, dim3(8192), 256, 0, stream,
                       se1_next, se2_next, next_emb_bf);

    dim3 mmGrid(128, 4);
    // start head
    hipLaunchKernelGGL(fhmm_emb_bf16_kernel, dim3(8192), 256, 0, stream,
                       se1_start, se2_start, emb_bf);
    hipLaunchKernelGGL(fhmm_mlp_mfma, mmGrid, 256, 0, stream,
                       emb_bf, Wt + 0 * HH * HH, start_b1, (const u16*)nullptr, h1_bf);
    hipLaunchKernelGGL(fhmm_mlp_mfma, mmGrid, 256, 0, stream,
                       h1_bf, Wt + 1 * HH * HH, start_b2, emb_bf, hstart_bf);
    hipLaunchKernelGGL(fhmm_dotpw_kernel, dim3(2048), 256, 0, stream,
                       hstart_bf, start_pw, start_pb, startv);
    hipLaunchKernelGGL(fhmm_lsm_vec_kernel, dim3(1), 1024, 0, stream, startv);

    // state head
    hipLaunchKernelGGL(fhmm_emb_bf16_kernel, dim3(8192), 256, 0, stream,
                       se1_state, se2_state, emb_bf);
    hipLaunchKernelGGL(fhmm_mlp_mfma, mmGrid, 256, 0, stream,
                       emb_bf, Wt + 2 * HH * HH, trans_b1, (const u16*)nullptr, h1_bf);
    hipLaunchKernelGGL(fhmm_mlp_mfma, mmGrid, 256, 0, stream,
                       h1_bf, Wt + 3 * HH * HH, trans_b2, emb_bf, h_state_bf);

    // pre head
    hipLaunchKernelGGL(fhmm_emb_bf16_kernel, dim3(8192), 256, 0, stream,
                       se1_pre, se2_pre, emb_bf);
    hipLaunchKernelGGL(fhmm_mlp_mfma, mmGrid, 256, 0, stream,
                       emb_bf, Wt + 4 * HH * HH, term_b1, (const u16*)nullptr, h1_bf);
    hipLaunchKernelGGL(fhmm_mlp_mfma, mmGrid, 256, 0, stream,
                       h1_bf, Wt + 5 * HH * HH, term_b2, emb_bf, h_pre_bf);

    // transition row-lse + pots (base-2 prescaled outputs)
    hipLaunchKernelGGL(fhmm_trans_lse_mfma, dim3(256), 256, 0, stream,
                       h_state_bf, next_emb_bf, lse_trans);
    hipLaunchKernelGGL(fhmm_pots_mfma, dim3(BBB * (TTT - 1)), 256, 0, stream,
                       h_state_bf, next_emb_bf, text, w2s, potsT);

    // emission
    hipLaunchKernelGGL(fhmm_ew_mfma, dim3(NCC), 256, 0, stream,
                       h_pre_bf, pwT, term_pb, wlist, counts, offsets, Ew);
    hipLaunchKernelGGL(fhmm_lse_em_kernel, dim3(NCC), 64, 0, stream,
                       Ew, wlist, counts, offsets, lse_em);
    hipLaunchKernelGGL(fhmm_obs_kernel, dim3(BBB * TTT), 64, 0, stream,
                       Ew, lse_em, text, w2s, obs);

    // ---- tree reduction over transition matrices ----
    hipLaunchKernelGGL((fhmm_combine<0>), dim3(128, BBB), 256, 0, stream,
                       potsT, obs, lse_trans, text, w2s,
                       (const float*)nullptr, Lv0, 128);
    float* cin = Lv0;
    const int lv_sizes[7] = {64, 32, 16, 8, 4, 2, 1};
    for (int li = 0; li < 7; ++li) {
        float* cout = (cin == Lv0) ? Lv1 : Lv0;
        hipLaunchKernelGGL((fhmm_combine<1>), dim3(lv_sizes[li], BBB), 256, 0, stream,
                           (const u16*)nullptr, (const float*)nullptr,
                           (const float*)nullptr, (const int*)nullptr,
                           (const int*)nullptr, cin, cout, lv_sizes[li]);
        cin = cout;
    }

    // ---- final apply + lse ----
    hipLaunchKernelGGL(fhmm_final, dim3(BBB), 256, 0, stream,
                       startv, obs, cin, text, w2s, out);
}

// Round 6
// 315.016 us; speedup vs baseline: 1.8200x; 1.1387x over previous
//
#include <hip/hip_runtime.h>
#include <hip/hip_bf16.h>
#include <math.h>

#define HH 256
#define NCC 128
#define SPWW 64
#define CST 8192
#define VV 10000
#define BBB 16
#define TTT 256
#define LOG2E 1.4426950408889634f
#define LN2 0.6931471805599453f

typedef __attribute__((ext_vector_type(8))) short short8;
typedef __attribute__((ext_vector_type(4))) float f32x4;
typedef unsigned short u16;

__device__ inline float bf2f(u16 u) {
    union { unsigned int i; float f; } v; v.i = ((unsigned int)u) << 16; return v.f;
}
__device__ inline u16 f2bf(float f) {
    __hip_bfloat16 h = __float2bfloat16(f);
    return *reinterpret_cast<u16*>(&h);
}
__device__ inline float ex2(float x) { return __builtin_amdgcn_exp2f(x); }
__device__ inline float lg2(float x) { return __builtin_amdgcn_logf(x); }

// ---------------- embeddings (bf16 out) ----------------
__global__ __launch_bounds__(256) void fhmm_emb_bf16_kernel(
    const float* __restrict__ e1, const float* __restrict__ e2,
    u16* __restrict__ out)
{
    int idx = blockIdx.x * 256 + threadIdx.x;   // over 8192*256
    int s = idx >> 8, h = idx & 255;
    out[idx] = f2bf(e1[(s >> 6) * HH + h] + e2[(s & 63) * HH + h]);
}

// ---------------- weight transpose 256x256: Wt[n][k] = bf16(W[k][n]) ----------------
__global__ __launch_bounds__(256) void fhmm_wtrans_kernel(
    const float* __restrict__ W, u16* __restrict__ Wt)
{
    __shared__ float t[64][65];
    int k0 = blockIdx.x * 64, n0 = blockIdx.y * 64, tid = threadIdx.x;
    #pragma unroll
    for (int i = 0; i < 16; ++i) {
        int idx = tid + i * 256; int r = idx >> 6, c = idx & 63;
        t[r][c] = W[(k0 + r) * HH + n0 + c];
    }
    __syncthreads();
    #pragma unroll
    for (int i = 0; i < 16; ++i) {
        int idx = tid + i * 256; int r = idx >> 6, c = idx & 63;
        Wt[(n0 + r) * HH + k0 + c] = f2bf(t[c][r]);
    }
}

// ---------------- pw transpose: pwT[v][k] = bf16(pw[k][v]) ----------------
__global__ __launch_bounds__(256) void fhmm_pwtrans_kernel(
    const float* __restrict__ pw, u16* __restrict__ pwT)
{
    __shared__ float t[64][65];
    int v0 = blockIdx.x * 64, k0 = blockIdx.y * 64, tid = threadIdx.x;
    #pragma unroll
    for (int i = 0; i < 16; ++i) {
        int idx = tid + i * 256; int r = idx >> 6, c = idx & 63;   // r:k, c:v
        int v = v0 + c;
        t[r][c] = (v < VV) ? pw[(size_t)(k0 + r) * VV + v] : 0.f;
    }
    __syncthreads();
    #pragma unroll
    for (int i = 0; i < 16; ++i) {
        int idx = tid + i * 256; int r = idx >> 6, c = idx & 63;   // r:v, c:k
        int v = v0 + r;
        if (v < VV) pwT[(size_t)v * HH + k0 + c] = f2bf(t[c][r]);
    }
}

// ---------------- MFMA MLP layer: Y = relu(X@W + b) [+ res], all bf16 I/O ----------------
__global__ __launch_bounds__(256) void fhmm_mlp_mfma(
    const u16* __restrict__ Xbf, const u16* __restrict__ Wt,
    const float* __restrict__ bias, const u16* __restrict__ resbf,
    u16* __restrict__ Ybf)
{
    int m0 = blockIdx.x * 64, n0 = blockIdx.y * 64;
    __shared__ char Xs[32768];
    __shared__ char Ws[32768];
    int tid = threadIdx.x, w = tid >> 6, lane = tid & 63, lr = lane & 15, lg = lane >> 4;
    const char* xsrc = (const char*)(Xbf + (size_t)m0 * HH);
    const char* wsrc = (const char*)(Wt + (size_t)n0 * HH);
    #pragma unroll
    for (int i = 0; i < 8; ++i) {
        int cc = i * 256 + tid; int row = cc >> 5, tt = cc & 31;
        int dst = row * 512 + ((tt ^ (row & 7)) << 4);
        *(uint4*)&Xs[dst] = *(const uint4*)(xsrc + cc * 16);
        *(uint4*)&Ws[dst] = *(const uint4*)(wsrc + cc * 16);
    }
    __syncthreads();
    short8 bfr[8];
    int brow = w * 16 + lr, bb = brow * 512, bsw = (brow & 7) << 4;
    #pragma unroll
    for (int ks = 0; ks < 8; ++ks)
        bfr[ks] = *(const short8*)(Ws + bb + (((ks * 4 + lg) << 4) ^ bsw));
    int cb = w * 16 + lg * 4;
    f32x4 bv = *(const f32x4*)(bias + n0 + cb);
    #pragma unroll
    for (int rm = 0; rm < 4; ++rm) {
        f32x4 acc = {0.f, 0.f, 0.f, 0.f};
        int ar = rm * 16 + lr, ab = ar * 512, asw = (ar & 7) << 4;
        #pragma unroll
        for (int ks = 0; ks < 8; ++ks) {
            short8 af = *(const short8*)(Xs + ab + (((ks * 4 + lg) << 4) ^ asw));
            acc = __builtin_amdgcn_mfma_f32_16x16x32_bf16(bfr[ks], af, acc, 0, 0, 0);
        }
        int gm = m0 + rm * 16 + lr;
        ushort4 o;
        if (resbf) {
            const u16* rp = resbf + (size_t)gm * HH + n0 + cb;
            #pragma unroll
            for (int e = 0; e < 4; ++e)
                ((u16*)&o)[e] = f2bf(fmaxf(acc[e] + bv[e], 0.f) + bf2f(rp[e]));
        } else {
            #pragma unroll
            for (int e = 0; e < 4; ++e)
                ((u16*)&o)[e] = f2bf(fmaxf(acc[e] + bv[e], 0.f));
        }
        *(ushort4*)(Ybf + (size_t)gm * HH + n0 + cb) = o;
    }
}

// ---------------- start head: dot with pw (bf16 h) ----------------
__global__ __launch_bounds__(256) void fhmm_dotpw_kernel(
    const u16* __restrict__ hb, const float* __restrict__ pw,
    const float* __restrict__ pbp, float* __restrict__ p)
{
    int wv = threadIdx.x >> 6;
    int lane = threadIdx.x & 63;
    int s = blockIdx.x * 4 + wv;
    const u16* hr = hb + (size_t)s * HH;
    float acc = 0.f;
    #pragma unroll
    for (int i = 0; i < 4; ++i) acc += bf2f(hr[i * 64 + lane]) * pw[i * 64 + lane];
    #pragma unroll
    for (int d = 32; d; d >>= 1) acc += __shfl_xor(acc, d);
    if (lane == 0) p[s] = acc + pbp[0];
}

// ---------------- in-place log_softmax over a length-8192 vector ----------------
__global__ __launch_bounds__(1024) void fhmm_lsm_vec_kernel(float* __restrict__ p)
{
    __shared__ float red[64];
    int tid = threadIdx.x;
    float m = -1e30f;
    for (int i = tid; i < CST; i += 1024) m = fmaxf(m, p[i]);
    #pragma unroll
    for (int d = 32; d; d >>= 1) m = fmaxf(m, __shfl_xor(m, d));
    if ((tid & 63) == 0) red[tid >> 6] = m;
    __syncthreads();
    if (tid == 0) {
        float mm = red[0];
        for (int q = 1; q < 16; ++q) mm = fmaxf(mm, red[q]);
        red[32] = mm;
    }
    __syncthreads();
    float M = red[32];
    float s = 0.f;
    for (int i = tid; i < CST; i += 1024) s += expf(p[i] - M);
    #pragma unroll
    for (int d = 32; d; d >>= 1) s += __shfl_xor(s, d);
    if ((tid & 63) == 0) red[tid >> 6] = s;
    __syncthreads();
    if (tid == 0) {
        float ss = 0.f;
        for (int q = 0; q < 16; ++q) ss += red[q];
        red[33] = ss;
    }
    __syncthreads();
    float lse = M + logf(red[33]);
    for (int i = tid; i < CST; i += 1024) p[i] -= lse;
}

// ---------------- transition row-lse: direct-from-L2, barrier-free ----------------
// Block: 64 A-rows (regs) x 2048-col quarter. Wave w walks its own 16-col tiles,
// B frags loaded global->reg (L2-resident, no LDS, no barriers). Partial (m,s)
// per (col-quarter, row) written out; tiny combine kernel merges 4 quarters.
__global__ __launch_bounds__(256) void fhmm_trans_lse_direct(
    const u16* __restrict__ Abf,   // h_state bf16 [8192][256]
    const u16* __restrict__ Bbf,   // next_emb bf16 [8192][256]
    float* __restrict__ pm, float* __restrict__ ps)
{
    int r0 = blockIdx.x * 64;
    int cq = blockIdx.y;           // col quarter (2048 cols)
    int tid = threadIdx.x, w = tid >> 6, lane = tid & 63;
    int lr = lane & 15, lg = lane >> 4;

    // A fragments in registers for the whole kernel (64 rows x K=256)
    short8 afr[4][8];
    #pragma unroll
    for (int rm = 0; rm < 4; ++rm)
        #pragma unroll
        for (int ks = 0; ks < 8; ++ks)
            afr[rm][ks] = *reinterpret_cast<const short8*>(
                Abf + (size_t)(r0 + rm * 16 + lr) * HH + ks * 32 + lg * 8);

    float m[4], s[4];
    #pragma unroll
    for (int rm = 0; rm < 4; ++rm) { m[rm] = -3e38f; s[rm] = 0.f; }

    // wave w cols: cq*2048 + it*64 + w*16 ; this lane's B-row = +lr
    const u16* Bp = Bbf + (size_t)(cq * 2048 + w * 16 + lr) * HH + lg * 8;
    short8 bcur[8], bnxt[8];
    #pragma unroll
    for (int ks = 0; ks < 8; ++ks)
        bcur[ks] = *reinterpret_cast<const short8*>(Bp + ks * 32);

    for (int it = 0; it < 32; ++it) {
        if (it < 31) {
            const u16* Bn = Bp + (size_t)(it + 1) * 64 * HH;
            #pragma unroll
            for (int ks = 0; ks < 8; ++ks)
                bnxt[ks] = *reinterpret_cast<const short8*>(Bn + ks * 32);
        }
        f32x4 acc[4];
        #pragma unroll
        for (int rm = 0; rm < 4; ++rm) acc[rm] = (f32x4){0.f, 0.f, 0.f, 0.f};
        #pragma unroll
        for (int ks = 0; ks < 8; ++ks) {
            #pragma unroll
            for (int rm = 0; rm < 4; ++rm)
                acc[rm] = __builtin_amdgcn_mfma_f32_16x16x32_bf16(
                    bcur[ks], afr[rm][ks], acc[rm], 0, 0, 0);
        }
        // online lse: lane holds rows rm*16+lr, 4 cols each
        #pragma unroll
        for (int rm = 0; rm < 4; ++rm) {
            float lm = fmaxf(fmaxf(acc[rm][0], acc[rm][1]),
                             fmaxf(acc[rm][2], acc[rm][3]));
            float mn = fmaxf(m[rm], lm);
            s[rm] = s[rm] * __expf(m[rm] - mn)
                  + __expf(acc[rm][0] - mn) + __expf(acc[rm][1] - mn)
                  + __expf(acc[rm][2] - mn) + __expf(acc[rm][3] - mn);
            m[rm] = mn;
        }
        #pragma unroll
        for (int ks = 0; ks < 8; ++ks) bcur[ks] = bnxt[ks];
    }

    // combine across lg groups (lane bits 4,5)
    #pragma unroll
    for (int rm = 0; rm < 4; ++rm) {
        #pragma unroll
        for (int d = 16; d < 64; d <<= 1) {
            float m2 = __shfl_xor(m[rm], d), sx = __shfl_xor(s[rm], d);
            float mn = fmaxf(m[rm], m2);
            s[rm] = s[rm] * __expf(m[rm] - mn) + sx * __expf(m2 - mn);
            m[rm] = mn;
        }
    }
    __shared__ float lm_[4][64], ls_[4][64];
    if (lane < 16) {
        #pragma unroll
        for (int rm = 0; rm < 4; ++rm) {
            lm_[w][rm * 16 + lane] = m[rm];
            ls_[w][rm * 16 + lane] = s[rm];
        }
    }
    __syncthreads();
    if (tid < 64) {
        float M = lm_[0][tid], S = ls_[0][tid];
        #pragma unroll
        for (int q = 1; q < 4; ++q) {
            float m2 = lm_[q][tid], sx = ls_[q][tid];
            float mn = fmaxf(M, m2);
            S = S * __expf(M - mn) + sx * __expf(m2 - mn); M = mn;
        }
        pm[(size_t)cq * CST + r0 + tid] = M;
        ps[(size_t)cq * CST + r0 + tid] = S;
    }
}

__global__ __launch_bounds__(256) void fhmm_trans_lse_combine(
    const float* __restrict__ pm, const float* __restrict__ ps,
    float* __restrict__ lse2)
{
    int r = blockIdx.x * 256 + threadIdx.x;
    float M = pm[r], S = ps[r];
    #pragma unroll
    for (int q = 1; q < 4; ++q) {
        float m2 = pm[(size_t)q * CST + r], sx = ps[(size_t)q * CST + r];
        float mn = fmaxf(M, m2);
        S = S * __expf(M - mn) + sx * __expf(m2 - mn); M = mn;
    }
    lse2[r] = (M + logf(S)) * LOG2E;
}

// ---------------- per-(b,t) 64x64 transition-logit blocks, TRANSPOSED bf16 out ----------------
// potsT2[blk][j][i] = logits[i][j] * log2e
__global__ __launch_bounds__(256) void fhmm_pots_mfma(
    const u16* __restrict__ Abf, const u16* __restrict__ Bbf,
    const int* __restrict__ text, const int* __restrict__ w2s,
    u16* __restrict__ potsT2)
{
    int blk = blockIdx.x;              // b*255 + t
    int b = blk / (TTT - 1), t = blk % (TTT - 1);
    int sr = w2s[text[b * TTT + t] * SPWW];
    int sc = w2s[text[b * TTT + t + 1] * SPWW];
    __shared__ char As_[32768];
    __shared__ char Bs_[32768];
    int tid = threadIdx.x;
    int w = tid >> 6, lane = tid & 63;
    int lr = lane & 15, lg = lane >> 4;

    const char* Asrc = reinterpret_cast<const char*>(Abf + (size_t)sr * HH);
    const char* Bsrc = reinterpret_cast<const char*>(Bbf + (size_t)sc * HH);
    #pragma unroll
    for (int i = 0; i < 8; ++i) {
        int c = i * 256 + tid;
        int row = c >> 5, tt = c & 31;
        int dst = row * 512 + ((tt ^ (row & 7)) << 4);
        *reinterpret_cast<uint4*>(&As_[dst]) = *reinterpret_cast<const uint4*>(Asrc + c * 16);
        *reinterpret_cast<uint4*>(&Bs_[dst]) = *reinterpret_cast<const uint4*>(Bsrc + c * 16);
    }
    __syncthreads();

    short8 bfr[8];
    int brow = w * 16 + lr;
    int bbase = brow * 512;
    int bswz = (brow & 7) << 4;
    #pragma unroll
    for (int ks = 0; ks < 8; ++ks)
        bfr[ks] = *reinterpret_cast<const short8*>(
            Bs_ + bbase + (((ks * 4 + lg) << 4) ^ bswz));

    u16* op = potsT2 + (size_t)blk * 4096;
    #pragma unroll
    for (int rm = 0; rm < 4; ++rm) {
        f32x4 acc = {0.f, 0.f, 0.f, 0.f};
        int arow = rm * 16 + lr;
        int abase = arow * 512;
        int aswz = (arow & 7) << 4;
        #pragma unroll
        for (int ks = 0; ks < 8; ++ks) {
            short8 af = *reinterpret_cast<const short8*>(
                As_ + abase + (((ks * 4 + lg) << 4) ^ aswz));
            acc = __builtin_amdgcn_mfma_f32_16x16x32_bf16(af, bfr[ks], acc, 0, 0, 0);
        }
        ushort4 o;
        #pragma unroll
        for (int e = 0; e < 4; ++e) ((u16*)&o)[e] = f2bf(acc[e] * LOG2E);
        *(ushort4*)(op + (size_t)(w * 16 + lr) * 64 + rm * 16 + lg * 4) = o;
    }
}

// ---------------- per-class emission GEMM: Ew[v][k] = H_c @ pwT[v] + pb[v] ----------------
__global__ __launch_bounds__(256) void fhmm_ew_mfma(
    const u16* __restrict__ hpre_bf, const u16* __restrict__ pwT,
    const float* __restrict__ pb, const int* __restrict__ wlist,
    const int* __restrict__ counts, const int* __restrict__ offsets,
    float* __restrict__ Ew)
{
    int c = blockIdx.x;
    int cnt = counts[c], off = offsets[c];
    __shared__ char Hs[32768];
    int tid = threadIdx.x, w = tid >> 6, lane = tid & 63, lr = lane & 15, lg = lane >> 4;
    const char* src = (const char*)(hpre_bf + (size_t)c * 64 * HH);
    #pragma unroll
    for (int i = 0; i < 8; ++i) {
        int cc = i * 256 + tid; int row = cc >> 5, tt = cc & 31;
        *(uint4*)&Hs[row * 512 + ((tt ^ (row & 7)) << 4)] = *(const uint4*)(src + cc * 16);
    }
    __syncthreads();
    for (int ch = 0; ch * 64 < cnt; ++ch) {
        int widx = ch * 64 + w * 16 + lr;
        bool valid = widx < cnt;
        int v = valid ? wlist[off + widx] : 0;
        short8 bw[8];
        short8 bz = {0, 0, 0, 0, 0, 0, 0, 0};
        #pragma unroll
        for (int ks = 0; ks < 8; ++ks)
            bw[ks] = valid ? *(const short8*)(pwT + (size_t)v * HH + ks * 32 + lg * 8) : bz;
        float pbv = valid ? pb[v] : 0.f;
        #pragma unroll
        for (int rm = 0; rm < 4; ++rm) {
            f32x4 acc = {0.f, 0.f, 0.f, 0.f};
            int ar = rm * 16 + lr, ab = ar * 512, asw = (ar & 7) << 4;
            #pragma unroll
            for (int ks = 0; ks < 8; ++ks) {
                short8 ah = *(const short8*)(Hs + ab + (((ks * 4 + lg) << 4) ^ asw));
                acc = __builtin_amdgcn_mfma_f32_16x16x32_bf16(ah, bw[ks], acc, 0, 0, 0);
            }
            if (valid) {
                f32x4 o;
                #pragma unroll
                for (int e = 0; e < 4; ++e) o[e] = acc[e] + pbv;
                *(f32x4*)(Ew + (size_t)v * 64 + rm * 16 + lg * 4) = o;
            }
        }
    }
}

// ---------------- class word-lists ----------------
__global__ void fhmm_init_counts_kernel(int* counts, int* cursor) {
    int i = threadIdx.x;
    if (i < NCC) { counts[i] = 0; cursor[i] = 0; }
}
__global__ void fhmm_hist_kernel(const int* __restrict__ w2s, int* counts) {
    int v = blockIdx.x * 256 + threadIdx.x;
    if (v < VV) atomicAdd(&counts[w2s[v * SPWW] >> 6], 1);
}
__global__ void fhmm_offsets_kernel(const int* counts, int* offsets) {
    if (threadIdx.x == 0) {
        int acc = 0;
        for (int c = 0; c < NCC; ++c) { offsets[c] = acc; acc += counts[c]; }
        offsets[NCC] = acc;
    }
}
__global__ void fhmm_scatter_kernel(const int* __restrict__ w2s, const int* offsets,
                                    int* cursor, int* wlist) {
    int v = blockIdx.x * 256 + threadIdx.x;
    if (v < VV) {
        int c = w2s[v * SPWW] >> 6;
        int pos = atomicAdd(&cursor[c], 1);
        wlist[offsets[c] + pos] = v;
    }
}

// ---------------- per-state emission lse ----------------
__global__ __launch_bounds__(64) void fhmm_lse_em_kernel(
    const float* __restrict__ Ew, const int* __restrict__ wlist,
    const int* __restrict__ counts, const int* __restrict__ offsets,
    float* __restrict__ lse_em)
{
    int c = blockIdx.x, k = threadIdx.x;
    int cnt = counts[c], off = offsets[c];
    float m = -1e30f;
    for (int i = 0; i < cnt; ++i) m = fmaxf(m, Ew[wlist[off + i] * 64 + k]);
    float s = 0.f;
    for (int i = 0; i < cnt; ++i) s += __expf(Ew[wlist[off + i] * 64 + k] - m);
    lse_em[c * 64 + k] = (cnt > 0) ? (m + logf(s)) : -1e30f;
}

// ---------------- obs2[b,t,k] (base-2 prescaled) ----------------
__global__ __launch_bounds__(64) void fhmm_obs_kernel(
    const float* __restrict__ Ew, const float* __restrict__ lse_em,
    const int* __restrict__ text, const int* __restrict__ w2s,
    float* __restrict__ obs2)
{
    int i = blockIdx.x;      // b*T + t
    int k = threadIdx.x;
    int v = text[i];
    int s = w2s[v * SPWW + k];
    obs2[i * 64 + k] = (Ew[v * 64 + k] - lse_em[s]) * LOG2E;
}

// ================= TREE COMBINE: C = A (x) B in lse2 semiring ==================
template<int MODE>
__global__ __launch_bounds__(256) void fhmm_combine(
    const u16* __restrict__ potsT2, const float* __restrict__ obs2,
    const float* __restrict__ lse_trans2,
    const int* __restrict__ text, const int* __restrict__ w2s,
    const float* __restrict__ Lin, float* __restrict__ Lout, int pairs)
{
    int p = blockIdx.x, b = blockIdx.y;
    int tid = threadIdx.x;
    int l6 = tid & 63, q = tid >> 6;

    __shared__ char Ps[8192];            // P [i][k] bf16, 128B rows, swizzled
    __shared__ char Qs[8192];            // Qt [j][k] bf16
    __shared__ float mA2[64], mB2[64];   // output offsets
    __shared__ float mAf[64], mBf[64];   // maxes used inside exp2
    __shared__ float part[2][4][64];
    __shared__ float ltB_l[64];

    float va[16], vb[16];
    float ltA = 0.f, obB = 0.f;
    float* Co = Lout + ((size_t)(b * pairs + p)) * 4096;

    if (MODE == 0) {
        int tA = 2 * p + 1, tB = 2 * p + 2;
        int i = l6;
        const u16* pA = potsT2 + ((size_t)(b * 255 + (tA - 1))) * 4096;  // [j][i]
        ltA = lse_trans2[w2s[text[b * TTT + (tA - 1)] * SPWW] + i];
        float mloc = -3e38f;
        #pragma unroll
        for (int jj = 0; jj < 16; ++jj) {
            int j = q * 16 + jj;
            float v = bf2f(pA[j * 64 + i]) + obs2[(size_t)(b * TTT + tA) * 64 + j];
            va[jj] = v; mloc = fmaxf(mloc, v);
        }
        if (tB > 255) {          // B = identity: C = M_A exactly
            #pragma unroll
            for (int jj = 0; jj < 16; ++jj)
                Co[i * 64 + q * 16 + jj] = va[jj] - ltA;
            return;
        }
        part[0][q][i] = mloc;
        int srowB = w2s[text[b * TTT + (tB - 1)] * SPWW];
        if (tid < 64) ltB_l[tid] = lse_trans2[srowB + tid];
        const u16* pB = potsT2 + ((size_t)(b * 255 + (tB - 1))) * 4096;  // [j][k]
        obB = obs2[(size_t)(b * TTT + tB) * 64 + l6];
        uint4 r0 = *(const uint4*)(pB + (size_t)l6 * 64 + q * 16);
        uint4 r1 = *(const uint4*)(pB + (size_t)l6 * 64 + q * 16 + 8);
        __syncthreads();
        const u16* rb = (const u16*)&r0;
        float mlocB = -3e38f;
        #pragma unroll
        for (int kk = 0; kk < 8; ++kk) {
            vb[kk] = bf2f(rb[kk]) - ltB_l[q * 16 + kk];
            mlocB = fmaxf(mlocB, vb[kk]);
        }
        rb = (const u16*)&r1;
        #pragma unroll
        for (int kk = 0; kk < 8; ++kk) {
            vb[8 + kk] = bf2f(rb[kk]) - ltB_l[q * 16 + 8 + kk];
            mlocB = fmaxf(mlocB, vb[8 + kk]);
        }
        part[1][q][l6] = mlocB;
    } else {
        const float* Af = Lin + ((size_t)(b * (2 * pairs) + 2 * p)) * 4096;
        const float* Bf = Af + 4096;
        float mloc = -3e38f;
        #pragma unroll
        for (int jj = 0; jj < 16; ++jj) {
            float v = Af[l6 * 64 + q * 16 + jj];
            va[jj] = v; mloc = fmaxf(mloc, v);
        }
        part[0][q][l6] = mloc;
        float mlocB = -3e38f;
        #pragma unroll
        for (int kk = 0; kk < 16; ++kk) {
            float v = Bf[(q * 16 + kk) * 64 + l6];
            vb[kk] = v; mlocB = fmaxf(mlocB, v);
        }
        part[1][q][l6] = mlocB;
        __syncthreads();
    }
    __syncthreads();

    if (tid < 64) {
        float mf = fmaxf(fmaxf(part[0][0][tid], part[0][1][tid]),
                         fmaxf(part[0][2][tid], part[0][3][tid]));
        mAf[tid] = mf;
        mA2[tid] = (MODE == 0) ? (mf - ltA) : mf;
    } else if (tid < 128) {
        int j = tid & 63;
        float mf = fmaxf(fmaxf(part[1][0][j], part[1][1][j]),
                         fmaxf(part[1][2][j], part[1][3][j]));
        mBf[j] = mf;
        mB2[j] = (MODE == 0) ? (mf + obB) : mf;
    }
    __syncthreads();

    {
        float ma = mAf[l6];
        u16 pk[16];
        #pragma unroll
        for (int e = 0; e < 16; ++e) pk[e] = f2bf(ex2(va[e] - ma));
        uint4* src = (uint4*)pk;
        int base = l6 * 128;
        int s0 = 2 * q, s1 = 2 * q + 1, sw = (l6 & 7);
        *(uint4*)&Ps[base + (((s0 ^ sw)) << 4)] = src[0];
        *(uint4*)&Ps[base + (((s1 ^ sw)) << 4)] = src[1];
        float mb = mBf[l6];
        #pragma unroll
        for (int e = 0; e < 16; ++e) pk[e] = f2bf(ex2(vb[e] - mb));
        *(uint4*)&Qs[base + (((s0 ^ sw)) << 4)] = src[0];
        *(uint4*)&Qs[base + (((s1 ^ sw)) << 4)] = src[1];
    }
    __syncthreads();

    int w = q, lr = l6 & 15, lg = l6 >> 4;
    int brow = w * 16 + lr;
    short8 bfr[2];
    #pragma unroll
    for (int ks = 0; ks < 2; ++ks)
        bfr[ks] = *(const short8*)(Qs + brow * 128 + ((((ks * 4 + lg)) << 4) ^ ((brow & 7) << 4)));
    #pragma unroll
    for (int rm = 0; rm < 4; ++rm) {
        f32x4 acc = {0.f, 0.f, 0.f, 0.f};
        int ar = rm * 16 + lr;
        #pragma unroll
        for (int ks = 0; ks < 2; ++ks) {
            short8 af = *(const short8*)(Ps + ar * 128 + ((((ks * 4 + lg)) << 4) ^ ((ar & 7) << 4)));
            acc = __builtin_amdgcn_mfma_f32_16x16x32_bf16(af, bfr[ks], acc, 0, 0, 0);
        }
        #pragma unroll
        for (int e = 0; e < 4; ++e) {
            int ii = rm * 16 + lg * 4 + e;
            int jj = w * 16 + lr;
            Co[ii * 64 + jj] = mA2[ii] + mB2[jj] + lg2(fmaxf(acc[e], 1e-33f));
        }
    }
}

// ---------------- final: out[b] = LN2 * lse2_{i,j}( a0_2[i] + Mtot[i][j] ) ----------------
__global__ __launch_bounds__(256) void fhmm_final(
    const float* __restrict__ startv, const float* __restrict__ obs2,
    const float* __restrict__ Mtot, const int* __restrict__ text,
    const int* __restrict__ w2s, float* __restrict__ out)
{
    int b = blockIdx.x, tid = threadIdx.x;
    __shared__ float a0[64];
    __shared__ float rm_[4], rs_[4];
    if (tid < 64) {
        int s0 = w2s[text[b * TTT] * SPWW];
        a0[tid] = startv[s0 + tid] * LOG2E + obs2[(size_t)(b * TTT) * 64 + tid];
    }
    __syncthreads();
    const float* M = Mtot + (size_t)b * 4096;
    float m = -3e38f, s = 0.f;
    for (int e = tid; e < 4096; e += 256) {
        float v = a0[e >> 6] + M[e];
        float mn = fmaxf(m, v);
        s = s * ex2(m - mn) + ex2(v - mn);
        m = mn;
    }
    #pragma unroll
    for (int d = 32; d; d >>= 1) {
        float m2 = __shfl_xor(m, d), sx = __shfl_xor(s, d);
        float mn = fmaxf(m, m2);
        s = s * ex2(m - mn) + sx * ex2(m2 - mn); m = mn;
    }
    if ((tid & 63) == 0) { rm_[tid >> 6] = m; rs_[tid >> 6] = s; }
    __syncthreads();
    if (tid == 0) {
        float M_ = rm_[0], S_ = rs_[0];
        #pragma unroll
        for (int qq = 1; qq < 4; ++qq) {
            float mn = fmaxf(M_, rm_[qq]);
            S_ = S_ * ex2(M_ - mn) + rs_[qq] * ex2(rm_[qq] - mn); M_ = mn;
        }
        out[b] = (M_ + lg2(S_)) * LN2;
    }
}

extern "C" void kernel_launch(void* const* d_in, const int* in_sizes, int n_in,
                              void* d_out, int out_size, void* d_ws, size_t ws_size,
                              hipStream_t stream) {
    const int* text        = (const int*)d_in[0];
    const int* w2s         = (const int*)d_in[1];
    const float* se1_start = (const float*)d_in[2];
    const float* se2_start = (const float*)d_in[3];
    const float* start_w1  = (const float*)d_in[4];
    const float* start_b1  = (const float*)d_in[5];
    const float* start_w2  = (const float*)d_in[6];
    const float* start_b2  = (const float*)d_in[7];
    const float* start_pw  = (const float*)d_in[8];
    const float* start_pb  = (const float*)d_in[9];
    const float* se1_state = (const float*)d_in[10];
    const float* se2_state = (const float*)d_in[11];
    const float* se1_next  = (const float*)d_in[12];
    const float* se2_next  = (const float*)d_in[13];
    const float* trans_w1  = (const float*)d_in[14];
    const float* trans_b1  = (const float*)d_in[15];
    const float* trans_w2  = (const float*)d_in[16];
    const float* trans_b2  = (const float*)d_in[17];
    const float* se1_pre   = (const float*)d_in[18];
    const float* se2_pre   = (const float*)d_in[19];
    const float* term_w1   = (const float*)d_in[20];
    const float* term_b1   = (const float*)d_in[21];
    const float* term_w2   = (const float*)d_in[22];
    const float* term_b2   = (const float*)d_in[23];
    const float* term_pw   = (const float*)d_in[24];
    const float* term_pb   = (const float*)d_in[25];
    float* out = (float*)d_out;

    char* wp = (char*)d_ws;
    auto alloc = [&](size_t bytes) {
        char* p = wp;
        wp += (bytes + 255) & ~(size_t)255;
        return (void*)p;
    };
    u16* emb_bf      = (u16*)alloc((size_t)CST * HH * 2);
    u16* h1_bf       = (u16*)alloc((size_t)CST * HH * 2);
    u16* hstart_bf   = (u16*)alloc((size_t)CST * HH * 2);
    u16* h_state_bf  = (u16*)alloc((size_t)CST * HH * 2);
    u16* h_pre_bf    = (u16*)alloc((size_t)CST * HH * 2);
    u16* next_emb_bf = (u16*)alloc((size_t)CST * HH * 2);
    u16* Wt          = (u16*)alloc((size_t)6 * HH * HH * 2);
    u16* pwT         = (u16*)alloc((size_t)VV * HH * 2);
    float* startv    = (float*)alloc(CST * 4);
    float* lse_trans = (float*)alloc(CST * 4);
    float* pm        = (float*)alloc((size_t)4 * CST * 4);
    float* ps        = (float*)alloc((size_t)4 * CST * 4);
    float* lse_em    = (float*)alloc(CST * 4);
    float* Ew        = (float*)alloc((size_t)VV * 64 * 4);
    int* counts      = (int*)alloc(NCC * 4);
    int* offsets     = (int*)alloc((NCC + 4) * 4);
    int* cursor      = (int*)alloc(NCC * 4);
    int* wlist       = (int*)alloc(VV * 4);
    float* obs       = (float*)alloc((size_t)BBB * TTT * 64 * 4);
    u16* potsT       = (u16*)alloc((size_t)BBB * (TTT - 1) * 4096 * 2);
    float* Lv0       = (float*)alloc((size_t)BBB * 128 * 4096 * 4);
    float* Lv1       = (float*)alloc((size_t)BBB * 64 * 4096 * 4);

    // weight transposes
    const float* Ws_[6] = {start_w1, start_w2, trans_w1, trans_w2, term_w1, term_w2};
    for (int q = 0; q < 6; ++q)
        hipLaunchKernelGGL(fhmm_wtrans_kernel, dim3(4, 4), 256, 0, stream,
                           Ws_[q], Wt + (size_t)q * HH * HH);
    hipLaunchKernelGGL(fhmm_pwtrans_kernel, dim3((VV + 63) / 64, 4), 256, 0, stream,
                       term_pw, pwT);

    // class word-lists
    hipLaunchKernelGGL(fhmm_init_counts_kernel, dim3(1), 128, 0, stream, counts, cursor);
    hipLaunchKernelGGL(fhmm_hist_kernel, dim3(40), 256, 0, stream, w2s, counts);
    hipLaunchKernelGGL(fhmm_offsets_kernel, dim3(1), 64, 0, stream, counts, offsets);
    hipLaunchKernelGGL(fhmm_scatter_kernel, dim3(40), 256, 0, stream, w2s, offsets, cursor, wlist);

    // next_emb
    hipLaunchKernelGGL(fhmm_emb_bf16_kernel, dim3(8192), 256, 0, stream,
                       se1_next, se2_next, next_emb_bf);

    dim3 mmGrid(128, 4);
    // start head
    hipLaunchKernelGGL(fhmm_emb_bf16_kernel, dim3(8192), 256, 0, stream,
                       se1_start, se2_start, emb_bf);
    hipLaunchKernelGGL(fhmm_mlp_mfma, mmGrid, 256, 0, stream,
                       emb_bf, Wt + 0 * HH * HH, start_b1, (const u16*)nullptr, h1_bf);
    hipLaunchKernelGGL(fhmm_mlp_mfma, mmGrid, 256, 0, stream,
                       h1_bf, Wt + 1 * HH * HH, start_b2, emb_bf, hstart_bf);
    hipLaunchKernelGGL(fhmm_dotpw_kernel, dim3(2048), 256, 0, stream,
                       hstart_bf, start_pw, start_pb, startv);
    hipLaunchKernelGGL(fhmm_lsm_vec_kernel, dim3(1), 1024, 0, stream, startv);

    // state head
    hipLaunchKernelGGL(fhmm_emb_bf16_kernel, dim3(8192), 256, 0, stream,
                       se1_state, se2_state, emb_bf);
    hipLaunchKernelGGL(fhmm_mlp_mfma, mmGrid, 256, 0, stream,
                       emb_bf, Wt + 2 * HH * HH, trans_b1, (const u16*)nullptr, h1_bf);
    hipLaunchKernelGGL(fhmm_mlp_mfma, mmGrid, 256, 0, stream,
                       h1_bf, Wt + 3 * HH * HH, trans_b2, emb_bf, h_state_bf);

    // pre head
    hipLaunchKernelGGL(fhmm_emb_bf16_kernel, dim3(8192), 256, 0, stream,
                       se1_pre, se2_pre, emb_bf);
    hipLaunchKernelGGL(fhmm_mlp_mfma, mmGrid, 256, 0, stream,
                       emb_bf, Wt + 4 * HH * HH, term_b1, (const u16*)nullptr, h1_bf);
    hipLaunchKernelGGL(fhmm_mlp_mfma, mmGrid, 256, 0, stream,
                       h1_bf, Wt + 5 * HH * HH, term_b2, emb_bf, h_pre_bf);

    // transition row-lse: direct + combine
    hipLaunchKernelGGL(fhmm_trans_lse_direct, dim3(128, 4), 256, 0, stream,
                       h_state_bf, next_emb_bf, pm, ps);
    hipLaunchKernelGGL(fhmm_trans_lse_combine, dim3(32), 256, 0, stream,
                       pm, ps, lse_trans);

    // per-(b,t) 64x64 logit blocks
    hipLaunchKernelGGL(fhmm_pots_mfma, dim3(BBB * (TTT - 1)), 256, 0, stream,
                       h_state_bf, next_emb_bf, text, w2s, potsT);

    // emission
    hipLaunchKernelGGL(fhmm_ew_mfma, dim3(NCC), 256, 0, stream,
                       h_pre_bf, pwT, term_pb, wlist, counts, offsets, Ew);
    hipLaunchKernelGGL(fhmm_lse_em_kernel, dim3(NCC), 64, 0, stream,
                       Ew, wlist, counts, offsets, lse_em);
    hipLaunchKernelGGL(fhmm_obs_kernel, dim3(BBB * TTT), 64, 0, stream,
                       Ew, lse_em, text, w2s, obs);

    // ---- tree reduction over transition matrices ----
    hipLaunchKernelGGL((fhmm_combine<0>), dim3(128, BBB), 256, 0, stream,
                       potsT, obs, lse_trans, text, w2s,
                       (const float*)nullptr, Lv0, 128);
    float* cin = Lv0;
    const int lv_sizes[7] = {64, 32, 16, 8, 4, 2, 1};
    for (int li = 0; li < 7; ++li) {
        float* cout = (cin == Lv0) ? Lv1 : Lv0;
        hipLaunchKernelGGL((fhmm_combine<1>), dim3(lv_sizes[li], BBB), 256, 0, stream,
                           (const u16*)nullptr, (const float*)nullptr,
                           (const float*)nullptr, (const int*)nullptr,
                           (const int*)nullptr, cin, cout, lv_sizes[li]);
        cin = cout;
    }

    // ---- final apply + lse ----
    hipLaunchKernelGGL(fhmm_final, dim3(BBB), 256, 0, stream,
                       startv, obs, cin, text, w2s, out);
}

// Round 7
// 290.376 us; speedup vs baseline: 1.9745x; 1.0849x over previous
//
#include <hip/hip_runtime.h>
#include <hip/hip_bf16.h>
#include <math.h>

#define HH 256
#define NCC 128
#define SPWW 64
#define CST 8192
#define VV 10000
#define BBB 16
#define TTT 256
#define LOG2E 1.4426950408889634f
#define LN2 0.6931471805599453f

typedef __attribute__((ext_vector_type(8))) short short8;
typedef __attribute__((ext_vector_type(4))) float f32x4;
typedef unsigned short u16;

struct Ptr6 { const float* p[6]; };
struct EmbA { const float* e1[4]; const float* e2[4]; u16* out[4]; };

__device__ inline float bf2f(u16 u) {
    union { unsigned int i; float f; } v; v.i = ((unsigned int)u) << 16; return v.f;
}
__device__ inline u16 f2bf(float f) {
    __hip_bfloat16 h = __float2bfloat16(f);
    return *reinterpret_cast<u16*>(&h);
}
__device__ inline float ex2(float x) { return __builtin_amdgcn_exp2f(x); }
__device__ inline float lg2(float x) { return __builtin_amdgcn_logf(x); }   // v_log_f32 = log2

// ---------------- all embeddings in one kernel (bf16 out) ----------------
__global__ __launch_bounds__(256) void fhmm_emb_all(EmbA a)
{
    int hd = blockIdx.y;
    const float* e1 = a.e1[hd];
    const float* e2 = a.e2[hd];
    u16* out = a.out[hd];
    int idx = blockIdx.x * 256 + threadIdx.x;   // over 8192*256
    int s = idx >> 8, h = idx & 255;
    out[idx] = f2bf(e1[(s >> 6) * HH + h] + e2[(s & 63) * HH + h]);
}

// ---------------- all 6 weight transposes: Wt[n][k] = bf16(W[k][n]) ----------------
__global__ __launch_bounds__(256) void fhmm_wtrans_all(Ptr6 Ws, u16* __restrict__ Wt)
{
    __shared__ float t[64][65];
    const float* W = Ws.p[blockIdx.z];
    u16* dst = Wt + (size_t)blockIdx.z * HH * HH;
    int k0 = blockIdx.x * 64, n0 = blockIdx.y * 64, tid = threadIdx.x;
    #pragma unroll
    for (int i = 0; i < 16; ++i) {
        int idx = tid + i * 256; int r = idx >> 6, c = idx & 63;
        t[r][c] = W[(k0 + r) * HH + n0 + c];
    }
    __syncthreads();
    #pragma unroll
    for (int i = 0; i < 16; ++i) {
        int idx = tid + i * 256; int r = idx >> 6, c = idx & 63;
        dst[(n0 + r) * HH + k0 + c] = f2bf(t[c][r]);
    }
}

// ---------------- pw transpose: pwT[v][k] = bf16(pw[k][v]) ----------------
__global__ __launch_bounds__(256) void fhmm_pwtrans_kernel(
    const float* __restrict__ pw, u16* __restrict__ pwT)
{
    __shared__ float t[64][65];
    int v0 = blockIdx.x * 64, k0 = blockIdx.y * 64, tid = threadIdx.x;
    #pragma unroll
    for (int i = 0; i < 16; ++i) {
        int idx = tid + i * 256; int r = idx >> 6, c = idx & 63;   // r:k, c:v
        int v = v0 + c;
        t[r][c] = (v < VV) ? pw[(size_t)(k0 + r) * VV + v] : 0.f;
    }
    __syncthreads();
    #pragma unroll
    for (int i = 0; i < 16; ++i) {
        int idx = tid + i * 256; int r = idx >> 6, c = idx & 63;   // r:v, c:k
        int v = v0 + r;
        if (v < VV) pwT[(size_t)v * HH + k0 + c] = f2bf(t[c][r]);
    }
}

// ---------------- word-list build: one block does hist+prefix+scatter ----------------
__global__ __launch_bounds__(1024) void fhmm_wordlist(
    const int* __restrict__ w2s, int* __restrict__ counts,
    int* __restrict__ offsets, int* __restrict__ wlist)
{
    __shared__ int cnt[NCC], off[NCC + 1], cur[NCC];
    int tid = threadIdx.x;
    if (tid < NCC) cnt[tid] = 0;
    __syncthreads();
    for (int v = tid; v < VV; v += 1024)
        atomicAdd(&cnt[w2s[v * SPWW] >> 6], 1);
    __syncthreads();
    if (tid == 0) {
        int acc = 0;
        for (int c = 0; c < NCC; ++c) { off[c] = acc; acc += cnt[c]; }
        off[NCC] = acc;
    }
    __syncthreads();
    if (tid < NCC) cur[tid] = off[tid];
    __syncthreads();
    for (int v = tid; v < VV; v += 1024) {
        int c = w2s[v * SPWW] >> 6;
        int pos = atomicAdd(&cur[c], 1);
        wlist[pos] = v;
    }
    if (tid < NCC) { counts[tid] = cnt[tid]; offsets[tid] = off[tid]; }
    if (tid == 0) offsets[NCC] = off[NCC];
}

// ---------------- MFMA MLP layer: Y = (relu(X@W + b) [+ res]) * oscale, bf16 I/O ----------------
__global__ __launch_bounds__(256) void fhmm_mlp_mfma(
    const u16* __restrict__ Xbf, const u16* __restrict__ Wt,
    const float* __restrict__ bias, const u16* __restrict__ resbf,
    u16* __restrict__ Ybf, float oscale)
{
    int m0 = blockIdx.x * 64, n0 = blockIdx.y * 64;
    __shared__ char Xs[32768];
    __shared__ char Ws[32768];
    int tid = threadIdx.x, w = tid >> 6, lane = tid & 63, lr = lane & 15, lg = lane >> 4;
    const char* xsrc = (const char*)(Xbf + (size_t)m0 * HH);
    const char* wsrc = (const char*)(Wt + (size_t)n0 * HH);
    #pragma unroll
    for (int i = 0; i < 8; ++i) {
        int cc = i * 256 + tid; int row = cc >> 5, tt = cc & 31;
        int dst = row * 512 + ((tt ^ (row & 7)) << 4);
        *(uint4*)&Xs[dst] = *(const uint4*)(xsrc + cc * 16);
        *(uint4*)&Ws[dst] = *(const uint4*)(wsrc + cc * 16);
    }
    __syncthreads();
    short8 bfr[8];
    int brow = w * 16 + lr, bb = brow * 512, bsw = (brow & 7) << 4;
    #pragma unroll
    for (int ks = 0; ks < 8; ++ks)
        bfr[ks] = *(const short8*)(Ws + bb + (((ks * 4 + lg) << 4) ^ bsw));
    int cb = w * 16 + lg * 4;
    f32x4 bv = *(const f32x4*)(bias + n0 + cb);
    #pragma unroll
    for (int rm = 0; rm < 4; ++rm) {
        f32x4 acc = {0.f, 0.f, 0.f, 0.f};
        int ar = rm * 16 + lr, ab = ar * 512, asw = (ar & 7) << 4;
        #pragma unroll
        for (int ks = 0; ks < 8; ++ks) {
            short8 af = *(const short8*)(Xs + ab + (((ks * 4 + lg) << 4) ^ asw));
            acc = __builtin_amdgcn_mfma_f32_16x16x32_bf16(bfr[ks], af, acc, 0, 0, 0);
        }
        int gm = m0 + rm * 16 + lr;
        ushort4 o;
        if (resbf) {
            const u16* rp = resbf + (size_t)gm * HH + n0 + cb;
            #pragma unroll
            for (int e = 0; e < 4; ++e)
                ((u16*)&o)[e] = f2bf((fmaxf(acc[e] + bv[e], 0.f) + bf2f(rp[e])) * oscale);
        } else {
            #pragma unroll
            for (int e = 0; e < 4; ++e)
                ((u16*)&o)[e] = f2bf(fmaxf(acc[e] + bv[e], 0.f) * oscale);
        }
        *(ushort4*)(Ybf + (size_t)gm * HH + n0 + cb) = o;
    }
}

// ---------------- start head: dot with pw (bf16 h) ----------------
__global__ __launch_bounds__(256) void fhmm_dotpw_kernel(
    const u16* __restrict__ hb, const float* __restrict__ pw,
    const float* __restrict__ pbp, float* __restrict__ p)
{
    int wv = threadIdx.x >> 6;
    int lane = threadIdx.x & 63;
    int s = blockIdx.x * 4 + wv;
    const u16* hr = hb + (size_t)s * HH;
    float acc = 0.f;
    #pragma unroll
    for (int i = 0; i < 4; ++i) acc += bf2f(hr[i * 64 + lane]) * pw[i * 64 + lane];
    #pragma unroll
    for (int d = 32; d; d >>= 1) acc += __shfl_xor(acc, d);
    if (lane == 0) p[s] = acc + pbp[0];
}

// ---------------- in-place log_softmax over a length-8192 vector ----------------
__global__ __launch_bounds__(1024) void fhmm_lsm_vec_kernel(float* __restrict__ p)
{
    __shared__ float red[64];
    int tid = threadIdx.x;
    float m = -1e30f;
    for (int i = tid; i < CST; i += 1024) m = fmaxf(m, p[i]);
    #pragma unroll
    for (int d = 32; d; d >>= 1) m = fmaxf(m, __shfl_xor(m, d));
    if ((tid & 63) == 0) red[tid >> 6] = m;
    __syncthreads();
    if (tid == 0) {
        float mm = red[0];
        for (int q = 1; q < 16; ++q) mm = fmaxf(mm, red[q]);
        red[32] = mm;
    }
    __syncthreads();
    float M = red[32];
    float s = 0.f;
    for (int i = tid; i < CST; i += 1024) s += expf(p[i] - M);
    #pragma unroll
    for (int d = 32; d; d >>= 1) s += __shfl_xor(s, d);
    if ((tid & 63) == 0) red[tid >> 6] = s;
    __syncthreads();
    if (tid == 0) {
        float ss = 0.f;
        for (int q = 0; q < 16; ++q) ss += red[q];
        red[33] = ss;
    }
    __syncthreads();
    float lse = M + logf(red[33]);
    for (int i = tid; i < CST; i += 1024) p[i] -= lse;
}

// ---------------- transition row-lse: direct-from-L2, barrier-free, base-2 ----------------
// A (h_state) is PRESCALED by log2e -> MFMA emits base-2 logits; native ex2/lg2.
// Grid (128, 8): block = 64 A-rows x 1024-col eighth; 4 blocks/CU.
__global__ __launch_bounds__(256) void fhmm_trans_lse_direct(
    const u16* __restrict__ Abf,   // h_state*log2e bf16 [8192][256]
    const u16* __restrict__ Bbf,   // next_emb bf16 [8192][256]
    float* __restrict__ pm, float* __restrict__ ps)
{
    int r0 = blockIdx.x * 64;
    int cq = blockIdx.y;           // col eighth (1024 cols)
    int tid = threadIdx.x, w = tid >> 6, lane = tid & 63;
    int lr = lane & 15, lg = lane >> 4;

    short8 afr[4][8];
    #pragma unroll
    for (int rm = 0; rm < 4; ++rm)
        #pragma unroll
        for (int ks = 0; ks < 8; ++ks)
            afr[rm][ks] = *reinterpret_cast<const short8*>(
                Abf + (size_t)(r0 + rm * 16 + lr) * HH + ks * 32 + lg * 8);

    float m[4], s[4];
    #pragma unroll
    for (int rm = 0; rm < 4; ++rm) { m[rm] = -3e38f; s[rm] = 0.f; }

    const u16* Bp = Bbf + (size_t)(cq * 1024 + w * 16 + lr) * HH + lg * 8;
    short8 bcur[8], bnxt[8];
    #pragma unroll
    for (int ks = 0; ks < 8; ++ks)
        bcur[ks] = *reinterpret_cast<const short8*>(Bp + ks * 32);

    for (int it = 0; it < 16; ++it) {
        if (it < 15) {
            const u16* Bn = Bp + (size_t)(it + 1) * 64 * HH;
            #pragma unroll
            for (int ks = 0; ks < 8; ++ks)
                bnxt[ks] = *reinterpret_cast<const short8*>(Bn + ks * 32);
        }
        f32x4 acc[4];
        #pragma unroll
        for (int rm = 0; rm < 4; ++rm) acc[rm] = (f32x4){0.f, 0.f, 0.f, 0.f};
        #pragma unroll
        for (int ks = 0; ks < 8; ++ks) {
            #pragma unroll
            for (int rm = 0; rm < 4; ++rm)
                acc[rm] = __builtin_amdgcn_mfma_f32_16x16x32_bf16(
                    bcur[ks], afr[rm][ks], acc[rm], 0, 0, 0);
        }
        #pragma unroll
        for (int rm = 0; rm < 4; ++rm) {
            float lm = fmaxf(fmaxf(acc[rm][0], acc[rm][1]),
                             fmaxf(acc[rm][2], acc[rm][3]));
            float mn = fmaxf(m[rm], lm);
            s[rm] = s[rm] * ex2(m[rm] - mn)
                  + ex2(acc[rm][0] - mn) + ex2(acc[rm][1] - mn)
                  + ex2(acc[rm][2] - mn) + ex2(acc[rm][3] - mn);
            m[rm] = mn;
        }
        #pragma unroll
        for (int ks = 0; ks < 8; ++ks) bcur[ks] = bnxt[ks];
    }

    #pragma unroll
    for (int rm = 0; rm < 4; ++rm) {
        #pragma unroll
        for (int d = 16; d < 64; d <<= 1) {
            float m2 = __shfl_xor(m[rm], d), sx = __shfl_xor(s[rm], d);
            float mn = fmaxf(m[rm], m2);
            s[rm] = s[rm] * ex2(m[rm] - mn) + sx * ex2(m2 - mn);
            m[rm] = mn;
        }
    }
    __shared__ float lm_[4][64], ls_[4][64];
    if (lane < 16) {
        #pragma unroll
        for (int rm = 0; rm < 4; ++rm) {
            lm_[w][rm * 16 + lane] = m[rm];
            ls_[w][rm * 16 + lane] = s[rm];
        }
    }
    __syncthreads();
    if (tid < 64) {
        float M = lm_[0][tid], S = ls_[0][tid];
        #pragma unroll
        for (int q = 1; q < 4; ++q) {
            float m2 = lm_[q][tid], sx = ls_[q][tid];
            float mn = fmaxf(M, m2);
            S = S * ex2(M - mn) + sx * ex2(m2 - mn); M = mn;
        }
        pm[(size_t)cq * CST + r0 + tid] = M;
        ps[(size_t)cq * CST + r0 + tid] = S;
    }
}

__global__ __launch_bounds__(256) void fhmm_trans_lse_combine(
    const float* __restrict__ pm, const float* __restrict__ ps,
    float* __restrict__ lse2)
{
    int r = blockIdx.x * 256 + threadIdx.x;
    float M = pm[r], S = ps[r];
    #pragma unroll
    for (int q = 1; q < 8; ++q) {
        float m2 = pm[(size_t)q * CST + r], sx = ps[(size_t)q * CST + r];
        float mn = fmaxf(M, m2);
        S = S * ex2(M - mn) + sx * ex2(m2 - mn); M = mn;
    }
    lse2[r] = M + lg2(S);     // base-2 lse
}

// ---------------- per-(b,t) 64x64 transition-logit blocks, TRANSPOSED bf16 out ----------------
// A prescaled by log2e -> acc is already base-2: potsT2[blk][j][i] = logits2[i][j]
__global__ __launch_bounds__(256) void fhmm_pots_mfma(
    const u16* __restrict__ Abf, const u16* __restrict__ Bbf,
    const int* __restrict__ text, const int* __restrict__ w2s,
    u16* __restrict__ potsT2)
{
    int blk = blockIdx.x;              // b*255 + t
    int b = blk / (TTT - 1), t = blk % (TTT - 1);
    int sr = w2s[text[b * TTT + t] * SPWW];
    int sc = w2s[text[b * TTT + t + 1] * SPWW];
    __shared__ char As_[32768];
    __shared__ char Bs_[32768];
    int tid = threadIdx.x;
    int w = tid >> 6, lane = tid & 63;
    int lr = lane & 15, lg = lane >> 4;

    const char* Asrc = reinterpret_cast<const char*>(Abf + (size_t)sr * HH);
    const char* Bsrc = reinterpret_cast<const char*>(Bbf + (size_t)sc * HH);
    #pragma unroll
    for (int i = 0; i < 8; ++i) {
        int c = i * 256 + tid;
        int row = c >> 5, tt = c & 31;
        int dst = row * 512 + ((tt ^ (row & 7)) << 4);
        *reinterpret_cast<uint4*>(&As_[dst]) = *reinterpret_cast<const uint4*>(Asrc + c * 16);
        *reinterpret_cast<uint4*>(&Bs_[dst]) = *reinterpret_cast<const uint4*>(Bsrc + c * 16);
    }
    __syncthreads();

    short8 bfr[8];
    int brow = w * 16 + lr;
    int bbase = brow * 512;
    int bswz = (brow & 7) << 4;
    #pragma unroll
    for (int ks = 0; ks < 8; ++ks)
        bfr[ks] = *reinterpret_cast<const short8*>(
            Bs_ + bbase + (((ks * 4 + lg) << 4) ^ bswz));

    u16* op = potsT2 + (size_t)blk * 4096;
    #pragma unroll
    for (int rm = 0; rm < 4; ++rm) {
        f32x4 acc = {0.f, 0.f, 0.f, 0.f};
        int arow = rm * 16 + lr;
        int abase = arow * 512;
        int aswz = (arow & 7) << 4;
        #pragma unroll
        for (int ks = 0; ks < 8; ++ks) {
            short8 af = *reinterpret_cast<const short8*>(
                As_ + abase + (((ks * 4 + lg) << 4) ^ aswz));
            acc = __builtin_amdgcn_mfma_f32_16x16x32_bf16(af, bfr[ks], acc, 0, 0, 0);
        }
        ushort4 o;
        #pragma unroll
        for (int e = 0; e < 4; ++e) ((u16*)&o)[e] = f2bf(acc[e]);
        *(ushort4*)(op + (size_t)(w * 16 + lr) * 64 + rm * 16 + lg * 4) = o;
    }
}

// ---------------- per-class emission GEMM: Ew[v][k] = H_c @ pwT[v] + pb[v] ----------------
__global__ __launch_bounds__(256) void fhmm_ew_mfma(
    const u16* __restrict__ hpre_bf, const u16* __restrict__ pwT,
    const float* __restrict__ pb, const int* __restrict__ wlist,
    const int* __restrict__ counts, const int* __restrict__ offsets,
    float* __restrict__ Ew)
{
    int c = blockIdx.x;
    int cnt = counts[c], off = offsets[c];
    __shared__ char Hs[32768];
    int tid = threadIdx.x, w = tid >> 6, lane = tid & 63, lr = lane & 15, lg = lane >> 4;
    const char* src = (const char*)(hpre_bf + (size_t)c * 64 * HH);
    #pragma unroll
    for (int i = 0; i < 8; ++i) {
        int cc = i * 256 + tid; int row = cc >> 5, tt = cc & 31;
        *(uint4*)&Hs[row * 512 + ((tt ^ (row & 7)) << 4)] = *(const uint4*)(src + cc * 16);
    }
    __syncthreads();
    for (int ch = 0; ch * 64 < cnt; ++ch) {
        int widx = ch * 64 + w * 16 + lr;
        bool valid = widx < cnt;
        int v = valid ? wlist[off + widx] : 0;
        short8 bw[8];
        short8 bz = {0, 0, 0, 0, 0, 0, 0, 0};
        #pragma unroll
        for (int ks = 0; ks < 8; ++ks)
            bw[ks] = valid ? *(const short8*)(pwT + (size_t)v * HH + ks * 32 + lg * 8) : bz;
        float pbv = valid ? pb[v] : 0.f;
        #pragma unroll
        for (int rm = 0; rm < 4; ++rm) {
            f32x4 acc = {0.f, 0.f, 0.f, 0.f};
            int ar = rm * 16 + lr, ab = ar * 512, asw = (ar & 7) << 4;
            #pragma unroll
            for (int ks = 0; ks < 8; ++ks) {
                short8 ah = *(const short8*)(Hs + ab + (((ks * 4 + lg) << 4) ^ asw));
                acc = __builtin_amdgcn_mfma_f32_16x16x32_bf16(ah, bw[ks], acc, 0, 0, 0);
            }
            if (valid) {
                f32x4 o;
                #pragma unroll
                for (int e = 0; e < 4; ++e) o[e] = acc[e] + pbv;
                *(f32x4*)(Ew + (size_t)v * 64 + rm * 16 + lg * 4) = o;
            }
        }
    }
}

// ---------------- per-state emission lse ----------------
__global__ __launch_bounds__(64) void fhmm_lse_em_kernel(
    const float* __restrict__ Ew, const int* __restrict__ wlist,
    const int* __restrict__ counts, const int* __restrict__ offsets,
    float* __restrict__ lse_em)
{
    int c = blockIdx.x, k = threadIdx.x;
    int cnt = counts[c], off = offsets[c];
    float m = -1e30f;
    for (int i = 0; i < cnt; ++i) m = fmaxf(m, Ew[wlist[off + i] * 64 + k]);
    float s = 0.f;
    for (int i = 0; i < cnt; ++i) s += __expf(Ew[wlist[off + i] * 64 + k] - m);
    lse_em[c * 64 + k] = (cnt > 0) ? (m + logf(s)) : -1e30f;
}

// ---------------- obs2[b,t,k] (base-2 prescaled) ----------------
__global__ __launch_bounds__(64) void fhmm_obs_kernel(
    const float* __restrict__ Ew, const float* __restrict__ lse_em,
    const int* __restrict__ text, const int* __restrict__ w2s,
    float* __restrict__ obs2)
{
    int i = blockIdx.x;      // b*T + t
    int k = threadIdx.x;
    int v = text[i];
    int s = w2s[v * SPWW + k];
    obs2[i * 64 + k] = (Ew[v * 64 + k] - lse_em[s]) * LOG2E;
}

// ================= TREE COMBINE: C = A (x) B in lse2 semiring ==================
template<int MODE>
__global__ __launch_bounds__(256) void fhmm_combine(
    const u16* __restrict__ potsT2, const float* __restrict__ obs2,
    const float* __restrict__ lse_trans2,
    const int* __restrict__ text, const int* __restrict__ w2s,
    const float* __restrict__ Lin, float* __restrict__ Lout, int pairs)
{
    int p = blockIdx.x, b = blockIdx.y;
    int tid = threadIdx.x;
    int l6 = tid & 63, q = tid >> 6;

    __shared__ char Ps[8192];            // P [i][k] bf16, 128B rows, swizzled
    __shared__ char Qs[8192];            // Qt [j][k] bf16
    __shared__ float mA2[64], mB2[64];   // output offsets
    __shared__ float mAf[64], mBf[64];   // maxes used inside exp2
    __shared__ float part[2][4][64];
    __shared__ float ltB_l[64];

    float va[16], vb[16];
    float ltA = 0.f, obB = 0.f;
    float* Co = Lout + ((size_t)(b * pairs + p)) * 4096;

    if (MODE == 0) {
        int tA = 2 * p + 1, tB = 2 * p + 2;
        int i = l6;
        const u16* pA = potsT2 + ((size_t)(b * 255 + (tA - 1))) * 4096;  // [j][i]
        ltA = lse_trans2[w2s[text[b * TTT + (tA - 1)] * SPWW] + i];
        float mloc = -3e38f;
        #pragma unroll
        for (int jj = 0; jj < 16; ++jj) {
            int j = q * 16 + jj;
            float v = bf2f(pA[j * 64 + i]) + obs2[(size_t)(b * TTT + tA) * 64 + j];
            va[jj] = v; mloc = fmaxf(mloc, v);
        }
        if (tB > 255) {          // B = identity: C = M_A exactly
            #pragma unroll
            for (int jj = 0; jj < 16; ++jj)
                Co[i * 64 + q * 16 + jj] = va[jj] - ltA;
            return;
        }
        part[0][q][i] = mloc;
        int srowB = w2s[text[b * TTT + (tB - 1)] * SPWW];
        if (tid < 64) ltB_l[tid] = lse_trans2[srowB + tid];
        const u16* pB = potsT2 + ((size_t)(b * 255 + (tB - 1))) * 4096;  // [j][k]
        obB = obs2[(size_t)(b * TTT + tB) * 64 + l6];
        uint4 r0 = *(const uint4*)(pB + (size_t)l6 * 64 + q * 16);
        uint4 r1 = *(const uint4*)(pB + (size_t)l6 * 64 + q * 16 + 8);
        __syncthreads();
        const u16* rb = (const u16*)&r0;
        float mlocB = -3e38f;
        #pragma unroll
        for (int kk = 0; kk < 8; ++kk) {
            vb[kk] = bf2f(rb[kk]) - ltB_l[q * 16 + kk];
            mlocB = fmaxf(mlocB, vb[kk]);
        }
        rb = (const u16*)&r1;
        #pragma unroll
        for (int kk = 0; kk < 8; ++kk) {
            vb[8 + kk] = bf2f(rb[kk]) - ltB_l[q * 16 + 8 + kk];
            mlocB = fmaxf(mlocB, vb[8 + kk]);
        }
        part[1][q][l6] = mlocB;
    } else {
        const float* Af = Lin + ((size_t)(b * (2 * pairs) + 2 * p)) * 4096;
        const float* Bf = Af + 4096;
        float mloc = -3e38f;
        #pragma unroll
        for (int jj = 0; jj < 16; ++jj) {
            float v = Af[l6 * 64 + q * 16 + jj];
            va[jj] = v; mloc = fmaxf(mloc, v);
        }
        part[0][q][l6] = mloc;
        float mlocB = -3e38f;
        #pragma unroll
        for (int kk = 0; kk < 16; ++kk) {
            float v = Bf[(q * 16 + kk) * 64 + l6];
            vb[kk] = v; mlocB = fmaxf(mlocB, v);
        }
        part[1][q][l6] = mlocB;
        __syncthreads();
    }
    __syncthreads();

    if (tid < 64) {
        float mf = fmaxf(fmaxf(part[0][0][tid], part[0][1][tid]),
                         fmaxf(part[0][2][tid], part[0][3][tid]));
        mAf[tid] = mf;
        mA2[tid] = (MODE == 0) ? (mf - ltA) : mf;
    } else if (tid < 128) {
        int j = tid & 63;
        float mf = fmaxf(fmaxf(part[1][0][j], part[1][1][j]),
                         fmaxf(part[1][2][j], part[1][3][j]));
        mBf[j] = mf;
        mB2[j] = (MODE == 0) ? (mf + obB) : mf;
    }
    __syncthreads();

    {
        float ma = mAf[l6];
        u16 pk[16];
        #pragma unroll
        for (int e = 0; e < 16; ++e) pk[e] = f2bf(ex2(va[e] - ma));
        uint4* src = (uint4*)pk;
        int base = l6 * 128;
        int s0 = 2 * q, s1 = 2 * q + 1, sw = (l6 & 7);
        *(uint4*)&Ps[base + (((s0 ^ sw)) << 4)] = src[0];
        *(uint4*)&Ps[base + (((s1 ^ sw)) << 4)] = src[1];
        float mb = mBf[l6];
        #pragma unroll
        for (int e = 0; e < 16; ++e) pk[e] = f2bf(ex2(vb[e] - mb));
        *(uint4*)&Qs[base + (((s0 ^ sw)) << 4)] = src[0];
        *(uint4*)&Qs[base + (((s1 ^ sw)) << 4)] = src[1];
    }
    __syncthreads();

    int w = q, lr = l6 & 15, lg = l6 >> 4;
    int brow = w * 16 + lr;
    short8 bfr[2];
    #pragma unroll
    for (int ks = 0; ks < 2; ++ks)
        bfr[ks] = *(const short8*)(Qs + brow * 128 + ((((ks * 4 + lg)) << 4) ^ ((brow & 7) << 4)));
    #pragma unroll
    for (int rm = 0; rm < 4; ++rm) {
        f32x4 acc = {0.f, 0.f, 0.f, 0.f};
        int ar = rm * 16 + lr;
        #pragma unroll
        for (int ks = 0; ks < 2; ++ks) {
            short8 af = *(const short8*)(Ps + ar * 128 + ((((ks * 4 + lg)) << 4) ^ ((ar & 7) << 4)));
            acc = __builtin_amdgcn_mfma_f32_16x16x32_bf16(af, bfr[ks], acc, 0, 0, 0);
        }
        #pragma unroll
        for (int e = 0; e < 4; ++e) {
            int ii = rm * 16 + lg * 4 + e;
            int jj = w * 16 + lr;
            Co[ii * 64 + jj] = mA2[ii] + mB2[jj] + lg2(fmaxf(acc[e], 1e-33f));
        }
    }
}

// ---------------- final: out[b] = LN2 * lse2_{i,j}( a0_2[i] + Mtot[i][j] ) ----------------
__global__ __launch_bounds__(256) void fhmm_final(
    const float* __restrict__ startv, const float* __restrict__ obs2,
    const float* __restrict__ Mtot, const int* __restrict__ text,
    const int* __restrict__ w2s, float* __restrict__ out)
{
    int b = blockIdx.x, tid = threadIdx.x;
    __shared__ float a0[64];
    __shared__ float rm_[4], rs_[4];
    if (tid < 64) {
        int s0 = w2s[text[b * TTT] * SPWW];
        a0[tid] = startv[s0 + tid] * LOG2E + obs2[(size_t)(b * TTT) * 64 + tid];
    }
    __syncthreads();
    const float* M = Mtot + (size_t)b * 4096;
    float m = -3e38f, s = 0.f;
    for (int e = tid; e < 4096; e += 256) {
        float v = a0[e >> 6] + M[e];
        float mn = fmaxf(m, v);
        s = s * ex2(m - mn) + ex2(v - mn);
        m = mn;
    }
    #pragma unroll
    for (int d = 32; d; d >>= 1) {
        float m2 = __shfl_xor(m, d), sx = __shfl_xor(s, d);
        float mn = fmaxf(m, m2);
        s = s * ex2(m - mn) + sx * ex2(m2 - mn); m = mn;
    }
    if ((tid & 63) == 0) { rm_[tid >> 6] = m; rs_[tid >> 6] = s; }
    __syncthreads();
    if (tid == 0) {
        float M_ = rm_[0], S_ = rs_[0];
        #pragma unroll
        for (int qq = 1; qq < 4; ++qq) {
            float mn = fmaxf(M_, rm_[qq]);
            S_ = S_ * ex2(M_ - mn) + rs_[qq] * ex2(rm_[qq] - mn); M_ = mn;
        }
        out[b] = (M_ + lg2(S_)) * LN2;
    }
}

extern "C" void kernel_launch(void* const* d_in, const int* in_sizes, int n_in,
                              void* d_out, int out_size, void* d_ws, size_t ws_size,
                              hipStream_t stream) {
    const int* text        = (const int*)d_in[0];
    const int* w2s         = (const int*)d_in[1];
    const float* se1_start = (const float*)d_in[2];
    const float* se2_start = (const float*)d_in[3];
    const float* start_w1  = (const float*)d_in[4];
    const float* start_b1  = (const float*)d_in[5];
    const float* start_w2  = (const float*)d_in[6];
    const float* start_b2  = (const float*)d_in[7];
    const float* start_pw  = (const float*)d_in[8];
    const float* start_pb  = (const float*)d_in[9];
    const float* se1_state = (const float*)d_in[10];
    const float* se2_state = (const float*)d_in[11];
    const float* se1_next  = (const float*)d_in[12];
    const float* se2_next  = (const float*)d_in[13];
    const float* trans_w1  = (const float*)d_in[14];
    const float* trans_b1  = (const float*)d_in[15];
    const float* trans_w2  = (const float*)d_in[16];
    const float* trans_b2  = (const float*)d_in[17];
    const float* se1_pre   = (const float*)d_in[18];
    const float* se2_pre   = (const float*)d_in[19];
    const float* term_w1   = (const float*)d_in[20];
    const float* term_b1   = (const float*)d_in[21];
    const float* term_w2   = (const float*)d_in[22];
    const float* term_b2   = (const float*)d_in[23];
    const float* term_pw   = (const float*)d_in[24];
    const float* term_pb   = (const float*)d_in[25];
    float* out = (float*)d_out;

    char* wp = (char*)d_ws;
    auto alloc = [&](size_t bytes) {
        char* p = wp;
        wp += (bytes + 255) & ~(size_t)255;
        return (void*)p;
    };
    u16* emb_start   = (u16*)alloc((size_t)CST * HH * 2);
    u16* emb_state   = (u16*)alloc((size_t)CST * HH * 2);
    u16* emb_pre     = (u16*)alloc((size_t)CST * HH * 2);
    u16* next_emb_bf = (u16*)alloc((size_t)CST * HH * 2);
    u16* h1_bf       = (u16*)alloc((size_t)CST * HH * 2);
    u16* hstart_bf   = (u16*)alloc((size_t)CST * HH * 2);
    u16* h_state_bf  = (u16*)alloc((size_t)CST * HH * 2);
    u16* h_pre_bf    = (u16*)alloc((size_t)CST * HH * 2);
    u16* Wt          = (u16*)alloc((size_t)6 * HH * HH * 2);
    u16* pwT         = (u16*)alloc((size_t)VV * HH * 2);
    float* startv    = (float*)alloc(CST * 4);
    float* lse_trans = (float*)alloc(CST * 4);
    float* pm        = (float*)alloc((size_t)8 * CST * 4);
    float* ps        = (float*)alloc((size_t)8 * CST * 4);
    float* lse_em    = (float*)alloc(CST * 4);
    float* Ew        = (float*)alloc((size_t)VV * 64 * 4);
    int* counts      = (int*)alloc(NCC * 4);
    int* offsets     = (int*)alloc((NCC + 4) * 4);
    int* wlist       = (int*)alloc(VV * 4);
    float* obs       = (float*)alloc((size_t)BBB * TTT * 64 * 4);
    u16* potsT       = (u16*)alloc((size_t)BBB * (TTT - 1) * 4096 * 2);
    float* Lv0       = (float*)alloc((size_t)BBB * 128 * 4096 * 4);
    float* Lv1       = (float*)alloc((size_t)BBB * 64 * 4096 * 4);

    // weight transposes (all in one) + pw transpose
    Ptr6 wargs = {{start_w1, start_w2, trans_w1, trans_w2, term_w1, term_w2}};
    hipLaunchKernelGGL(fhmm_wtrans_all, dim3(4, 4, 6), 256, 0, stream, wargs, Wt);
    hipLaunchKernelGGL(fhmm_pwtrans_kernel, dim3((VV + 63) / 64, 4), 256, 0, stream,
                       term_pw, pwT);

    // class word-lists (single block)
    hipLaunchKernelGGL(fhmm_wordlist, dim3(1), 1024, 0, stream,
                       w2s, counts, offsets, wlist);

    // all 4 embeddings
    EmbA eargs = {{se1_start, se1_state, se1_pre, se1_next},
                  {se2_start, se2_state, se2_pre, se2_next},
                  {emb_start, emb_state, emb_pre, next_emb_bf}};
    hipLaunchKernelGGL(fhmm_emb_all, dim3(8192, 4), 256, 0, stream, eargs);

    dim3 mmGrid(128, 4);
    // start head
    hipLaunchKernelGGL(fhmm_mlp_mfma, mmGrid, 256, 0, stream,
                       emb_start, Wt + 0 * HH * HH, start_b1, (const u16*)nullptr, h1_bf, 1.0f);
    hipLaunchKernelGGL(fhmm_mlp_mfma, mmGrid, 256, 0, stream,
                       h1_bf, Wt + 1 * HH * HH, start_b2, emb_start, hstart_bf, 1.0f);
    hipLaunchKernelGGL(fhmm_dotpw_kernel, dim3(2048), 256, 0, stream,
                       hstart_bf, start_pw, start_pb, startv);
    hipLaunchKernelGGL(fhmm_lsm_vec_kernel, dim3(1), 1024, 0, stream, startv);

    // state head (output prescaled by log2e -> base-2 logits downstream)
    hipLaunchKernelGGL(fhmm_mlp_mfma, mmGrid, 256, 0, stream,
                       emb_state, Wt + 2 * HH * HH, trans_b1, (const u16*)nullptr, h1_bf, 1.0f);
    hipLaunchKernelGGL(fhmm_mlp_mfma, mmGrid, 256, 0, stream,
                       h1_bf, Wt + 3 * HH * HH, trans_b2, emb_state, h_state_bf, LOG2E);

    // pre head
    hipLaunchKernelGGL(fhmm_mlp_mfma, mmGrid, 256, 0, stream,
                       emb_pre, Wt + 4 * HH * HH, term_b1, (const u16*)nullptr, h1_bf, 1.0f);
    hipLaunchKernelGGL(fhmm_mlp_mfma, mmGrid, 256, 0, stream,
                       h1_bf, Wt + 5 * HH * HH, term_b2, emb_pre, h_pre_bf, 1.0f);

    // transition row-lse: direct (8 col-eighths) + combine
    hipLaunchKernelGGL(fhmm_trans_lse_direct, dim3(128, 8), 256, 0, stream,
                       h_state_bf, next_emb_bf, pm, ps);
    hipLaunchKernelGGL(fhmm_trans_lse_combine, dim3(32), 256, 0, stream,
                       pm, ps, lse_trans);

    // per-(b,t) 64x64 logit blocks
    hipLaunchKernelGGL(fhmm_pots_mfma, dim3(BBB * (TTT - 1)), 256, 0, stream,
                       h_state_bf, next_emb_bf, text, w2s, potsT);

    // emission
    hipLaunchKernelGGL(fhmm_ew_mfma, dim3(NCC), 256, 0, stream,
                       h_pre_bf, pwT, term_pb, wlist, counts, offsets, Ew);
    hipLaunchKernelGGL(fhmm_lse_em_kernel, dim3(NCC), 64, 0, stream,
                       Ew, wlist, counts, offsets, lse_em);
    hipLaunchKernelGGL(fhmm_obs_kernel, dim3(BBB * TTT), 64, 0, stream,
                       Ew, lse_em, text, w2s, obs);

    // ---- tree reduction over transition matrices ----
    hipLaunchKernelGGL((fhmm_combine<0>), dim3(128, BBB), 256, 0, stream,
                       potsT, obs, lse_trans, text, w2s,
                       (const float*)nullptr, Lv0, 128);
    float* cin = Lv0;
    const int lv_sizes[7] = {64, 32, 16, 8, 4, 2, 1};
    for (int li = 0; li < 7; ++li) {
        float* cout = (cin == Lv0) ? Lv1 : Lv0;
        hipLaunchKernelGGL((fhmm_combine<1>), dim3(lv_sizes[li], BBB), 256, 0, stream,
                           (const u16*)nullptr, (const float*)nullptr,
                           (const float*)nullptr, (const int*)nullptr,
                           (const int*)nullptr, cin, cout, lv_sizes[li]);
        cin = cout;
    }

    // ---- final apply + lse ----
    hipLaunchKernelGGL(fhmm_final, dim3(BBB), 256, 0, stream,
                       startv, obs, cin, text, w2s, out);
}

// Round 8
// 200.330 us; speedup vs baseline: 2.8620x; 1.4495x over previous
//
#include <hip/hip_runtime.h>
#include <hip/hip_bf16.h>
#include <math.h>

#define HH 256
#define NCC 128
#define SPWW 64
#define CST 8192
#define VV 10000
#define BBB 16
#define TTT 256
#define LOG2E 1.4426950408889634f
#define LN2 0.6931471805599453f

typedef __attribute__((ext_vector_type(8))) short short8;
typedef __attribute__((ext_vector_type(4))) float f32x4;
typedef unsigned short u16;

struct Ptr6 { const float* p[6]; };
struct EmbA { const float* e1[3]; const float* e2[3]; u16* out[3]; };

__device__ inline float bf2f(u16 u) {
    union { unsigned int i; float f; } v; v.i = ((unsigned int)u) << 16; return v.f;
}
__device__ inline u16 f2bf(float f) {
    __hip_bfloat16 h = __float2bfloat16(f);
    return *reinterpret_cast<u16*>(&h);
}
__device__ inline float ex2(float x) { return __builtin_amdgcn_exp2f(x); }
__device__ inline float lg2(float x) { return __builtin_amdgcn_logf(x); }   // v_log_f32 = log2

// ---------------- 3 big embeddings in one kernel (bf16 out) ----------------
__global__ __launch_bounds__(256) void fhmm_emb_all(EmbA a)
{
    int hd = blockIdx.y;
    const float* e1 = a.e1[hd];
    const float* e2 = a.e2[hd];
    u16* out = a.out[hd];
    int idx = blockIdx.x * 256 + threadIdx.x;   // over 8192*256
    int s = idx >> 8, h = idx & 255;
    out[idx] = f2bf(e1[(s >> 6) * HH + h] + e2[(s & 63) * HH + h]);
}

// ---------------- next-state factor embeddings to bf16 (small) ----------------
__global__ __launch_bounds__(256) void fhmm_emb_next_small(
    const float* __restrict__ e1, const float* __restrict__ e2,
    u16* __restrict__ e1b, u16* __restrict__ e2b)
{
    int idx = blockIdx.x * 256 + threadIdx.x;
    if (idx < NCC * HH) e1b[idx] = f2bf(e1[idx]);
    if (idx < SPWW * HH) e2b[idx] = f2bf(e2[idx]);
}

// ---------------- all 6 weight transposes: Wt[n][k] = bf16(W[k][n]) ----------------
__global__ __launch_bounds__(256) void fhmm_wtrans_all(Ptr6 Ws, u16* __restrict__ Wt)
{
    __shared__ float t[64][65];
    const float* W = Ws.p[blockIdx.z];
    u16* dst = Wt + (size_t)blockIdx.z * HH * HH;
    int k0 = blockIdx.x * 64, n0 = blockIdx.y * 64, tid = threadIdx.x;
    #pragma unroll
    for (int i = 0; i < 16; ++i) {
        int idx = tid + i * 256; int r = idx >> 6, c = idx & 63;
        t[r][c] = W[(k0 + r) * HH + n0 + c];
    }
    __syncthreads();
    #pragma unroll
    for (int i = 0; i < 16; ++i) {
        int idx = tid + i * 256; int r = idx >> 6, c = idx & 63;
        dst[(n0 + r) * HH + k0 + c] = f2bf(t[c][r]);
    }
}

// ---------------- pw transpose: pwT[v][k] = bf16(pw[k][v]) ----------------
__global__ __launch_bounds__(256) void fhmm_pwtrans_kernel(
    const float* __restrict__ pw, u16* __restrict__ pwT)
{
    __shared__ float t[64][65];
    int v0 = blockIdx.x * 64, k0 = blockIdx.y * 64, tid = threadIdx.x;
    #pragma unroll
    for (int i = 0; i < 16; ++i) {
        int idx = tid + i * 256; int r = idx >> 6, c = idx & 63;   // r:k, c:v
        int v = v0 + c;
        t[r][c] = (v < VV) ? pw[(size_t)(k0 + r) * VV + v] : 0.f;
    }
    __syncthreads();
    #pragma unroll
    for (int i = 0; i < 16; ++i) {
        int idx = tid + i * 256; int r = idx >> 6, c = idx & 63;   // r:v, c:k
        int v = v0 + r;
        if (v < VV) pwT[(size_t)v * HH + k0 + c] = f2bf(t[c][r]);
    }
}

// ---------------- word-list build: one block does hist+prefix+scatter ----------------
__global__ __launch_bounds__(1024) void fhmm_wordlist(
    const int* __restrict__ w2s, int* __restrict__ counts,
    int* __restrict__ offsets, int* __restrict__ wlist)
{
    __shared__ int cnt[NCC], off[NCC + 1], cur[NCC];
    int tid = threadIdx.x;
    if (tid < NCC) cnt[tid] = 0;
    __syncthreads();
    for (int v = tid; v < VV; v += 1024)
        atomicAdd(&cnt[w2s[v * SPWW] >> 6], 1);
    __syncthreads();
    if (tid == 0) {
        int acc = 0;
        for (int c = 0; c < NCC; ++c) { off[c] = acc; acc += cnt[c]; }
        off[NCC] = acc;
    }
    __syncthreads();
    if (tid < NCC) cur[tid] = off[tid];
    __syncthreads();
    for (int v = tid; v < VV; v += 1024) {
        int c = w2s[v * SPWW] >> 6;
        int pos = atomicAdd(&cur[c], 1);
        wlist[pos] = v;
    }
    if (tid < NCC) { counts[tid] = cnt[tid]; offsets[tid] = off[tid]; }
    if (tid == 0) offsets[NCC] = off[NCC];
}

// ---------------- MFMA MLP layer: Y = (relu(X@W + b) [+ res]) * oscale, bf16 I/O ----------------
__global__ __launch_bounds__(256) void fhmm_mlp_mfma(
    const u16* __restrict__ Xbf, const u16* __restrict__ Wt,
    const float* __restrict__ bias, const u16* __restrict__ resbf,
    u16* __restrict__ Ybf, float oscale)
{
    int m0 = blockIdx.x * 64, n0 = blockIdx.y * 64;
    __shared__ char Xs[32768];
    __shared__ char Ws[32768];
    int tid = threadIdx.x, w = tid >> 6, lane = tid & 63, lr = lane & 15, lg = lane >> 4;
    const char* xsrc = (const char*)(Xbf + (size_t)m0 * HH);
    const char* wsrc = (const char*)(Wt + (size_t)n0 * HH);
    #pragma unroll
    for (int i = 0; i < 8; ++i) {
        int cc = i * 256 + tid; int row = cc >> 5, tt = cc & 31;
        int dst = row * 512 + ((tt ^ (row & 7)) << 4);
        *(uint4*)&Xs[dst] = *(const uint4*)(xsrc + cc * 16);
        *(uint4*)&Ws[dst] = *(const uint4*)(wsrc + cc * 16);
    }
    __syncthreads();
    short8 bfr[8];
    int brow = w * 16 + lr, bb = brow * 512, bsw = (brow & 7) << 4;
    #pragma unroll
    for (int ks = 0; ks < 8; ++ks)
        bfr[ks] = *(const short8*)(Ws + bb + (((ks * 4 + lg) << 4) ^ bsw));
    int cb = w * 16 + lg * 4;
    f32x4 bv = *(const f32x4*)(bias + n0 + cb);
    #pragma unroll
    for (int rm = 0; rm < 4; ++rm) {
        f32x4 acc = {0.f, 0.f, 0.f, 0.f};
        int ar = rm * 16 + lr, ab = ar * 512, asw = (ar & 7) << 4;
        #pragma unroll
        for (int ks = 0; ks < 8; ++ks) {
            short8 af = *(const short8*)(Xs + ab + (((ks * 4 + lg) << 4) ^ asw));
            acc = __builtin_amdgcn_mfma_f32_16x16x32_bf16(bfr[ks], af, acc, 0, 0, 0);
        }
        int gm = m0 + rm * 16 + lr;
        ushort4 o;
        if (resbf) {
            const u16* rp = resbf + (size_t)gm * HH + n0 + cb;
            #pragma unroll
            for (int e = 0; e < 4; ++e)
                ((u16*)&o)[e] = f2bf((fmaxf(acc[e] + bv[e], 0.f) + bf2f(rp[e])) * oscale);
        } else {
            #pragma unroll
            for (int e = 0; e < 4; ++e)
                ((u16*)&o)[e] = f2bf(fmaxf(acc[e] + bv[e], 0.f) * oscale);
        }
        *(ushort4*)(Ybf + (size_t)gm * HH + n0 + cb) = o;
    }
}

// ---------------- generic small GEMM: C[M][ldc] = A(bf16 [M][256]) @ B(bf16 [N][256])^T ----------------
__global__ __launch_bounds__(256) void fhmm_gemm_nt(
    const u16* __restrict__ Abf, const u16* __restrict__ Bbf,
    float* __restrict__ C, int ldc)
{
    int m0 = blockIdx.x * 64, n0 = blockIdx.y * 64;
    __shared__ char Xs[32768];
    __shared__ char Ws[32768];
    int tid = threadIdx.x, w = tid >> 6, lane = tid & 63, lr = lane & 15, lg = lane >> 4;
    const char* xsrc = (const char*)(Abf + (size_t)m0 * HH);
    const char* wsrc = (const char*)(Bbf + (size_t)n0 * HH);
    #pragma unroll
    for (int i = 0; i < 8; ++i) {
        int cc = i * 256 + tid; int row = cc >> 5, tt = cc & 31;
        int dst = row * 512 + ((tt ^ (row & 7)) << 4);
        *(uint4*)&Xs[dst] = *(const uint4*)(xsrc + cc * 16);
        *(uint4*)&Ws[dst] = *(const uint4*)(wsrc + cc * 16);
    }
    __syncthreads();
    short8 bfr[8];
    int brow = w * 16 + lr, bb = brow * 512, bsw = (brow & 7) << 4;
    #pragma unroll
    for (int ks = 0; ks < 8; ++ks)
        bfr[ks] = *(const short8*)(Ws + bb + (((ks * 4 + lg) << 4) ^ bsw));
    int cb = w * 16 + lg * 4;
    #pragma unroll
    for (int rm = 0; rm < 4; ++rm) {
        f32x4 acc = {0.f, 0.f, 0.f, 0.f};
        int ar = rm * 16 + lr, ab = ar * 512, asw = (ar & 7) << 4;
        #pragma unroll
        for (int ks = 0; ks < 8; ++ks) {
            short8 af = *(const short8*)(Xs + ab + (((ks * 4 + lg) << 4) ^ asw));
            acc = __builtin_amdgcn_mfma_f32_16x16x32_bf16(bfr[ks], af, acc, 0, 0, 0);
        }
        int gm = m0 + rm * 16 + lr;
        *(f32x4*)(C + (size_t)gm * ldc + n0 + cb) = acc;
    }
}

// ---------------- lse_trans2[s] = lse2(U2[s]) + lse2(V2[s]) ----------------
__global__ __launch_bounds__(256) void fhmm_lse_uv(
    const float* __restrict__ U2, const float* __restrict__ V2,
    float* __restrict__ lse2)
{
    int tid = threadIdx.x, w = tid >> 6, lane = tid & 63;
    int s = blockIdx.x * 4 + w;
    float u0 = U2[(size_t)s * NCC + lane];
    float u1 = U2[(size_t)s * NCC + 64 + lane];
    float vv = V2[(size_t)s * SPWW + lane];
    float mu = fmaxf(u0, u1);
    #pragma unroll
    for (int d = 32; d; d >>= 1) mu = fmaxf(mu, __shfl_xor(mu, d));
    float su = ex2(u0 - mu) + ex2(u1 - mu);
    #pragma unroll
    for (int d = 32; d; d >>= 1) su += __shfl_xor(su, d);
    float mv = vv;
    #pragma unroll
    for (int d = 32; d; d >>= 1) mv = fmaxf(mv, __shfl_xor(mv, d));
    float sv = ex2(vv - mv);
    #pragma unroll
    for (int d = 32; d; d >>= 1) sv += __shfl_xor(sv, d);
    if (lane == 0) lse2[s] = (mu + lg2(su)) + (mv + lg2(sv));
}

// ---------------- start head: dot with pw (bf16 h) ----------------
__global__ __launch_bounds__(256) void fhmm_dotpw_kernel(
    const u16* __restrict__ hb, const float* __restrict__ pw,
    const float* __restrict__ pbp, float* __restrict__ p)
{
    int wv = threadIdx.x >> 6;
    int lane = threadIdx.x & 63;
    int s = blockIdx.x * 4 + wv;
    const u16* hr = hb + (size_t)s * HH;
    float acc = 0.f;
    #pragma unroll
    for (int i = 0; i < 4; ++i) acc += bf2f(hr[i * 64 + lane]) * pw[i * 64 + lane];
    #pragma unroll
    for (int d = 32; d; d >>= 1) acc += __shfl_xor(acc, d);
    if (lane == 0) p[s] = acc + pbp[0];
}

// ---------------- in-place log_softmax over a length-8192 vector ----------------
__global__ __launch_bounds__(1024) void fhmm_lsm_vec_kernel(float* __restrict__ p)
{
    __shared__ float red[64];
    int tid = threadIdx.x;
    float m = -1e30f;
    for (int i = tid; i < CST; i += 1024) m = fmaxf(m, p[i]);
    #pragma unroll
    for (int d = 32; d; d >>= 1) m = fmaxf(m, __shfl_xor(m, d));
    if ((tid & 63) == 0) red[tid >> 6] = m;
    __syncthreads();
    if (tid == 0) {
        float mm = red[0];
        for (int q = 1; q < 16; ++q) mm = fmaxf(mm, red[q]);
        red[32] = mm;
    }
    __syncthreads();
    float M = red[32];
    float s = 0.f;
    for (int i = tid; i < CST; i += 1024) s += expf(p[i] - M);
    #pragma unroll
    for (int d = 32; d; d >>= 1) s += __shfl_xor(s, d);
    if ((tid & 63) == 0) red[tid >> 6] = s;
    __syncthreads();
    if (tid == 0) {
        float ss = 0.f;
        for (int q = 0; q < 16; ++q) ss += red[q];
        red[33] = ss;
    }
    __syncthreads();
    float lse = M + logf(red[33]);
    for (int i = tid; i < CST; i += 1024) p[i] -= lse;
}

// ---------------- per-class emission GEMM: Ew[v][k] = H_c @ pwT[v] + pb[v] ----------------
__global__ __launch_bounds__(256) void fhmm_ew_mfma(
    const u16* __restrict__ hpre_bf, const u16* __restrict__ pwT,
    const float* __restrict__ pb, const int* __restrict__ wlist,
    const int* __restrict__ counts, const int* __restrict__ offsets,
    float* __restrict__ Ew)
{
    int c = blockIdx.x;
    int cnt = counts[c], off = offsets[c];
    __shared__ char Hs[32768];
    int tid = threadIdx.x, w = tid >> 6, lane = tid & 63, lr = lane & 15, lg = lane >> 4;
    const char* src = (const char*)(hpre_bf + (size_t)c * 64 * HH);
    #pragma unroll
    for (int i = 0; i < 8; ++i) {
        int cc = i * 256 + tid; int row = cc >> 5, tt = cc & 31;
        *(uint4*)&Hs[row * 512 + ((tt ^ (row & 7)) << 4)] = *(const uint4*)(src + cc * 16);
    }
    __syncthreads();
    for (int ch = 0; ch * 64 < cnt; ++ch) {
        int widx = ch * 64 + w * 16 + lr;
        bool valid = widx < cnt;
        int v = valid ? wlist[off + widx] : 0;
        short8 bw[8];
        short8 bz = {0, 0, 0, 0, 0, 0, 0, 0};
        #pragma unroll
        for (int ks = 0; ks < 8; ++ks)
            bw[ks] = valid ? *(const short8*)(pwT + (size_t)v * HH + ks * 32 + lg * 8) : bz;
        float pbv = valid ? pb[v] : 0.f;
        #pragma unroll
        for (int rm = 0; rm < 4; ++rm) {
            f32x4 acc = {0.f, 0.f, 0.f, 0.f};
            int ar = rm * 16 + lr, ab = ar * 512, asw = (ar & 7) << 4;
            #pragma unroll
            for (int ks = 0; ks < 8; ++ks) {
                short8 ah = *(const short8*)(Hs + ab + (((ks * 4 + lg) << 4) ^ asw));
                acc = __builtin_amdgcn_mfma_f32_16x16x32_bf16(ah, bw[ks], acc, 0, 0, 0);
            }
            if (valid) {
                f32x4 o;
                #pragma unroll
                for (int e = 0; e < 4; ++e) o[e] = acc[e] + pbv;
                *(f32x4*)(Ew + (size_t)v * 64 + rm * 16 + lg * 4) = o;
            }
        }
    }
}

// ---------------- per-state emission lse ----------------
__global__ __launch_bounds__(64) void fhmm_lse_em_kernel(
    const float* __restrict__ Ew, const int* __restrict__ wlist,
    const int* __restrict__ counts, const int* __restrict__ offsets,
    float* __restrict__ lse_em)
{
    int c = blockIdx.x, k = threadIdx.x;
    int cnt = counts[c], off = offsets[c];
    float m = -1e30f;
    for (int i = 0; i < cnt; ++i) m = fmaxf(m, Ew[wlist[off + i] * 64 + k]);
    float s = 0.f;
    for (int i = 0; i < cnt; ++i) s += __expf(Ew[wlist[off + i] * 64 + k] - m);
    lse_em[c * 64 + k] = (cnt > 0) ? (m + logf(s)) : -1e30f;
}

// ---------------- obs2[b,t,k] (base-2 prescaled) ----------------
__global__ __launch_bounds__(64) void fhmm_obs_kernel(
    const float* __restrict__ Ew, const float* __restrict__ lse_em,
    const int* __restrict__ text, const int* __restrict__ w2s,
    float* __restrict__ obs2)
{
    int i = blockIdx.x;      // b*T + t
    int k = threadIdx.x;
    int v = text[i];
    int s = w2s[v * SPWW + k];
    obs2[i * 64 + k] = (Ew[v * 64 + k] - lse_em[s]) * LOG2E;
}

// ================= TREE COMBINE: C = A (x) B in lse2 semiring ==================
// MODE 0 (level 1): M_t[i][j] = U2[sr_{t-1}+i][c_t] + V2[sr_{t-1}+i][j]
//                              - lse_trans2[sr_{t-1}+i] + obs2[t][j]
//   (U-term and lse fold into the per-row offset; obs folds into per-col for B)
// MODE 1: A,B read from f32 level buffer [b][2*pairs][64][64].
template<int MODE>
__global__ __launch_bounds__(256) void fhmm_combine(
    const float* __restrict__ U2, const float* __restrict__ V2,
    const float* __restrict__ obs2, const float* __restrict__ lse_trans2,
    const int* __restrict__ text, const int* __restrict__ w2s,
    const float* __restrict__ Lin, float* __restrict__ Lout, int pairs)
{
    int p = blockIdx.x, b = blockIdx.y;
    int tid = threadIdx.x;
    int l6 = tid & 63, q = tid >> 6;

    __shared__ char Ps[8192];            // P [i][k] bf16, 128B rows, swizzled
    __shared__ char Qs[8192];            // Qt [j][k] bf16
    __shared__ float mA2[64], mB2[64];   // output offsets
    __shared__ float mAf[64], mBf[64];   // maxes used inside exp2
    __shared__ float part[2][4][64];
    __shared__ float rtB_l[64];

    float va[16], vb[16];
    float rowA = 0.f, obB = 0.f;
    float* Co = Lout + ((size_t)(b * pairs + p)) * 4096;

    if (MODE == 0) {
        int tA = 2 * p + 1, tB = 2 * p + 2;
        int i = l6;
        int srA = w2s[text[b * TTT + (tA - 1)] * SPWW];
        int cA  = w2s[text[b * TTT + tA] * SPWW] >> 6;
        rowA = U2[(size_t)(srA + i) * NCC + cA] - lse_trans2[srA + i];
        const float* vrow = V2 + (size_t)(srA + i) * SPWW;
        const float* orow = obs2 + (size_t)(b * TTT + tA) * 64;
        float mloc = -3e38f;
        #pragma unroll
        for (int jj = 0; jj < 16; ++jj) {
            int j = q * 16 + jj;
            float v = vrow[j] + orow[j];
            va[jj] = v; mloc = fmaxf(mloc, v);
        }
        if (tB > 255) {          // B = identity: C = M_A exactly
            #pragma unroll
            for (int jj = 0; jj < 16; ++jj)
                Co[i * 64 + q * 16 + jj] = va[jj] + rowA;
            return;
        }
        part[0][q][i] = mloc;
        int srB = w2s[text[b * TTT + (tB - 1)] * SPWW];
        int cB  = w2s[text[b * TTT + tB] * SPWW] >> 6;
        if (tid < 64)
            rtB_l[tid] = U2[(size_t)(srB + tid) * NCC + cB] - lse_trans2[srB + tid];
        obB = obs2[(size_t)(b * TTT + tB) * 64 + l6];
        // raw V2 column loads for B side: k = q*16+kk, j = l6
        float vraw[16];
        #pragma unroll
        for (int kk = 0; kk < 16; ++kk)
            vraw[kk] = V2[(size_t)(srB + q * 16 + kk) * SPWW + l6];
        __syncthreads();
        float mlocB = -3e38f;
        #pragma unroll
        for (int kk = 0; kk < 16; ++kk) {
            vb[kk] = vraw[kk] + rtB_l[q * 16 + kk];
            mlocB = fmaxf(mlocB, vb[kk]);
        }
        part[1][q][l6] = mlocB;
    } else {
        const float* Af = Lin + ((size_t)(b * (2 * pairs) + 2 * p)) * 4096;
        const float* Bf = Af + 4096;
        float mloc = -3e38f;
        #pragma unroll
        for (int jj = 0; jj < 16; ++jj) {
            float v = Af[l6 * 64 + q * 16 + jj];
            va[jj] = v; mloc = fmaxf(mloc, v);
        }
        part[0][q][l6] = mloc;
        float mlocB = -3e38f;
        #pragma unroll
        for (int kk = 0; kk < 16; ++kk) {
            float v = Bf[(q * 16 + kk) * 64 + l6];
            vb[kk] = v; mlocB = fmaxf(mlocB, v);
        }
        part[1][q][l6] = mlocB;
        __syncthreads();
    }
    __syncthreads();

    if (tid < 64) {
        float mf = fmaxf(fmaxf(part[0][0][tid], part[0][1][tid]),
                         fmaxf(part[0][2][tid], part[0][3][tid]));
        mAf[tid] = mf;
        mA2[tid] = (MODE == 0) ? (mf + rowA) : mf;
    } else if (tid < 128) {
        int j = tid & 63;
        float mf = fmaxf(fmaxf(part[1][0][j], part[1][1][j]),
                         fmaxf(part[1][2][j], part[1][3][j]));
        mBf[j] = mf;
        mB2[j] = (MODE == 0) ? (mf + obB) : mf;
    }
    __syncthreads();

    {
        float ma = mAf[l6];
        u16 pk[16];
        #pragma unroll
        for (int e = 0; e < 16; ++e) pk[e] = f2bf(ex2(va[e] - ma));
        uint4* src = (uint4*)pk;
        int base = l6 * 128;
        int s0 = 2 * q, s1 = 2 * q + 1, sw = (l6 & 7);
        *(uint4*)&Ps[base + (((s0 ^ sw)) << 4)] = src[0];
        *(uint4*)&Ps[base + (((s1 ^ sw)) << 4)] = src[1];
        float mb = mBf[l6];
        #pragma unroll
        for (int e = 0; e < 16; ++e) pk[e] = f2bf(ex2(vb[e] - mb));
        *(uint4*)&Qs[base + (((s0 ^ sw)) << 4)] = src[0];
        *(uint4*)&Qs[base + (((s1 ^ sw)) << 4)] = src[1];
    }
    __syncthreads();

    int w = q, lr = l6 & 15, lg = l6 >> 4;
    int brow = w * 16 + lr;
    short8 bfr[2];
    #pragma unroll
    for (int ks = 0; ks < 2; ++ks)
        bfr[ks] = *(const short8*)(Qs + brow * 128 + ((((ks * 4 + lg)) << 4) ^ ((brow & 7) << 4)));
    #pragma unroll
    for (int rm = 0; rm < 4; ++rm) {
        f32x4 acc = {0.f, 0.f, 0.f, 0.f};
        int ar = rm * 16 + lr;
        #pragma unroll
        for (int ks = 0; ks < 2; ++ks) {
            short8 af = *(const short8*)(Ps + ar * 128 + ((((ks * 4 + lg)) << 4) ^ ((ar & 7) << 4)));
            acc = __builtin_amdgcn_mfma_f32_16x16x32_bf16(af, bfr[ks], acc, 0, 0, 0);
        }
        #pragma unroll
        for (int e = 0; e < 4; ++e) {
            int ii = rm * 16 + lg * 4 + e;
            int jj = w * 16 + lr;
            Co[ii * 64 + jj] = mA2[ii] + mB2[jj] + lg2(fmaxf(acc[e], 1e-33f));
        }
    }
}

// ---------------- final: out[b] = LN2 * lse2_{i,j}( a0_2[i] + Mtot[i][j] ) ----------------
__global__ __launch_bounds__(256) void fhmm_final(
    const float* __restrict__ startv, const float* __restrict__ obs2,
    const float* __restrict__ Mtot, const int* __restrict__ text,
    const int* __restrict__ w2s, float* __restrict__ out)
{
    int b = blockIdx.x, tid = threadIdx.x;
    __shared__ float a0[64];
    __shared__ float rm_[4], rs_[4];
    if (tid < 64) {
        int s0 = w2s[text[b * TTT] * SPWW];
        a0[tid] = startv[s0 + tid] * LOG2E + obs2[(size_t)(b * TTT) * 64 + tid];
    }
    __syncthreads();
    const float* M = Mtot + (size_t)b * 4096;
    float m = -3e38f, s = 0.f;
    for (int e = tid; e < 4096; e += 256) {
        float v = a0[e >> 6] + M[e];
        float mn = fmaxf(m, v);
        s = s * ex2(m - mn) + ex2(v - mn);
        m = mn;
    }
    #pragma unroll
    for (int d = 32; d; d >>= 1) {
        float m2 = __shfl_xor(m, d), sx = __shfl_xor(s, d);
        float mn = fmaxf(m, m2);
        s = s * ex2(m - mn) + sx * ex2(m2 - mn); m = mn;
    }
    if ((tid & 63) == 0) { rm_[tid >> 6] = m; rs_[tid >> 6] = s; }
    __syncthreads();
    if (tid == 0) {
        float M_ = rm_[0], S_ = rs_[0];
        #pragma unroll
        for (int qq = 1; qq < 4; ++qq) {
            float mn = fmaxf(M_, rm_[qq]);
            S_ = S_ * ex2(M_ - mn) + rs_[qq] * ex2(rm_[qq] - mn); M_ = mn;
        }
        out[b] = (M_ + lg2(S_)) * LN2;
    }
}

extern "C" void kernel_launch(void* const* d_in, const int* in_sizes, int n_in,
                              void* d_out, int out_size, void* d_ws, size_t ws_size,
                              hipStream_t stream) {
    const int* text        = (const int*)d_in[0];
    const int* w2s         = (const int*)d_in[1];
    const float* se1_start = (const float*)d_in[2];
    const float* se2_start = (const float*)d_in[3];
    const float* start_w1  = (const float*)d_in[4];
    const float* start_b1  = (const float*)d_in[5];
    const float* start_w2  = (const float*)d_in[6];
    const float* start_b2  = (const float*)d_in[7];
    const float* start_pw  = (const float*)d_in[8];
    const float* start_pb  = (const float*)d_in[9];
    const float* se1_state = (const float*)d_in[10];
    const float* se2_state = (const float*)d_in[11];
    const float* se1_next  = (const float*)d_in[12];
    const float* se2_next  = (const float*)d_in[13];
    const float* trans_w1  = (const float*)d_in[14];
    const float* trans_b1  = (const float*)d_in[15];
    const float* trans_w2  = (const float*)d_in[16];
    const float* trans_b2  = (const float*)d_in[17];
    const float* se1_pre   = (const float*)d_in[18];
    const float* se2_pre   = (const float*)d_in[19];
    const float* term_w1   = (const float*)d_in[20];
    const float* term_b1   = (const float*)d_in[21];
    const float* term_w2   = (const float*)d_in[22];
    const float* term_b2   = (const float*)d_in[23];
    const float* term_pw   = (const float*)d_in[24];
    const float* term_pb   = (const float*)d_in[25];
    float* out = (float*)d_out;

    char* wp = (char*)d_ws;
    auto alloc = [&](size_t bytes) {
        char* p = wp;
        wp += (bytes + 255) & ~(size_t)255;
        return (void*)p;
    };
    u16* emb_start   = (u16*)alloc((size_t)CST * HH * 2);
    u16* emb_state   = (u16*)alloc((size_t)CST * HH * 2);
    u16* emb_pre     = (u16*)alloc((size_t)CST * HH * 2);
    u16* h1_bf       = (u16*)alloc((size_t)CST * HH * 2);
    u16* hstart_bf   = (u16*)alloc((size_t)CST * HH * 2);
    u16* h_state_bf  = (u16*)alloc((size_t)CST * HH * 2);
    u16* h_pre_bf    = (u16*)alloc((size_t)CST * HH * 2);
    u16* Wt          = (u16*)alloc((size_t)6 * HH * HH * 2);
    u16* pwT         = (u16*)alloc((size_t)VV * HH * 2);
    u16* e1n_bf      = (u16*)alloc((size_t)NCC * HH * 2);
    u16* e2n_bf      = (u16*)alloc((size_t)SPWW * HH * 2);
    float* U2        = (float*)alloc((size_t)CST * NCC * 4);
    float* V2        = (float*)alloc((size_t)CST * SPWW * 4);
    float* startv    = (float*)alloc(CST * 4);
    float* lse_trans = (float*)alloc(CST * 4);
    float* lse_em    = (float*)alloc(CST * 4);
    float* Ew        = (float*)alloc((size_t)VV * 64 * 4);
    int* counts      = (int*)alloc(NCC * 4);
    int* offsets     = (int*)alloc((NCC + 4) * 4);
    int* wlist       = (int*)alloc(VV * 4);
    float* obs       = (float*)alloc((size_t)BBB * TTT * 64 * 4);
    float* Lv0       = (float*)alloc((size_t)BBB * 128 * 4096 * 4);
    float* Lv1       = (float*)alloc((size_t)BBB * 64 * 4096 * 4);

    // weight transposes (all in one) + pw transpose + small next-factor embs
    Ptr6 wargs = {{start_w1, start_w2, trans_w1, trans_w2, term_w1, term_w2}};
    hipLaunchKernelGGL(fhmm_wtrans_all, dim3(4, 4, 6), 256, 0, stream, wargs, Wt);
    hipLaunchKernelGGL(fhmm_pwtrans_kernel, dim3((VV + 63) / 64, 4), 256, 0, stream,
                       term_pw, pwT);
    hipLaunchKernelGGL(fhmm_emb_next_small, dim3(128), 256, 0, stream,
                       se1_next, se2_next, e1n_bf, e2n_bf);

    // class word-lists (single block)
    hipLaunchKernelGGL(fhmm_wordlist, dim3(1), 1024, 0, stream,
                       w2s, counts, offsets, wlist);

    // 3 big embeddings
    EmbA eargs = {{se1_start, se1_state, se1_pre},
                  {se2_start, se2_state, se2_pre},
                  {emb_start, emb_state, emb_pre}};
    hipLaunchKernelGGL(fhmm_emb_all, dim3(8192, 3), 256, 0, stream, eargs);

    dim3 mmGrid(128, 4);
    // start head
    hipLaunchKernelGGL(fhmm_mlp_mfma, mmGrid, 256, 0, stream,
                       emb_start, Wt + 0 * HH * HH, start_b1, (const u16*)nullptr, h1_bf, 1.0f);
    hipLaunchKernelGGL(fhmm_mlp_mfma, mmGrid, 256, 0, stream,
                       h1_bf, Wt + 1 * HH * HH, start_b2, emb_start, hstart_bf, 1.0f);
    hipLaunchKernelGGL(fhmm_dotpw_kernel, dim3(2048), 256, 0, stream,
                       hstart_bf, start_pw, start_pb, startv);
    hipLaunchKernelGGL(fhmm_lsm_vec_kernel, dim3(1), 1024, 0, stream, startv);

    // state head (output prescaled by log2e -> base-2 logits downstream)
    hipLaunchKernelGGL(fhmm_mlp_mfma, mmGrid, 256, 0, stream,
                       emb_state, Wt + 2 * HH * HH, trans_b1, (const u16*)nullptr, h1_bf, 1.0f);
    hipLaunchKernelGGL(fhmm_mlp_mfma, mmGrid, 256, 0, stream,
                       h1_bf, Wt + 3 * HH * HH, trans_b2, emb_state, h_state_bf, LOG2E);

    // pre head
    hipLaunchKernelGGL(fhmm_mlp_mfma, mmGrid, 256, 0, stream,
                       emb_pre, Wt + 4 * HH * HH, term_b1, (const u16*)nullptr, h1_bf, 1.0f);
    hipLaunchKernelGGL(fhmm_mlp_mfma, mmGrid, 256, 0, stream,
                       h1_bf, Wt + 5 * HH * HH, term_b2, emb_pre, h_pre_bf, 1.0f);

    // U2 = h_state2 @ e1n^T   (8192 x 128), V2 = h_state2 @ e2n^T (8192 x 64)
    hipLaunchKernelGGL(fhmm_gemm_nt, dim3(128, 2), 256, 0, stream,
                       h_state_bf, e1n_bf, U2, NCC);
    hipLaunchKernelGGL(fhmm_gemm_nt, dim3(128, 1), 256, 0, stream,
                       h_state_bf, e2n_bf, V2, SPWW);
    // lse_trans2 = lse2(U2 row) + lse2(V2 row)
    hipLaunchKernelGGL(fhmm_lse_uv, dim3(2048), 256, 0, stream, U2, V2, lse_trans);

    // emission
    hipLaunchKernelGGL(fhmm_ew_mfma, dim3(NCC), 256, 0, stream,
                       h_pre_bf, pwT, term_pb, wlist, counts, offsets, Ew);
    hipLaunchKernelGGL(fhmm_lse_em_kernel, dim3(NCC), 64, 0, stream,
                       Ew, wlist, counts, offsets, lse_em);
    hipLaunchKernelGGL(fhmm_obs_kernel, dim3(BBB * TTT), 64, 0, stream,
                       Ew, lse_em, text, w2s, obs);

    // ---- tree reduction over transition matrices ----
    hipLaunchKernelGGL((fhmm_combine<0>), dim3(128, BBB), 256, 0, stream,
                       U2, V2, obs, lse_trans, text, w2s,
                       (const float*)nullptr, Lv0, 128);
    float* cin = Lv0;
    const int lv_sizes[7] = {64, 32, 16, 8, 4, 2, 1};
    for (int li = 0; li < 7; ++li) {
        float* cout = (cin == Lv0) ? Lv1 : Lv0;
        hipLaunchKernelGGL((fhmm_combine<1>), dim3(lv_sizes[li], BBB), 256, 0, stream,
                           (const float*)nullptr, (const float*)nullptr,
                           (const float*)nullptr, (const float*)nullptr,
                           (const int*)nullptr, (const int*)nullptr,
                           cin, cout, lv_sizes[li]);
        cin = cout;
    }

    // ---- final apply + lse ----
    hipLaunchKernelGGL(fhmm_final, dim3(BBB), 256, 0, stream,
                       startv, obs, cin, text, w2s, out);
}

// Round 9
// 161.887 us; speedup vs baseline: 3.5416x; 1.2375x over previous
//
#include <hip/hip_runtime.h>
#include <hip/hip_bf16.h>
#include <math.h>

#define HH 256
#define NCC 128
#define SPWW 64
#define CST 8192
#define VV 10000
#define BBB 16
#define TTT 256
#define LOG2E 1.4426950408889634f
#define LN2 0.6931471805599453f

typedef __attribute__((ext_vector_type(8))) short short8;
typedef __attribute__((ext_vector_type(4))) float f32x4;
typedef unsigned short u16;

struct Ptr6 { const float* p[6]; };
struct EmbA { const float* e1[3]; const float* e2[3]; u16* out[3]; };

__device__ inline float bf2f(u16 u) {
    union { unsigned int i; float f; } v; v.i = ((unsigned int)u) << 16; return v.f;
}
__device__ inline u16 f2bf(float f) {
    __hip_bfloat16 h = __float2bfloat16(f);
    return *reinterpret_cast<u16*>(&h);
}
__device__ inline float ex2(float x) { return __builtin_amdgcn_exp2f(x); }
__device__ inline float lg2(float x) { return __builtin_amdgcn_logf(x); }   // v_log_f32 = log2

// ---------------- 3 big embeddings in one kernel (bf16 out) ----------------
__global__ __launch_bounds__(256) void fhmm_emb_all(EmbA a)
{
    int hd = blockIdx.y;
    const float* e1 = a.e1[hd];
    const float* e2 = a.e2[hd];
    u16* out = a.out[hd];
    int idx = blockIdx.x * 256 + threadIdx.x;   // over 8192*256
    int s = idx >> 8, h = idx & 255;
    out[idx] = f2bf(e1[(s >> 6) * HH + h] + e2[(s & 63) * HH + h]);
}

// ---------------- next-state factor embeddings to bf16 (small) ----------------
__global__ __launch_bounds__(256) void fhmm_emb_next_small(
    const float* __restrict__ e1, const float* __restrict__ e2,
    u16* __restrict__ e1b, u16* __restrict__ e2b)
{
    int idx = blockIdx.x * 256 + threadIdx.x;
    if (idx < NCC * HH) e1b[idx] = f2bf(e1[idx]);
    if (idx < SPWW * HH) e2b[idx] = f2bf(e2[idx]);
}

// ---------------- all 6 weight transposes: Wt[n][k] = bf16(W[k][n]) ----------------
__global__ __launch_bounds__(256) void fhmm_wtrans_all(Ptr6 Ws, u16* __restrict__ Wt)
{
    __shared__ float t[64][65];
    const float* W = Ws.p[blockIdx.z];
    u16* dst = Wt + (size_t)blockIdx.z * HH * HH;
    int k0 = blockIdx.x * 64, n0 = blockIdx.y * 64, tid = threadIdx.x;
    #pragma unroll
    for (int i = 0; i < 16; ++i) {
        int idx = tid + i * 256; int r = idx >> 6, c = idx & 63;
        t[r][c] = W[(k0 + r) * HH + n0 + c];
    }
    __syncthreads();
    #pragma unroll
    for (int i = 0; i < 16; ++i) {
        int idx = tid + i * 256; int r = idx >> 6, c = idx & 63;
        dst[(n0 + r) * HH + k0 + c] = f2bf(t[c][r]);
    }
}

// ---------------- pw transpose: pwT[v][k] = bf16(pw[k][v]) ----------------
__global__ __launch_bounds__(256) void fhmm_pwtrans_kernel(
    const float* __restrict__ pw, u16* __restrict__ pwT)
{
    __shared__ float t[64][65];
    int v0 = blockIdx.x * 64, k0 = blockIdx.y * 64, tid = threadIdx.x;
    #pragma unroll
    for (int i = 0; i < 16; ++i) {
        int idx = tid + i * 256; int r = idx >> 6, c = idx & 63;   // r:k, c:v
        int v = v0 + c;
        t[r][c] = (v < VV) ? pw[(size_t)(k0 + r) * VV + v] : 0.f;
    }
    __syncthreads();
    #pragma unroll
    for (int i = 0; i < 16; ++i) {
        int idx = tid + i * 256; int r = idx >> 6, c = idx & 63;   // r:v, c:k
        int v = v0 + r;
        if (v < VV) pwT[(size_t)v * HH + k0 + c] = f2bf(t[c][r]);
    }
}

// ---------------- word-list build: one block does hist+prefix+scatter ----------------
__global__ __launch_bounds__(1024) void fhmm_wordlist(
    const int* __restrict__ w2s, int* __restrict__ counts,
    int* __restrict__ offsets, int* __restrict__ wlist)
{
    __shared__ int cnt[NCC], off[NCC + 1], cur[NCC];
    int tid = threadIdx.x;
    if (tid < NCC) cnt[tid] = 0;
    __syncthreads();
    for (int v = tid; v < VV; v += 1024)
        atomicAdd(&cnt[w2s[v * SPWW] >> 6], 1);
    __syncthreads();
    if (tid == 0) {
        int acc = 0;
        for (int c = 0; c < NCC; ++c) { off[c] = acc; acc += cnt[c]; }
        off[NCC] = acc;
    }
    __syncthreads();
    if (tid < NCC) cur[tid] = off[tid];
    __syncthreads();
    for (int v = tid; v < VV; v += 1024) {
        int c = w2s[v * SPWW] >> 6;
        int pos = atomicAdd(&cur[c], 1);
        wlist[pos] = v;
    }
    if (tid < NCC) { counts[tid] = cnt[tid]; offsets[tid] = off[tid]; }
    if (tid == 0) offsets[NCC] = off[NCC];
}

// ---------------- MFMA MLP layer: Y = (relu(X@W + b) [+ res]) * oscale, bf16 I/O ----------------
__global__ __launch_bounds__(256) void fhmm_mlp_mfma(
    const u16* __restrict__ Xbf, const u16* __restrict__ Wt,
    const float* __restrict__ bias, const u16* __restrict__ resbf,
    u16* __restrict__ Ybf, float oscale)
{
    int m0 = blockIdx.x * 64, n0 = blockIdx.y * 64;
    __shared__ char Xs[32768];
    __shared__ char Ws[32768];
    int tid = threadIdx.x, w = tid >> 6, lane = tid & 63, lr = lane & 15, lg = lane >> 4;
    const char* xsrc = (const char*)(Xbf + (size_t)m0 * HH);
    const char* wsrc = (const char*)(Wt + (size_t)n0 * HH);
    #pragma unroll
    for (int i = 0; i < 8; ++i) {
        int cc = i * 256 + tid; int row = cc >> 5, tt = cc & 31;
        int dst = row * 512 + ((tt ^ (row & 7)) << 4);
        *(uint4*)&Xs[dst] = *(const uint4*)(xsrc + cc * 16);
        *(uint4*)&Ws[dst] = *(const uint4*)(wsrc + cc * 16);
    }
    __syncthreads();
    short8 bfr[8];
    int brow = w * 16 + lr, bb = brow * 512, bsw = (brow & 7) << 4;
    #pragma unroll
    for (int ks = 0; ks < 8; ++ks)
        bfr[ks] = *(const short8*)(Ws + bb + (((ks * 4 + lg) << 4) ^ bsw));
    int cb = w * 16 + lg * 4;
    f32x4 bv = *(const f32x4*)(bias + n0 + cb);
    #pragma unroll
    for (int rm = 0; rm < 4; ++rm) {
        f32x4 acc = {0.f, 0.f, 0.f, 0.f};
        int ar = rm * 16 + lr, ab = ar * 512, asw = (ar & 7) << 4;
        #pragma unroll
        for (int ks = 0; ks < 8; ++ks) {
            short8 af = *(const short8*)(Xs + ab + (((ks * 4 + lg) << 4) ^ asw));
            acc = __builtin_amdgcn_mfma_f32_16x16x32_bf16(bfr[ks], af, acc, 0, 0, 0);
        }
        int gm = m0 + rm * 16 + lr;
        ushort4 o;
        if (resbf) {
            const u16* rp = resbf + (size_t)gm * HH + n0 + cb;
            #pragma unroll
            for (int e = 0; e < 4; ++e)
                ((u16*)&o)[e] = f2bf((fmaxf(acc[e] + bv[e], 0.f) + bf2f(rp[e])) * oscale);
        } else {
            #pragma unroll
            for (int e = 0; e < 4; ++e)
                ((u16*)&o)[e] = f2bf(fmaxf(acc[e] + bv[e], 0.f) * oscale);
        }
        *(ushort4*)(Ybf + (size_t)gm * HH + n0 + cb) = o;
    }
}

// ---------------- generic small GEMM: C[M][ldc] = A(bf16 [M][256]) @ B(bf16 [N][256])^T ----------------
__global__ __launch_bounds__(256) void fhmm_gemm_nt(
    const u16* __restrict__ Abf, const u16* __restrict__ Bbf,
    float* __restrict__ C, int ldc)
{
    int m0 = blockIdx.x * 64, n0 = blockIdx.y * 64;
    __shared__ char Xs[32768];
    __shared__ char Ws[32768];
    int tid = threadIdx.x, w = tid >> 6, lane = tid & 63, lr = lane & 15, lg = lane >> 4;
    const char* xsrc = (const char*)(Abf + (size_t)m0 * HH);
    const char* wsrc = (const char*)(Bbf + (size_t)n0 * HH);
    #pragma unroll
    for (int i = 0; i < 8; ++i) {
        int cc = i * 256 + tid; int row = cc >> 5, tt = cc & 31;
        int dst = row * 512 + ((tt ^ (row & 7)) << 4);
        *(uint4*)&Xs[dst] = *(const uint4*)(xsrc + cc * 16);
        *(uint4*)&Ws[dst] = *(const uint4*)(wsrc + cc * 16);
    }
    __syncthreads();
    short8 bfr[8];
    int brow = w * 16 + lr, bb = brow * 512, bsw = (brow & 7) << 4;
    #pragma unroll
    for (int ks = 0; ks < 8; ++ks)
        bfr[ks] = *(const short8*)(Ws + bb + (((ks * 4 + lg) << 4) ^ bsw));
    int cb = w * 16 + lg * 4;
    #pragma unroll
    for (int rm = 0; rm < 4; ++rm) {
        f32x4 acc = {0.f, 0.f, 0.f, 0.f};
        int ar = rm * 16 + lr, ab = ar * 512, asw = (ar & 7) << 4;
        #pragma unroll
        for (int ks = 0; ks < 8; ++ks) {
            short8 af = *(const short8*)(Xs + ab + (((ks * 4 + lg) << 4) ^ asw));
            acc = __builtin_amdgcn_mfma_f32_16x16x32_bf16(bfr[ks], af, acc, 0, 0, 0);
        }
        int gm = m0 + rm * 16 + lr;
        *(f32x4*)(C + (size_t)gm * ldc + n0 + cb) = acc;
    }
}

// ---------------- lse_trans2[s] = lse2(U2[s]) + lse2(V2[s]) ----------------
__global__ __launch_bounds__(256) void fhmm_lse_uv(
    const float* __restrict__ U2, const float* __restrict__ V2,
    float* __restrict__ lse2)
{
    int tid = threadIdx.x, w = tid >> 6, lane = tid & 63;
    int s = blockIdx.x * 4 + w;
    float u0 = U2[(size_t)s * NCC + lane];
    float u1 = U2[(size_t)s * NCC + 64 + lane];
    float vv = V2[(size_t)s * SPWW + lane];
    float mu = fmaxf(u0, u1);
    #pragma unroll
    for (int d = 32; d; d >>= 1) mu = fmaxf(mu, __shfl_xor(mu, d));
    float su = ex2(u0 - mu) + ex2(u1 - mu);
    #pragma unroll
    for (int d = 32; d; d >>= 1) su += __shfl_xor(su, d);
    float mv = vv;
    #pragma unroll
    for (int d = 32; d; d >>= 1) mv = fmaxf(mv, __shfl_xor(mv, d));
    float sv = ex2(vv - mv);
    #pragma unroll
    for (int d = 32; d; d >>= 1) sv += __shfl_xor(sv, d);
    if (lane == 0) lse2[s] = (mu + lg2(su)) + (mv + lg2(sv));
}

// ---------------- start head: dot with pw (bf16 h) ----------------
__global__ __launch_bounds__(256) void fhmm_dotpw_kernel(
    const u16* __restrict__ hb, const float* __restrict__ pw,
    const float* __restrict__ pbp, float* __restrict__ p)
{
    int wv = threadIdx.x >> 6;
    int lane = threadIdx.x & 63;
    int s = blockIdx.x * 4 + wv;
    const u16* hr = hb + (size_t)s * HH;
    float acc = 0.f;
    #pragma unroll
    for (int i = 0; i < 4; ++i) acc += bf2f(hr[i * 64 + lane]) * pw[i * 64 + lane];
    #pragma unroll
    for (int d = 32; d; d >>= 1) acc += __shfl_xor(acc, d);
    if (lane == 0) p[s] = acc + pbp[0];
}

// ---------------- in-place log_softmax over a length-8192 vector ----------------
__global__ __launch_bounds__(1024) void fhmm_lsm_vec_kernel(float* __restrict__ p)
{
    __shared__ float red[64];
    int tid = threadIdx.x;
    float m = -1e30f;
    for (int i = tid; i < CST; i += 1024) m = fmaxf(m, p[i]);
    #pragma unroll
    for (int d = 32; d; d >>= 1) m = fmaxf(m, __shfl_xor(m, d));
    if ((tid & 63) == 0) red[tid >> 6] = m;
    __syncthreads();
    if (tid == 0) {
        float mm = red[0];
        for (int q = 1; q < 16; ++q) mm = fmaxf(mm, red[q]);
        red[32] = mm;
    }
    __syncthreads();
    float M = red[32];
    float s = 0.f;
    for (int i = tid; i < CST; i += 1024) s += expf(p[i] - M);
    #pragma unroll
    for (int d = 32; d; d >>= 1) s += __shfl_xor(s, d);
    if ((tid & 63) == 0) red[tid >> 6] = s;
    __syncthreads();
    if (tid == 0) {
        float ss = 0.f;
        for (int q = 0; q < 16; ++q) ss += red[q];
        red[33] = ss;
    }
    __syncthreads();
    float lse = M + logf(red[33]);
    for (int i = tid; i < CST; i += 1024) p[i] -= lse;
}

// ---------------- per-class emission GEMM + fused per-state lse ----------------
// Ew2[v][k] = (H_c @ pwT[v] + pb[v]) * log2e ; lse_em2[s] = lse2_words(Ew2)
__global__ __launch_bounds__(256) void fhmm_ew_mfma(
    const u16* __restrict__ hpre_bf, const u16* __restrict__ pwT,
    const float* __restrict__ pb, const int* __restrict__ wlist,
    const int* __restrict__ counts, const int* __restrict__ offsets,
    float* __restrict__ Ew2, float* __restrict__ lse_em2)
{
    int c = blockIdx.x;
    int cnt = counts[c], off = offsets[c];
    __shared__ char Hs[32768];
    __shared__ float emM[4][64], emS[4][64];
    int tid = threadIdx.x, w = tid >> 6, lane = tid & 63, lr = lane & 15, lg = lane >> 4;
    const char* src = (const char*)(hpre_bf + (size_t)c * 64 * HH);
    #pragma unroll
    for (int i = 0; i < 8; ++i) {
        int cc = i * 256 + tid; int row = cc >> 5, tt = cc & 31;
        *(uint4*)&Hs[row * 512 + ((tt ^ (row & 7)) << 4)] = *(const uint4*)(src + cc * 16);
    }
    __syncthreads();

    float em_m[4][4], em_s[4][4];
    #pragma unroll
    for (int rm = 0; rm < 4; ++rm)
        #pragma unroll
        for (int e = 0; e < 4; ++e) { em_m[rm][e] = -3e38f; em_s[rm][e] = 0.f; }

    for (int ch = 0; ch * 64 < cnt; ++ch) {
        int widx = ch * 64 + w * 16 + lr;
        bool valid = widx < cnt;
        int v = valid ? wlist[off + widx] : 0;
        short8 bw[8];
        short8 bz = {0, 0, 0, 0, 0, 0, 0, 0};
        #pragma unroll
        for (int ks = 0; ks < 8; ++ks)
            bw[ks] = valid ? *(const short8*)(pwT + (size_t)v * HH + ks * 32 + lg * 8) : bz;
        float pbv = valid ? pb[v] : 0.f;
        #pragma unroll
        for (int rm = 0; rm < 4; ++rm) {
            f32x4 acc = {0.f, 0.f, 0.f, 0.f};
            int ar = rm * 16 + lr, ab = ar * 512, asw = (ar & 7) << 4;
            #pragma unroll
            for (int ks = 0; ks < 8; ++ks) {
                short8 ah = *(const short8*)(Hs + ab + (((ks * 4 + lg) << 4) ^ asw));
                acc = __builtin_amdgcn_mfma_f32_16x16x32_bf16(ah, bw[ks], acc, 0, 0, 0);
            }
            f32x4 o;
            #pragma unroll
            for (int e = 0; e < 4; ++e) o[e] = (acc[e] + pbv) * LOG2E;
            if (valid)
                *(f32x4*)(Ew2 + (size_t)v * 64 + rm * 16 + lg * 4) = o;
            #pragma unroll
            for (int e = 0; e < 4; ++e) {
                if (valid) {
                    float mn = fmaxf(em_m[rm][e], o[e]);
                    em_s[rm][e] = em_s[rm][e] * ex2(em_m[rm][e] - mn) + ex2(o[e] - mn);
                    em_m[rm][e] = mn;
                }
            }
        }
    }

    // reduce over the 16 words held across lr lanes (lane bits 0..3)
    #pragma unroll
    for (int rm = 0; rm < 4; ++rm)
        #pragma unroll
        for (int e = 0; e < 4; ++e) {
            float mm = em_m[rm][e], ss = em_s[rm][e];
            #pragma unroll
            for (int d = 1; d < 16; d <<= 1) {
                float m2 = __shfl_xor(mm, d);
                float s2 = __shfl_xor(ss, d);
                float mn = fmaxf(mm, m2);
                ss = ss * ex2(mm - mn) + s2 * ex2(m2 - mn);
                mm = mn;
            }
            em_m[rm][e] = mm; em_s[rm][e] = ss;
        }
    if (lr == 0) {
        #pragma unroll
        for (int rm = 0; rm < 4; ++rm)
            #pragma unroll
            for (int e = 0; e < 4; ++e) {
                emM[w][rm * 16 + lg * 4 + e] = em_m[rm][e];
                emS[w][rm * 16 + lg * 4 + e] = em_s[rm][e];
            }
    }
    __syncthreads();
    if (tid < 64) {
        float M = emM[0][tid], S = emS[0][tid];
        #pragma unroll
        for (int q2 = 1; q2 < 4; ++q2) {
            float m2 = emM[q2][tid], s2 = emS[q2][tid];
            float mn = fmaxf(M, m2);
            S = S * ex2(M - mn) + s2 * ex2(m2 - mn); M = mn;
        }
        lse_em2[c * 64 + tid] = M + lg2(fmaxf(S, 1e-33f));
    }
}

// ---------------- obs2[b,t,k] = Ew2 - lse_em2 ----------------
__global__ __launch_bounds__(256) void fhmm_obs_kernel(
    const float* __restrict__ Ew2, const float* __restrict__ lse_em2,
    const int* __restrict__ text, const int* __restrict__ w2s,
    float* __restrict__ obs2)
{
    int i = blockIdx.x * 4 + (threadIdx.x >> 6);   // b*T + t
    int k = threadIdx.x & 63;
    int v = text[i];
    int s = w2s[v * SPWW + k];
    obs2[i * 64 + k] = Ew2[v * 64 + k] - lse_em2[s];
}

// ================= 4-ARY TREE COMBINE in lse2 semiring ==================
// Node = ((M0 (x) M1) (x) M2) (x) M3; intermediate stays in LDS (f32).
// LEAF=1: M_t built on the fly: M_t[i][j] = U2[sr+i][c_t] - lse2[sr+i]
//                                          + V2[sr+i][j] + obs2[t][j]
//   node p covers t = 4p+1 .. min(4p+4, 255)  (p=63 -> 3 mats).
// LEAF=0: inputs from Lin (4*gridDim.x mats per batch), always 4 mats.
template<int LEAF>
__global__ __launch_bounds__(256) void fhmm_combine4(
    const float* __restrict__ U2, const float* __restrict__ V2,
    const float* __restrict__ obs2, const float* __restrict__ lse2,
    const int* __restrict__ text, const int* __restrict__ w2s,
    const float* __restrict__ Lin, float* __restrict__ Lout)
{
    int p = blockIdx.x, b = blockIdx.y;
    int nodes = gridDim.x;
    int tid = threadIdx.x;
    int l6 = tid & 63, q = tid >> 6;

    __shared__ float Rb[64][65];
    __shared__ char Ps[8192], Qs[8192];
    __shared__ float mA2[64], mB2[64], mAf[64], mBf[64];
    __shared__ float part[2][4][64];
    __shared__ float rtB_l[64];

    int nm = LEAF ? ((p == 63) ? 3 : 4) : 4;
    int t0 = 4 * p + 1;
    int in0 = 4 * p;

    float va[16];
    float rowA = 0.f;

    if (LEAF) {
        int srA = w2s[text[b * TTT + (t0 - 1)] * SPWW];
        int cA  = w2s[text[b * TTT + t0] * SPWW] >> 6;
        rowA = U2[(size_t)(srA + l6) * NCC + cA] - lse2[srA + l6];
        const float* vrow = V2 + (size_t)(srA + l6) * SPWW;
        const float* orow = obs2 + (size_t)(b * TTT + t0) * 64;
        #pragma unroll
        for (int jj = 0; jj < 16; ++jj)
            va[jj] = vrow[q * 16 + jj] + orow[q * 16 + jj];
    } else {
        const float* Af = Lin + ((size_t)(b * (4 * nodes) + in0)) * 4096;
        #pragma unroll
        for (int jj = 0; jj < 16; ++jj)
            va[jj] = Af[l6 * 64 + q * 16 + jj];
    }

    for (int s = 1; s < nm; ++s) {
        // A-side partial rowmax
        float mloc = -3e38f;
        #pragma unroll
        for (int jj = 0; jj < 16; ++jj) mloc = fmaxf(mloc, va[jj]);
        part[0][q][l6] = mloc;

        // B-side build/load
        float vb[16], obB = 0.f;
        if (LEAF) {
            int tB = t0 + s;
            int srB = w2s[text[b * TTT + (tB - 1)] * SPWW];
            int cB  = w2s[text[b * TTT + tB] * SPWW] >> 6;
            if (tid < 64)
                rtB_l[tid] = U2[(size_t)(srB + tid) * NCC + cB] - lse2[srB + tid];
            obB = obs2[(size_t)(b * TTT + tB) * 64 + l6];
            float vraw[16];
            #pragma unroll
            for (int kk = 0; kk < 16; ++kk)
                vraw[kk] = V2[(size_t)(srB + q * 16 + kk) * SPWW + l6];
            __syncthreads();
            float mlocB = -3e38f;
            #pragma unroll
            for (int kk = 0; kk < 16; ++kk) {
                vb[kk] = vraw[kk] + rtB_l[q * 16 + kk];
                mlocB = fmaxf(mlocB, vb[kk]);
            }
            part[1][q][l6] = mlocB;
        } else {
            const float* Bf = Lin + ((size_t)(b * (4 * nodes) + in0 + s)) * 4096;
            float mlocB = -3e38f;
            #pragma unroll
            for (int kk = 0; kk < 16; ++kk) {
                float v = Bf[(q * 16 + kk) * 64 + l6];
                vb[kk] = v; mlocB = fmaxf(mlocB, v);
            }
            part[1][q][l6] = mlocB;
        }
        __syncthreads();

        if (tid < 64) {
            float mf = fmaxf(fmaxf(part[0][0][tid], part[0][1][tid]),
                             fmaxf(part[0][2][tid], part[0][3][tid]));
            mAf[tid] = mf;
            mA2[tid] = mf + ((LEAF && s == 1) ? rowA : 0.f);
        } else if (tid < 128) {
            int j = tid & 63;
            float mf = fmaxf(fmaxf(part[1][0][j], part[1][1][j]),
                             fmaxf(part[1][2][j], part[1][3][j]));
            mBf[j] = mf;
            mB2[j] = mf + obB;     // obB==0 for non-leaf
        }
        __syncthreads();

        // exp-pack P (rows=i) and Qt (rows=j) as bf16, swizzled
        {
            float ma = mAf[l6];
            u16 pk[16];
            #pragma unroll
            for (int e = 0; e < 16; ++e) pk[e] = f2bf(ex2(va[e] - ma));
            uint4* srcv = (uint4*)pk;
            int base = l6 * 128;
            int s0 = 2 * q, s1 = 2 * q + 1, sw = (l6 & 7);
            *(uint4*)&Ps[base + ((s0 ^ sw) << 4)] = srcv[0];
            *(uint4*)&Ps[base + ((s1 ^ sw) << 4)] = srcv[1];
            float mb = mBf[l6];
            #pragma unroll
            for (int e = 0; e < 16; ++e) pk[e] = f2bf(ex2(vb[e] - mb));
            *(uint4*)&Qs[base + ((s0 ^ sw) << 4)] = srcv[0];
            *(uint4*)&Qs[base + ((s1 ^ sw) << 4)] = srcv[1];
        }
        __syncthreads();

        // MFMA: C = mA2 + mB2 + log2(P.Q^T)
        int w = q, lr = l6 & 15, lg = l6 >> 4;
        int brow = w * 16 + lr;
        short8 bfr[2];
        #pragma unroll
        for (int ks = 0; ks < 2; ++ks)
            bfr[ks] = *(const short8*)(Qs + brow * 128 + (((ks * 4 + lg) << 4) ^ ((brow & 7) << 4)));
        bool last = (s == nm - 1);
        float* Co = Lout + ((size_t)(b * nodes + p)) * 4096;
        #pragma unroll
        for (int rm = 0; rm < 4; ++rm) {
            f32x4 acc = {0.f, 0.f, 0.f, 0.f};
            int ar = rm * 16 + lr;
            #pragma unroll
            for (int ks = 0; ks < 2; ++ks) {
                short8 af = *(const short8*)(Ps + ar * 128 + (((ks * 4 + lg) << 4) ^ ((ar & 7) << 4)));
                acc = __builtin_amdgcn_mfma_f32_16x16x32_bf16(af, bfr[ks], acc, 0, 0, 0);
            }
            #pragma unroll
            for (int e = 0; e < 4; ++e) {
                int ii = rm * 16 + lg * 4 + e;
                int jj = w * 16 + lr;
                float cv = mA2[ii] + mB2[jj] + lg2(fmaxf(acc[e], 1e-33f));
                if (last) Co[ii * 64 + jj] = cv;
                else      Rb[ii][jj] = cv;
            }
        }
        if (!last) {
            __syncthreads();
            #pragma unroll
            for (int jj = 0; jj < 16; ++jj)
                va[jj] = Rb[l6][q * 16 + jj];
        }
    }
}

// ---------------- final: out[b] = LN2 * lse2_{i,j}( a0_2[i] + Mtot[i][j] ) ----------------
__global__ __launch_bounds__(256) void fhmm_final(
    const float* __restrict__ startv, const float* __restrict__ obs2,
    const float* __restrict__ Mtot, const int* __restrict__ text,
    const int* __restrict__ w2s, float* __restrict__ out)
{
    int b = blockIdx.x, tid = threadIdx.x;
    __shared__ float a0[64];
    __shared__ float rm_[4], rs_[4];
    if (tid < 64) {
        int s0 = w2s[text[b * TTT] * SPWW];
        a0[tid] = startv[s0 + tid] * LOG2E + obs2[(size_t)(b * TTT) * 64 + tid];
    }
    __syncthreads();
    const float* M = Mtot + (size_t)b * 4096;
    float m = -3e38f, s = 0.f;
    for (int e = tid; e < 4096; e += 256) {
        float v = a0[e >> 6] + M[e];
        float mn = fmaxf(m, v);
        s = s * ex2(m - mn) + ex2(v - mn);
        m = mn;
    }
    #pragma unroll
    for (int d = 32; d; d >>= 1) {
        float m2 = __shfl_xor(m, d), sx = __shfl_xor(s, d);
        float mn = fmaxf(m, m2);
        s = s * ex2(m - mn) + sx * ex2(m2 - mn); m = mn;
    }
    if ((tid & 63) == 0) { rm_[tid >> 6] = m; rs_[tid >> 6] = s; }
    __syncthreads();
    if (tid == 0) {
        float M_ = rm_[0], S_ = rs_[0];
        #pragma unroll
        for (int qq = 1; qq < 4; ++qq) {
            float mn = fmaxf(M_, rm_[qq]);
            S_ = S_ * ex2(M_ - mn) + rs_[qq] * ex2(rm_[qq] - mn); M_ = mn;
        }
        out[b] = (M_ + lg2(S_)) * LN2;
    }
}

extern "C" void kernel_launch(void* const* d_in, const int* in_sizes, int n_in,
                              void* d_out, int out_size, void* d_ws, size_t ws_size,
                              hipStream_t stream) {
    const int* text        = (const int*)d_in[0];
    const int* w2s         = (const int*)d_in[1];
    const float* se1_start = (const float*)d_in[2];
    const float* se2_start = (const float*)d_in[3];
    const float* start_w1  = (const float*)d_in[4];
    const float* start_b1  = (const float*)d_in[5];
    const float* start_w2  = (const float*)d_in[6];
    const float* start_b2  = (const float*)d_in[7];
    const float* start_pw  = (const float*)d_in[8];
    const float* start_pb  = (const float*)d_in[9];
    const float* se1_state = (const float*)d_in[10];
    const float* se2_state = (const float*)d_in[11];
    const float* se1_next  = (const float*)d_in[12];
    const float* se2_next  = (const float*)d_in[13];
    const float* trans_w1  = (const float*)d_in[14];
    const float* trans_b1  = (const float*)d_in[15];
    const float* trans_w2  = (const float*)d_in[16];
    const float* trans_b2  = (const float*)d_in[17];
    const float* se1_pre   = (const float*)d_in[18];
    const float* se2_pre   = (const float*)d_in[19];
    const float* term_w1   = (const float*)d_in[20];
    const float* term_b1   = (const float*)d_in[21];
    const float* term_w2   = (const float*)d_in[22];
    const float* term_b2   = (const float*)d_in[23];
    const float* term_pw   = (const float*)d_in[24];
    const float* term_pb   = (const float*)d_in[25];
    float* out = (float*)d_out;

    char* wp = (char*)d_ws;
    auto alloc = [&](size_t bytes) {
        char* p = wp;
        wp += (bytes + 255) & ~(size_t)255;
        return (void*)p;
    };
    u16* emb_start   = (u16*)alloc((size_t)CST * HH * 2);
    u16* emb_state   = (u16*)alloc((size_t)CST * HH * 2);
    u16* emb_pre     = (u16*)alloc((size_t)CST * HH * 2);
    u16* h1_bf       = (u16*)alloc((size_t)CST * HH * 2);
    u16* hstart_bf   = (u16*)alloc((size_t)CST * HH * 2);
    u16* h_state_bf  = (u16*)alloc((size_t)CST * HH * 2);
    u16* h_pre_bf    = (u16*)alloc((size_t)CST * HH * 2);
    u16* Wt          = (u16*)alloc((size_t)6 * HH * HH * 2);
    u16* pwT         = (u16*)alloc((size_t)VV * HH * 2);
    u16* e1n_bf      = (u16*)alloc((size_t)NCC * HH * 2);
    u16* e2n_bf      = (u16*)alloc((size_t)SPWW * HH * 2);
    float* U2        = (float*)alloc((size_t)CST * NCC * 4);
    float* V2        = (float*)alloc((size_t)CST * SPWW * 4);
    float* startv    = (float*)alloc(CST * 4);
    float* lse_trans = (float*)alloc(CST * 4);
    float* lse_em    = (float*)alloc(CST * 4);
    float* Ew        = (float*)alloc((size_t)VV * 64 * 4);
    int* counts      = (int*)alloc(NCC * 4);
    int* offsets     = (int*)alloc((NCC + 4) * 4);
    int* wlist       = (int*)alloc(VV * 4);
    float* obs       = (float*)alloc((size_t)BBB * TTT * 64 * 4);
    float* LvA       = (float*)alloc((size_t)BBB * 64 * 4096 * 4);
    float* LvB       = (float*)alloc((size_t)BBB * 16 * 4096 * 4);
    float* LvC       = (float*)alloc((size_t)BBB * 4 * 4096 * 4);
    float* LvD       = (float*)alloc((size_t)BBB * 1 * 4096 * 4);

    // setup: weight transposes, pw transpose, next-factor embs, word-lists
    Ptr6 wargs = {{start_w1, start_w2, trans_w1, trans_w2, term_w1, term_w2}};
    hipLaunchKernelGGL(fhmm_wtrans_all, dim3(4, 4, 6), 256, 0, stream, wargs, Wt);
    hipLaunchKernelGGL(fhmm_pwtrans_kernel, dim3((VV + 63) / 64, 4), 256, 0, stream,
                       term_pw, pwT);
    hipLaunchKernelGGL(fhmm_emb_next_small, dim3(128), 256, 0, stream,
                       se1_next, se2_next, e1n_bf, e2n_bf);
    hipLaunchKernelGGL(fhmm_wordlist, dim3(1), 1024, 0, stream,
                       w2s, counts, offsets, wlist);

    // 3 big embeddings
    EmbA eargs = {{se1_start, se1_state, se1_pre},
                  {se2_start, se2_state, se2_pre},
                  {emb_start, emb_state, emb_pre}};
    hipLaunchKernelGGL(fhmm_emb_all, dim3(8192, 3), 256, 0, stream, eargs);

    dim3 mmGrid(128, 4);
    // start head
    hipLaunchKernelGGL(fhmm_mlp_mfma, mmGrid, 256, 0, stream,
                       emb_start, Wt + 0 * HH * HH, start_b1, (const u16*)nullptr, h1_bf, 1.0f);
    hipLaunchKernelGGL(fhmm_mlp_mfma, mmGrid, 256, 0, stream,
                       h1_bf, Wt + 1 * HH * HH, start_b2, emb_start, hstart_bf, 1.0f);
    hipLaunchKernelGGL(fhmm_dotpw_kernel, dim3(2048), 256, 0, stream,
                       hstart_bf, start_pw, start_pb, startv);
    hipLaunchKernelGGL(fhmm_lsm_vec_kernel, dim3(1), 1024, 0, stream, startv);

    // state head (output prescaled by log2e -> base-2 logits downstream)
    hipLaunchKernelGGL(fhmm_mlp_mfma, mmGrid, 256, 0, stream,
                       emb_state, Wt + 2 * HH * HH, trans_b1, (const u16*)nullptr, h1_bf, 1.0f);
    hipLaunchKernelGGL(fhmm_mlp_mfma, mmGrid, 256, 0, stream,
                       h1_bf, Wt + 3 * HH * HH, trans_b2, emb_state, h_state_bf, LOG2E);

    // pre head
    hipLaunchKernelGGL(fhmm_mlp_mfma, mmGrid, 256, 0, stream,
                       emb_pre, Wt + 4 * HH * HH, term_b1, (const u16*)nullptr, h1_bf, 1.0f);
    hipLaunchKernelGGL(fhmm_mlp_mfma, mmGrid, 256, 0, stream,
                       h1_bf, Wt + 5 * HH * HH, term_b2, emb_pre, h_pre_bf, 1.0f);

    // U2 = h_state2 @ e1n^T (8192x128), V2 = h_state2 @ e2n^T (8192x64)
    hipLaunchKernelGGL(fhmm_gemm_nt, dim3(128, 2), 256, 0, stream,
                       h_state_bf, e1n_bf, U2, NCC);
    hipLaunchKernelGGL(fhmm_gemm_nt, dim3(128, 1), 256, 0, stream,
                       h_state_bf, e2n_bf, V2, SPWW);
    hipLaunchKernelGGL(fhmm_lse_uv, dim3(2048), 256, 0, stream, U2, V2, lse_trans);

    // emission (Ew2 + fused lse_em2) + obs
    hipLaunchKernelGGL(fhmm_ew_mfma, dim3(NCC), 256, 0, stream,
                       h_pre_bf, pwT, term_pb, wlist, counts, offsets, Ew, lse_em);
    hipLaunchKernelGGL(fhmm_obs_kernel, dim3(BBB * TTT / 4), 256, 0, stream,
                       Ew, lse_em, text, w2s, obs);

    // ---- 4-ary tree reduction over transition matrices ----
    hipLaunchKernelGGL((fhmm_combine4<1>), dim3(64, BBB), 256, 0, stream,
                       U2, V2, obs, lse_trans, text, w2s,
                       (const float*)nullptr, LvA);
    hipLaunchKernelGGL((fhmm_combine4<0>), dim3(16, BBB), 256, 0, stream,
                       (const float*)nullptr, (const float*)nullptr,
                       (const float*)nullptr, (const float*)nullptr,
                       (const int*)nullptr, (const int*)nullptr, LvA, LvB);
    hipLaunchKernelGGL((fhmm_combine4<0>), dim3(4, BBB), 256, 0, stream,
                       (const float*)nullptr, (const float*)nullptr,
                       (const float*)nullptr, (const float*)nullptr,
                       (const int*)nullptr, (const int*)nullptr, LvB, LvC);
    hipLaunchKernelGGL((fhmm_combine4<0>), dim3(1, BBB), 256, 0, stream,
                       (const float*)nullptr, (const float*)nullptr,
                       (const float*)nullptr, (const float*)nullptr,
                       (const int*)nullptr, (const int*)nullptr, LvC, LvD);

    // ---- final apply + lse ----
    hipLaunchKernelGGL(fhmm_final, dim3(BBB), 256, 0, stream,
                       startv, obs, LvD, text, w2s, out);
}

// Round 10
// 125.618 us; speedup vs baseline: 4.5641x; 1.2887x over previous
//
#include <hip/hip_runtime.h>
#include <hip/hip_bf16.h>
#include <math.h>

#define HH 256
#define NCC 128
#define SPWW 64
#define CST 8192
#define VV 10000
#define BBB 16
#define TTT 256
#define LOG2E 1.4426950408889634f
#define LN2 0.6931471805599453f

typedef __attribute__((ext_vector_type(8))) short short8;
typedef __attribute__((ext_vector_type(4))) float f32x4;
typedef unsigned short u16;

__device__ inline float bf2f(u16 u) {
    union { unsigned int i; float f; } v; v.i = ((unsigned int)u) << 16; return v.f;
}
__device__ inline u16 f2bf(float f) {
    __hip_bfloat16 h = __float2bfloat16(f);
    return *reinterpret_cast<u16*>(&h);
}
__device__ inline float ex2(float x) { return __builtin_amdgcn_exp2f(x); }
__device__ inline float lg2(float x) { return __builtin_amdgcn_logf(x); }   // v_log_f32 = log2

// ================= mega-setup: wtrans(96) + pwtrans(628) + embnext(128) + wordlist(1) =================
struct SetupA {
    const float* Ws[6]; u16* Wt;
    const float* pw; u16* pwT;
    const float* e1n; const float* e2n; u16* e1nb; u16* e2nb;
    const int* w2s; int* counts; int* offsets; int* wlist;
};
__global__ __launch_bounds__(256) void fhmm_setup(SetupA a)
{
    __shared__ float t[64][65];
    int blk = blockIdx.x, tid = threadIdx.x;
    if (blk < 96) {
        int z = blk >> 4, r = blk & 15;
        int k0 = (r & 3) * 64, n0 = (r >> 2) * 64;
        const float* W = a.Ws[z];
        u16* dst = a.Wt + (size_t)z * HH * HH;
        #pragma unroll
        for (int i = 0; i < 16; ++i) {
            int idx = tid + i * 256; int rr = idx >> 6, c = idx & 63;
            t[rr][c] = W[(k0 + rr) * HH + n0 + c];
        }
        __syncthreads();
        #pragma unroll
        for (int i = 0; i < 16; ++i) {
            int idx = tid + i * 256; int rr = idx >> 6, c = idx & 63;
            dst[(n0 + rr) * HH + k0 + c] = f2bf(t[c][rr]);
        }
    } else if (blk < 96 + 628) {
        int idx = blk - 96;
        int v0 = (idx % 157) * 64, k0 = (idx / 157) * 64;
        #pragma unroll
        for (int i = 0; i < 16; ++i) {
            int id2 = tid + i * 256; int rr = id2 >> 6, c = id2 & 63;   // rr:k, c:v
            int v = v0 + c;
            t[rr][c] = (v < VV) ? a.pw[(size_t)(k0 + rr) * VV + v] : 0.f;
        }
        __syncthreads();
        #pragma unroll
        for (int i = 0; i < 16; ++i) {
            int id2 = tid + i * 256; int rr = id2 >> 6, c = id2 & 63;   // rr:v, c:k
            int v = v0 + rr;
            if (v < VV) a.pwT[(size_t)v * HH + k0 + c] = f2bf(t[c][rr]);
        }
    } else if (blk < 96 + 628 + 128) {
        int idx = (blk - 724) * 256 + tid;
        if (idx < NCC * HH) a.e1nb[idx] = f2bf(a.e1n[idx]);
        if (idx < SPWW * HH) a.e2nb[idx] = f2bf(a.e2n[idx]);
    } else {
        __shared__ int cnt[NCC], off[NCC + 1], cur[NCC];
        if (tid < NCC) cnt[tid] = 0;
        __syncthreads();
        for (int v = tid; v < VV; v += 256)
            atomicAdd(&cnt[a.w2s[v * SPWW] >> 6], 1);
        __syncthreads();
        if (tid == 0) {
            int acc = 0;
            for (int c = 0; c < NCC; ++c) { off[c] = acc; acc += cnt[c]; }
            off[NCC] = acc;
        }
        __syncthreads();
        if (tid < NCC) cur[tid] = off[tid];
        __syncthreads();
        for (int v = tid; v < VV; v += 256) {
            int c = a.w2s[v * SPWW] >> 6;
            int pos = atomicAdd(&cur[c], 1);
            a.wlist[pos] = v;
        }
        if (tid < NCC) { a.counts[tid] = cnt[tid]; a.offsets[tid] = off[tid]; }
        if (tid == 0) a.offsets[NCC] = off[NCC];
    }
}

// ================= batched MFMA MLP (3 heads per launch) =================
// LAYER 0: X = bf16(se1+se2) computed on the fly, Y = relu(X@W+b)
// LAYER 1: X = X[h] (bf16 buffer), Y = (relu(X@W+b) + (se1+se2)) * oscale
struct MlpA {
    const u16* X[3];
    const float* se1[3]; const float* se2[3];
    const u16* Wth[3];
    const float* bias[3];
    u16* Y[3];
    float oscale[3];
};
template<int LAYER>
__global__ __launch_bounds__(256) void fhmm_mlp_batch(MlpA a)
{
    int hd = blockIdx.z;
    int m0 = blockIdx.x * 64, n0 = blockIdx.y * 64;
    __shared__ char Xs[32768];
    __shared__ char Ws[32768];
    int tid = threadIdx.x, w = tid >> 6, lane = tid & 63, lr = lane & 15, lg = lane >> 4;
    const char* wsrc = (const char*)(a.Wth[hd] + (size_t)n0 * HH);
    if (LAYER == 0) {
        const float* s1 = a.se1[hd];
        const float* s2 = a.se2[hd];
        #pragma unroll
        for (int i = 0; i < 8; ++i) {
            int cc = i * 256 + tid; int row = cc >> 5, tt = cc & 31;
            int gm = m0 + row, k = tt * 8;
            const float* p1 = s1 + (gm >> 6) * HH + k;
            const float* p2 = s2 + (gm & 63) * HH + k;
            u16 pk[8];
            #pragma unroll
            for (int e = 0; e < 8; ++e) pk[e] = f2bf(p1[e] + p2[e]);
            int dst = row * 512 + ((tt ^ (row & 7)) << 4);
            *(uint4*)&Xs[dst] = *(uint4*)pk;
            *(uint4*)&Ws[dst] = *(const uint4*)(wsrc + cc * 16);
        }
    } else {
        const char* xsrc = (const char*)(a.X[hd] + (size_t)m0 * HH);
        #pragma unroll
        for (int i = 0; i < 8; ++i) {
            int cc = i * 256 + tid; int row = cc >> 5, tt = cc & 31;
            int dst = row * 512 + ((tt ^ (row & 7)) << 4);
            *(uint4*)&Xs[dst] = *(const uint4*)(xsrc + cc * 16);
            *(uint4*)&Ws[dst] = *(const uint4*)(wsrc + cc * 16);
        }
    }
    __syncthreads();
    short8 bfr[8];
    int brow = w * 16 + lr, bb = brow * 512, bsw = (brow & 7) << 4;
    #pragma unroll
    for (int ks = 0; ks < 8; ++ks)
        bfr[ks] = *(const short8*)(Ws + bb + (((ks * 4 + lg) << 4) ^ bsw));
    int cb = w * 16 + lg * 4;
    f32x4 bv = *(const f32x4*)(a.bias[hd] + n0 + cb);
    float osc = a.oscale[hd];
    u16* Yp = a.Y[hd];
    #pragma unroll
    for (int rm = 0; rm < 4; ++rm) {
        f32x4 acc = {0.f, 0.f, 0.f, 0.f};
        int ar = rm * 16 + lr, ab = ar * 512, asw = (ar & 7) << 4;
        #pragma unroll
        for (int ks = 0; ks < 8; ++ks) {
            short8 af = *(const short8*)(Xs + ab + (((ks * 4 + lg) << 4) ^ asw));
            acc = __builtin_amdgcn_mfma_f32_16x16x32_bf16(bfr[ks], af, acc, 0, 0, 0);
        }
        int gm = m0 + rm * 16 + lr;
        ushort4 o;
        if (LAYER == 1) {
            const float* r1 = a.se1[hd] + (gm >> 6) * HH + n0 + cb;
            const float* r2 = a.se2[hd] + (gm & 63) * HH + n0 + cb;
            #pragma unroll
            for (int e = 0; e < 4; ++e)
                ((u16*)&o)[e] = f2bf((fmaxf(acc[e] + bv[e], 0.f) + r1[e] + r2[e]) * osc);
        } else {
            #pragma unroll
            for (int e = 0; e < 4; ++e)
                ((u16*)&o)[e] = f2bf(fmaxf(acc[e] + bv[e], 0.f));
        }
        *(ushort4*)(Yp + (size_t)gm * HH + n0 + cb) = o;
    }
}

// ================= U/V GEMM in one launch: y<2 -> U2 cols, y==2 -> V2 =================
__global__ __launch_bounds__(256) void fhmm_gemm_uv(
    const u16* __restrict__ Abf, const u16* __restrict__ e1n,
    const u16* __restrict__ e2n, float* __restrict__ U2, float* __restrict__ V2)
{
    int y = blockIdx.y;
    int m0 = blockIdx.x * 64;
    const u16* Bb; float* C; int ldc;
    if (y < 2) { Bb = e1n + (size_t)y * 64 * HH; C = U2 + y * 64; ldc = NCC; }
    else       { Bb = e2n;                        C = V2;          ldc = SPWW; }
    __shared__ char Xs[32768];
    __shared__ char Ws[32768];
    int tid = threadIdx.x, w = tid >> 6, lane = tid & 63, lr = lane & 15, lg = lane >> 4;
    const char* xsrc = (const char*)(Abf + (size_t)m0 * HH);
    const char* wsrc = (const char*)Bb;
    #pragma unroll
    for (int i = 0; i < 8; ++i) {
        int cc = i * 256 + tid; int row = cc >> 5, tt = cc & 31;
        int dst = row * 512 + ((tt ^ (row & 7)) << 4);
        *(uint4*)&Xs[dst] = *(const uint4*)(xsrc + cc * 16);
        *(uint4*)&Ws[dst] = *(const uint4*)(wsrc + cc * 16);
    }
    __syncthreads();
    short8 bfr[8];
    int brow = w * 16 + lr, bb = brow * 512, bsw = (brow & 7) << 4;
    #pragma unroll
    for (int ks = 0; ks < 8; ++ks)
        bfr[ks] = *(const short8*)(Ws + bb + (((ks * 4 + lg) << 4) ^ bsw));
    int cb = w * 16 + lg * 4;
    #pragma unroll
    for (int rm = 0; rm < 4; ++rm) {
        f32x4 acc = {0.f, 0.f, 0.f, 0.f};
        int ar = rm * 16 + lr, ab = ar * 512, asw = (ar & 7) << 4;
        #pragma unroll
        for (int ks = 0; ks < 8; ++ks) {
            short8 af = *(const short8*)(Xs + ab + (((ks * 4 + lg) << 4) ^ asw));
            acc = __builtin_amdgcn_mfma_f32_16x16x32_bf16(bfr[ks], af, acc, 0, 0, 0);
        }
        int gm = m0 + rm * 16 + lr;
        *(f32x4*)(C + (size_t)gm * ldc + cb) = acc;
    }
}

// ---------------- lse_trans2[s] = lse2(U2[s]) + lse2(V2[s]) ----------------
__global__ __launch_bounds__(256) void fhmm_lse_uv(
    const float* __restrict__ U2, const float* __restrict__ V2,
    float* __restrict__ lse2)
{
    int tid = threadIdx.x, w = tid >> 6, lane = tid & 63;
    int s = blockIdx.x * 4 + w;
    float u0 = U2[(size_t)s * NCC + lane];
    float u1 = U2[(size_t)s * NCC + 64 + lane];
    float vv = V2[(size_t)s * SPWW + lane];
    float mu = fmaxf(u0, u1);
    #pragma unroll
    for (int d = 32; d; d >>= 1) mu = fmaxf(mu, __shfl_xor(mu, d));
    float su = ex2(u0 - mu) + ex2(u1 - mu);
    #pragma unroll
    for (int d = 32; d; d >>= 1) su += __shfl_xor(su, d);
    float mv = vv;
    #pragma unroll
    for (int d = 32; d; d >>= 1) mv = fmaxf(mv, __shfl_xor(mv, d));
    float sv = ex2(vv - mv);
    #pragma unroll
    for (int d = 32; d; d >>= 1) sv += __shfl_xor(sv, d);
    if (lane == 0) lse2[s] = (mu + lg2(su)) + (mv + lg2(sv));
}

// ---------------- start head: dot with pw (bf16 h) ----------------
__global__ __launch_bounds__(256) void fhmm_dotpw_kernel(
    const u16* __restrict__ hb, const float* __restrict__ pw,
    const float* __restrict__ pbp, float* __restrict__ p)
{
    int wv = threadIdx.x >> 6;
    int lane = threadIdx.x & 63;
    int s = blockIdx.x * 4 + wv;
    const u16* hr = hb + (size_t)s * HH;
    float acc = 0.f;
    #pragma unroll
    for (int i = 0; i < 4; ++i) acc += bf2f(hr[i * 64 + lane]) * pw[i * 64 + lane];
    #pragma unroll
    for (int d = 32; d; d >>= 1) acc += __shfl_xor(acc, d);
    if (lane == 0) p[s] = acc + pbp[0];
}

// ---------------- in-place log_softmax over a length-8192 vector ----------------
__global__ __launch_bounds__(1024) void fhmm_lsm_vec_kernel(float* __restrict__ p)
{
    __shared__ float red[64];
    int tid = threadIdx.x;
    float m = -1e30f;
    for (int i = tid; i < CST; i += 1024) m = fmaxf(m, p[i]);
    #pragma unroll
    for (int d = 32; d; d >>= 1) m = fmaxf(m, __shfl_xor(m, d));
    if ((tid & 63) == 0) red[tid >> 6] = m;
    __syncthreads();
    if (tid == 0) {
        float mm = red[0];
        for (int q = 1; q < 16; ++q) mm = fmaxf(mm, red[q]);
        red[32] = mm;
    }
    __syncthreads();
    float M = red[32];
    float s = 0.f;
    for (int i = tid; i < CST; i += 1024) s += expf(p[i] - M);
    #pragma unroll
    for (int d = 32; d; d >>= 1) s += __shfl_xor(s, d);
    if ((tid & 63) == 0) red[tid >> 6] = s;
    __syncthreads();
    if (tid == 0) {
        float ss = 0.f;
        for (int q = 0; q < 16; ++q) ss += red[q];
        red[33] = ss;
    }
    __syncthreads();
    float lse = M + logf(red[33]);
    for (int i = tid; i < CST; i += 1024) p[i] -= lse;
}

// ---------------- per-class emission GEMM + fused per-state lse (base-2) ----------------
__global__ __launch_bounds__(256) void fhmm_ew_mfma(
    const u16* __restrict__ hpre_bf, const u16* __restrict__ pwT,
    const float* __restrict__ pb, const int* __restrict__ wlist,
    const int* __restrict__ counts, const int* __restrict__ offsets,
    float* __restrict__ Ew2, float* __restrict__ lse_em2)
{
    int c = blockIdx.x;
    int cnt = counts[c], off = offsets[c];
    __shared__ char Hs[32768];
    __shared__ float emM[4][64], emS[4][64];
    int tid = threadIdx.x, w = tid >> 6, lane = tid & 63, lr = lane & 15, lg = lane >> 4;
    const char* src = (const char*)(hpre_bf + (size_t)c * 64 * HH);
    #pragma unroll
    for (int i = 0; i < 8; ++i) {
        int cc = i * 256 + tid; int row = cc >> 5, tt = cc & 31;
        *(uint4*)&Hs[row * 512 + ((tt ^ (row & 7)) << 4)] = *(const uint4*)(src + cc * 16);
    }
    __syncthreads();

    float em_m[4][4], em_s[4][4];
    #pragma unroll
    for (int rm = 0; rm < 4; ++rm)
        #pragma unroll
        for (int e = 0; e < 4; ++e) { em_m[rm][e] = -3e38f; em_s[rm][e] = 0.f; }

    for (int ch = 0; ch * 64 < cnt; ++ch) {
        int widx = ch * 64 + w * 16 + lr;
        bool valid = widx < cnt;
        int v = valid ? wlist[off + widx] : 0;
        short8 bw[8];
        short8 bz = {0, 0, 0, 0, 0, 0, 0, 0};
        #pragma unroll
        for (int ks = 0; ks < 8; ++ks)
            bw[ks] = valid ? *(const short8*)(pwT + (size_t)v * HH + ks * 32 + lg * 8) : bz;
        float pbv = valid ? pb[v] : 0.f;
        #pragma unroll
        for (int rm = 0; rm < 4; ++rm) {
            f32x4 acc = {0.f, 0.f, 0.f, 0.f};
            int ar = rm * 16 + lr, ab = ar * 512, asw = (ar & 7) << 4;
            #pragma unroll
            for (int ks = 0; ks < 8; ++ks) {
                short8 ah = *(const short8*)(Hs + ab + (((ks * 4 + lg) << 4) ^ asw));
                acc = __builtin_amdgcn_mfma_f32_16x16x32_bf16(ah, bw[ks], acc, 0, 0, 0);
            }
            f32x4 o;
            #pragma unroll
            for (int e = 0; e < 4; ++e) o[e] = (acc[e] + pbv) * LOG2E;
            if (valid)
                *(f32x4*)(Ew2 + (size_t)v * 64 + rm * 16 + lg * 4) = o;
            #pragma unroll
            for (int e = 0; e < 4; ++e) {
                if (valid) {
                    float mn = fmaxf(em_m[rm][e], o[e]);
                    em_s[rm][e] = em_s[rm][e] * ex2(em_m[rm][e] - mn) + ex2(o[e] - mn);
                    em_m[rm][e] = mn;
                }
            }
        }
    }

    #pragma unroll
    for (int rm = 0; rm < 4; ++rm)
        #pragma unroll
        for (int e = 0; e < 4; ++e) {
            float mm = em_m[rm][e], ss = em_s[rm][e];
            #pragma unroll
            for (int d = 1; d < 16; d <<= 1) {
                float m2 = __shfl_xor(mm, d);
                float s2 = __shfl_xor(ss, d);
                float mn = fmaxf(mm, m2);
                ss = ss * ex2(mm - mn) + s2 * ex2(m2 - mn);
                mm = mn;
            }
            em_m[rm][e] = mm; em_s[rm][e] = ss;
        }
    if (lr == 0) {
        #pragma unroll
        for (int rm = 0; rm < 4; ++rm)
            #pragma unroll
            for (int e = 0; e < 4; ++e) {
                emM[w][rm * 16 + lg * 4 + e] = em_m[rm][e];
                emS[w][rm * 16 + lg * 4 + e] = em_s[rm][e];
            }
    }
    __syncthreads();
    if (tid < 64) {
        float M = emM[0][tid], S = emS[0][tid];
        #pragma unroll
        for (int q2 = 1; q2 < 4; ++q2) {
            float m2 = emM[q2][tid], s2 = emS[q2][tid];
            float mn = fmaxf(M, m2);
            S = S * ex2(M - mn) + s2 * ex2(m2 - mn); M = mn;
        }
        lse_em2[c * 64 + tid] = M + lg2(fmaxf(S, 1e-33f));
    }
}

// ================= 4-ARY TREE COMBINE in lse2 semiring (obs computed inline) ==================
// LEAF=1: M_t[i][j] = U2[sr+i][c_t] - lse2[sr+i] + V2[sr+i][j] + Ew2[v_t*64+j] - lse_em2[64c_t+j]
template<int LEAF>
__global__ __launch_bounds__(256) void fhmm_combine4(
    const float* __restrict__ U2, const float* __restrict__ V2,
    const float* __restrict__ Ew2, const float* __restrict__ lse_em2,
    const float* __restrict__ lse2,
    const int* __restrict__ text, const int* __restrict__ w2s,
    const float* __restrict__ Lin, float* __restrict__ Lout)
{
    int p = blockIdx.x, b = blockIdx.y;
    int nodes = gridDim.x;
    int tid = threadIdx.x;
    int l6 = tid & 63, q = tid >> 6;

    __shared__ float Rb[64][65];
    __shared__ char Ps[8192], Qs[8192];
    __shared__ float mA2[64], mB2[64], mAf[64], mBf[64];
    __shared__ float part[2][4][64];
    __shared__ float rtB_l[64];

    int nm = LEAF ? ((p == 63) ? 3 : 4) : 4;
    int t0 = 4 * p + 1;
    int in0 = 4 * p;

    float va[16];
    float rowA = 0.f;

    if (LEAF) {
        int vprev = text[b * TTT + (t0 - 1)];
        int vA = text[b * TTT + t0];
        int srA = w2s[vprev * SPWW];
        int sA = w2s[vA * SPWW];          // = 64*cA
        int cA = sA >> 6;
        rowA = U2[(size_t)(srA + l6) * NCC + cA] - lse2[srA + l6];
        const float* vrow = V2 + (size_t)(srA + l6) * SPWW;
        const float* ewA = Ew2 + (size_t)vA * 64;
        const float* leA = lse_em2 + sA;
        #pragma unroll
        for (int jj = 0; jj < 16; ++jj) {
            int j = q * 16 + jj;
            va[jj] = vrow[j] + ewA[j] - leA[j];
        }
    } else {
        const float* Af = Lin + ((size_t)(b * (4 * nodes) + in0)) * 4096;
        #pragma unroll
        for (int jj = 0; jj < 16; ++jj)
            va[jj] = Af[l6 * 64 + q * 16 + jj];
    }

    for (int s = 1; s < nm; ++s) {
        float mloc = -3e38f;
        #pragma unroll
        for (int jj = 0; jj < 16; ++jj) mloc = fmaxf(mloc, va[jj]);
        part[0][q][l6] = mloc;

        float vb[16], obB = 0.f;
        if (LEAF) {
            int tB = t0 + s;
            int vBp = text[b * TTT + (tB - 1)];
            int vB = text[b * TTT + tB];
            int srB = w2s[vBp * SPWW];
            int sB = w2s[vB * SPWW];
            int cB = sB >> 6;
            if (tid < 64)
                rtB_l[tid] = U2[(size_t)(srB + tid) * NCC + cB] - lse2[srB + tid];
            obB = Ew2[(size_t)vB * 64 + l6] - lse_em2[sB + l6];
            float vraw[16];
            #pragma unroll
            for (int kk = 0; kk < 16; ++kk)
                vraw[kk] = V2[(size_t)(srB + q * 16 + kk) * SPWW + l6];
            __syncthreads();
            float mlocB = -3e38f;
            #pragma unroll
            for (int kk = 0; kk < 16; ++kk) {
                vb[kk] = vraw[kk] + rtB_l[q * 16 + kk];
                mlocB = fmaxf(mlocB, vb[kk]);
            }
            part[1][q][l6] = mlocB;
        } else {
            const float* Bf = Lin + ((size_t)(b * (4 * nodes) + in0 + s)) * 4096;
            float mlocB = -3e38f;
            #pragma unroll
            for (int kk = 0; kk < 16; ++kk) {
                float v = Bf[(q * 16 + kk) * 64 + l6];
                vb[kk] = v; mlocB = fmaxf(mlocB, v);
            }
            part[1][q][l6] = mlocB;
        }
        __syncthreads();

        if (tid < 64) {
            float mf = fmaxf(fmaxf(part[0][0][tid], part[0][1][tid]),
                             fmaxf(part[0][2][tid], part[0][3][tid]));
            mAf[tid] = mf;
            mA2[tid] = mf + ((LEAF && s == 1) ? rowA : 0.f);
        } else if (tid < 128) {
            int j = tid & 63;
            float mf = fmaxf(fmaxf(part[1][0][j], part[1][1][j]),
                             fmaxf(part[1][2][j], part[1][3][j]));
            mBf[j] = mf;
            mB2[j] = mf + obB;
        }
        __syncthreads();

        {
            float ma = mAf[l6];
            u16 pk[16];
            #pragma unroll
            for (int e = 0; e < 16; ++e) pk[e] = f2bf(ex2(va[e] - ma));
            uint4* srcv = (uint4*)pk;
            int base = l6 * 128;
            int s0 = 2 * q, s1 = 2 * q + 1, sw = (l6 & 7);
            *(uint4*)&Ps[base + ((s0 ^ sw) << 4)] = srcv[0];
            *(uint4*)&Ps[base + ((s1 ^ sw) << 4)] = srcv[1];
            float mb = mBf[l6];
            #pragma unroll
            for (int e = 0; e < 16; ++e) pk[e] = f2bf(ex2(vb[e] - mb));
            *(uint4*)&Qs[base + ((s0 ^ sw) << 4)] = srcv[0];
            *(uint4*)&Qs[base + ((s1 ^ sw) << 4)] = srcv[1];
        }
        __syncthreads();

        int w = q, lr = l6 & 15, lg = l6 >> 4;
        int brow = w * 16 + lr;
        short8 bfr[2];
        #pragma unroll
        for (int ks = 0; ks < 2; ++ks)
            bfr[ks] = *(const short8*)(Qs + brow * 128 + (((ks * 4 + lg) << 4) ^ ((brow & 7) << 4)));
        bool last = (s == nm - 1);
        float* Co = Lout + ((size_t)(b * nodes + p)) * 4096;
        #pragma unroll
        for (int rm = 0; rm < 4; ++rm) {
            f32x4 acc = {0.f, 0.f, 0.f, 0.f};
            int ar = rm * 16 + lr;
            #pragma unroll
            for (int ks = 0; ks < 2; ++ks) {
                short8 af = *(const short8*)(Ps + ar * 128 + (((ks * 4 + lg) << 4) ^ ((ar & 7) << 4)));
                acc = __builtin_amdgcn_mfma_f32_16x16x32_bf16(af, bfr[ks], acc, 0, 0, 0);
            }
            #pragma unroll
            for (int e = 0; e < 4; ++e) {
                int ii = rm * 16 + lg * 4 + e;
                int jj = w * 16 + lr;
                float cv = mA2[ii] + mB2[jj] + lg2(fmaxf(acc[e], 1e-33f));
                if (last) Co[ii * 64 + jj] = cv;
                else      Rb[ii][jj] = cv;
            }
        }
        if (!last) {
            __syncthreads();
            #pragma unroll
            for (int jj = 0; jj < 16; ++jj)
                va[jj] = Rb[l6][q * 16 + jj];
        }
    }
}

// ================= fused last tree level + final lse ==================
// Lin = LvC: 4 mats per batch. Combine all 4 in LDS, then out[b].
__global__ __launch_bounds__(256) void fhmm_tree_final(
    const float* __restrict__ Lin,
    const float* __restrict__ startv, const float* __restrict__ Ew2,
    const float* __restrict__ lse_em2,
    const int* __restrict__ text, const int* __restrict__ w2s,
    float* __restrict__ out)
{
    int b = blockIdx.x;
    int tid = threadIdx.x;
    int l6 = tid & 63, q = tid >> 6;

    __shared__ float Rb[64][65];
    __shared__ char Ps[8192], Qs[8192];
    __shared__ float mA2[64], mB2[64], mAf[64], mBf[64];
    __shared__ float part[2][4][64];
    __shared__ float a0[64];
    __shared__ float rm_[4], rs_[4];

    float va[16];
    {
        const float* Af = Lin + ((size_t)(b * 4)) * 4096;
        #pragma unroll
        for (int jj = 0; jj < 16; ++jj)
            va[jj] = Af[l6 * 64 + q * 16 + jj];
    }

    for (int s = 1; s < 4; ++s) {
        float mloc = -3e38f;
        #pragma unroll
        for (int jj = 0; jj < 16; ++jj) mloc = fmaxf(mloc, va[jj]);
        part[0][q][l6] = mloc;

        const float* Bf = Lin + ((size_t)(b * 4 + s)) * 4096;
        float vb[16];
        float mlocB = -3e38f;
        #pragma unroll
        for (int kk = 0; kk < 16; ++kk) {
            float v = Bf[(q * 16 + kk) * 64 + l6];
            vb[kk] = v; mlocB = fmaxf(mlocB, v);
        }
        part[1][q][l6] = mlocB;
        __syncthreads();

        if (tid < 64) {
            float mf = fmaxf(fmaxf(part[0][0][tid], part[0][1][tid]),
                             fmaxf(part[0][2][tid], part[0][3][tid]));
            mAf[tid] = mf; mA2[tid] = mf;
        } else if (tid < 128) {
            int j = tid & 63;
            float mf = fmaxf(fmaxf(part[1][0][j], part[1][1][j]),
                             fmaxf(part[1][2][j], part[1][3][j]));
            mBf[j] = mf; mB2[j] = mf;
        }
        __syncthreads();

        {
            float ma = mAf[l6];
            u16 pk[16];
            #pragma unroll
            for (int e = 0; e < 16; ++e) pk[e] = f2bf(ex2(va[e] - ma));
            uint4* srcv = (uint4*)pk;
            int base = l6 * 128;
            int s0 = 2 * q, s1 = 2 * q + 1, sw = (l6 & 7);
            *(uint4*)&Ps[base + ((s0 ^ sw) << 4)] = srcv[0];
            *(uint4*)&Ps[base + ((s1 ^ sw) << 4)] = srcv[1];
            float mb = mBf[l6];
            #pragma unroll
            for (int e = 0; e < 16; ++e) pk[e] = f2bf(ex2(vb[e] - mb));
            *(uint4*)&Qs[base + ((s0 ^ sw) << 4)] = srcv[0];
            *(uint4*)&Qs[base + ((s1 ^ sw) << 4)] = srcv[1];
        }
        __syncthreads();

        int w = q, lr = l6 & 15, lg = l6 >> 4;
        int brow = w * 16 + lr;
        short8 bfr[2];
        #pragma unroll
        for (int ks = 0; ks < 2; ++ks)
            bfr[ks] = *(const short8*)(Qs + brow * 128 + (((ks * 4 + lg) << 4) ^ ((brow & 7) << 4)));
        #pragma unroll
        for (int rm = 0; rm < 4; ++rm) {
            f32x4 acc = {0.f, 0.f, 0.f, 0.f};
            int ar = rm * 16 + lr;
            #pragma unroll
            for (int ks = 0; ks < 2; ++ks) {
                short8 af = *(const short8*)(Ps + ar * 128 + (((ks * 4 + lg) << 4) ^ ((ar & 7) << 4)));
                acc = __builtin_amdgcn_mfma_f32_16x16x32_bf16(af, bfr[ks], acc, 0, 0, 0);
            }
            #pragma unroll
            for (int e = 0; e < 4; ++e) {
                int ii = rm * 16 + lg * 4 + e;
                int jj = w * 16 + lr;
                Rb[ii][jj] = mA2[ii] + mB2[jj] + lg2(fmaxf(acc[e], 1e-33f));
            }
        }
        __syncthreads();
        if (s < 3) {
            #pragma unroll
            for (int jj = 0; jj < 16; ++jj)
                va[jj] = Rb[l6][q * 16 + jj];
        }
    }

    // a0 and final lse
    if (tid < 64) {
        int v0 = text[b * TTT];
        int s0 = w2s[v0 * SPWW];
        a0[tid] = startv[s0 + tid] * LOG2E + Ew2[(size_t)v0 * 64 + tid] - lse_em2[s0 + tid];
    }
    __syncthreads();
    float m = -3e38f, s = 0.f;
    for (int e = tid; e < 4096; e += 256) {
        float v = a0[e >> 6] + Rb[e >> 6][e & 63];
        float mn = fmaxf(m, v);
        s = s * ex2(m - mn) + ex2(v - mn);
        m = mn;
    }
    #pragma unroll
    for (int d = 32; d; d >>= 1) {
        float m2 = __shfl_xor(m, d), sx = __shfl_xor(s, d);
        float mn = fmaxf(m, m2);
        s = s * ex2(m - mn) + sx * ex2(m2 - mn); m = mn;
    }
    if ((tid & 63) == 0) { rm_[tid >> 6] = m; rs_[tid >> 6] = s; }
    __syncthreads();
    if (tid == 0) {
        float M_ = rm_[0], S_ = rs_[0];
        #pragma unroll
        for (int qq = 1; qq < 4; ++qq) {
            float mn = fmaxf(M_, rm_[qq]);
            S_ = S_ * ex2(M_ - mn) + rs_[qq] * ex2(rm_[qq] - mn); M_ = mn;
        }
        out[b] = (M_ + lg2(S_)) * LN2;
    }
}

extern "C" void kernel_launch(void* const* d_in, const int* in_sizes, int n_in,
                              void* d_out, int out_size, void* d_ws, size_t ws_size,
                              hipStream_t stream) {
    const int* text        = (const int*)d_in[0];
    const int* w2s         = (const int*)d_in[1];
    const float* se1_start = (const float*)d_in[2];
    const float* se2_start = (const float*)d_in[3];
    const float* start_w1  = (const float*)d_in[4];
    const float* start_b1  = (const float*)d_in[5];
    const float* start_w2  = (const float*)d_in[6];
    const float* start_b2  = (const float*)d_in[7];
    const float* start_pw  = (const float*)d_in[8];
    const float* start_pb  = (const float*)d_in[9];
    const float* se1_state = (const float*)d_in[10];
    const float* se2_state = (const float*)d_in[11];
    const float* se1_next  = (const float*)d_in[12];
    const float* se2_next  = (const float*)d_in[13];
    const float* trans_w1  = (const float*)d_in[14];
    const float* trans_b1  = (const float*)d_in[15];
    const float* trans_w2  = (const float*)d_in[16];
    const float* trans_b2  = (const float*)d_in[17];
    const float* se1_pre   = (const float*)d_in[18];
    const float* se2_pre   = (const float*)d_in[19];
    const float* term_w1   = (const float*)d_in[20];
    const float* term_b1   = (const float*)d_in[21];
    const float* term_w2   = (const float*)d_in[22];
    const float* term_b2   = (const float*)d_in[23];
    const float* term_pw   = (const float*)d_in[24];
    const float* term_pb   = (const float*)d_in[25];
    float* out = (float*)d_out;

    char* wp = (char*)d_ws;
    auto alloc = [&](size_t bytes) {
        char* p = wp;
        wp += (bytes + 255) & ~(size_t)255;
        return (void*)p;
    };
    u16* h1a         = (u16*)alloc((size_t)CST * HH * 2);
    u16* h1b         = (u16*)alloc((size_t)CST * HH * 2);
    u16* h1c         = (u16*)alloc((size_t)CST * HH * 2);
    u16* hstart_bf   = (u16*)alloc((size_t)CST * HH * 2);
    u16* h_state_bf  = (u16*)alloc((size_t)CST * HH * 2);
    u16* h_pre_bf    = (u16*)alloc((size_t)CST * HH * 2);
    u16* Wt          = (u16*)alloc((size_t)6 * HH * HH * 2);
    u16* pwT         = (u16*)alloc((size_t)VV * HH * 2);
    u16* e1n_bf      = (u16*)alloc((size_t)NCC * HH * 2);
    u16* e2n_bf      = (u16*)alloc((size_t)SPWW * HH * 2);
    float* U2        = (float*)alloc((size_t)CST * NCC * 4);
    float* V2        = (float*)alloc((size_t)CST * SPWW * 4);
    float* startv    = (float*)alloc(CST * 4);
    float* lse_trans = (float*)alloc(CST * 4);
    float* lse_em    = (float*)alloc(CST * 4);
    float* Ew        = (float*)alloc((size_t)VV * 64 * 4);
    int* counts      = (int*)alloc(NCC * 4);
    int* offsets     = (int*)alloc((NCC + 4) * 4);
    int* wlist       = (int*)alloc(VV * 4);
    float* LvA       = (float*)alloc((size_t)BBB * 64 * 4096 * 4);
    float* LvB       = (float*)alloc((size_t)BBB * 16 * 4096 * 4);
    float* LvC       = (float*)alloc((size_t)BBB * 4 * 4096 * 4);

    // ---- mega setup: 6 wtrans + pwtrans + next-embs + wordlist ----
    SetupA sa;
    sa.Ws[0] = start_w1; sa.Ws[1] = start_w2; sa.Ws[2] = trans_w1;
    sa.Ws[3] = trans_w2; sa.Ws[4] = term_w1;  sa.Ws[5] = term_w2;
    sa.Wt = Wt; sa.pw = term_pw; sa.pwT = pwT;
    sa.e1n = se1_next; sa.e2n = se2_next; sa.e1nb = e1n_bf; sa.e2nb = e2n_bf;
    sa.w2s = w2s; sa.counts = counts; sa.offsets = offsets; sa.wlist = wlist;
    hipLaunchKernelGGL(fhmm_setup, dim3(853), 256, 0, stream, sa);

    // ---- batched MLP layer 1 (3 heads, emb on the fly) ----
    MlpA m1;
    m1.X[0] = m1.X[1] = m1.X[2] = nullptr;
    m1.se1[0] = se1_start; m1.se1[1] = se1_state; m1.se1[2] = se1_pre;
    m1.se2[0] = se2_start; m1.se2[1] = se2_state; m1.se2[2] = se2_pre;
    m1.Wth[0] = Wt + 0 * HH * HH; m1.Wth[1] = Wt + 2 * HH * HH; m1.Wth[2] = Wt + 4 * HH * HH;
    m1.bias[0] = start_b1; m1.bias[1] = trans_b1; m1.bias[2] = term_b1;
    m1.Y[0] = h1a; m1.Y[1] = h1b; m1.Y[2] = h1c;
    m1.oscale[0] = m1.oscale[1] = m1.oscale[2] = 1.0f;
    hipLaunchKernelGGL((fhmm_mlp_batch<0>), dim3(128, 4, 3), 256, 0, stream, m1);

    // ---- batched MLP layer 2 (3 heads, residual on the fly) ----
    MlpA m2 = m1;
    m2.X[0] = h1a; m2.X[1] = h1b; m2.X[2] = h1c;
    m2.Wth[0] = Wt + 1 * HH * HH; m2.Wth[1] = Wt + 3 * HH * HH; m2.Wth[2] = Wt + 5 * HH * HH;
    m2.bias[0] = start_b2; m2.bias[1] = trans_b2; m2.bias[2] = term_b2;
    m2.Y[0] = hstart_bf; m2.Y[1] = h_state_bf; m2.Y[2] = h_pre_bf;
    m2.oscale[0] = 1.0f; m2.oscale[1] = LOG2E; m2.oscale[2] = 1.0f;
    hipLaunchKernelGGL((fhmm_mlp_batch<1>), dim3(128, 4, 3), 256, 0, stream, m2);

    // ---- start probs ----
    hipLaunchKernelGGL(fhmm_dotpw_kernel, dim3(2048), 256, 0, stream,
                       hstart_bf, start_pw, start_pb, startv);
    hipLaunchKernelGGL(fhmm_lsm_vec_kernel, dim3(1), 1024, 0, stream, startv);

    // ---- U/V GEMMs + row-lse ----
    hipLaunchKernelGGL(fhmm_gemm_uv, dim3(128, 3), 256, 0, stream,
                       h_state_bf, e1n_bf, e2n_bf, U2, V2);
    hipLaunchKernelGGL(fhmm_lse_uv, dim3(2048), 256, 0, stream, U2, V2, lse_trans);

    // ---- emission (Ew2 + fused lse_em2) ----
    hipLaunchKernelGGL(fhmm_ew_mfma, dim3(NCC), 256, 0, stream,
                       h_pre_bf, pwT, term_pb, wlist, counts, offsets, Ew, lse_em);

    // ---- 4-ary tree (leaf builds M_t inline from U2/V2/Ew2/lse_em2) ----
    hipLaunchKernelGGL((fhmm_combine4<1>), dim3(64, BBB), 256, 0, stream,
                       U2, V2, Ew, lse_em, lse_trans, text, w2s,
                       (const float*)nullptr, LvA);
    hipLaunchKernelGGL((fhmm_combine4<0>), dim3(16, BBB), 256, 0, stream,
                       (const float*)nullptr, (const float*)nullptr,
                       (const float*)nullptr, (const float*)nullptr,
                       (const float*)nullptr, (const int*)nullptr,
                       (const int*)nullptr, LvA, LvB);
    hipLaunchKernelGGL((fhmm_combine4<0>), dim3(4, BBB), 256, 0, stream,
                       (const float*)nullptr, (const float*)nullptr,
                       (const float*)nullptr, (const float*)nullptr,
                       (const float*)nullptr, (const int*)nullptr,
                       (const int*)nullptr, LvB, LvC);

    // ---- last tree level fused with final lse ----
    hipLaunchKernelGGL(fhmm_tree_final, dim3(BBB), 256, 0, stream,
                       LvC, startv, Ew, lse_em, text, w2s, out);
}